// Round 1
// baseline (9234.801 us; speedup 1.0000x reference)
//
#include <hip/hip_runtime.h>
#include <hip/hip_bf16.h>

#define S_N 4
#define E_N 16384
#define SEQ_N (S_N*E_N)   // 65536
#define L_N 12
#define H_N 128
#define G_N 384           // 3*H
#define DIN_N 385
#define F_N 64
#define NSEL 100
#define TS 8
#define TWO_PI_F 6.28318530717958647692f

static __device__ __forceinline__ float sigm(float x){ return 1.0f/(1.0f+__expf(-x)); }
static __device__ __forceinline__ float tanhfast(float x){ return 1.0f - 2.0f/(__expf(2.0f*x)+1.0f); }
static __device__ __forceinline__ float softplusf(float x){ return fmaxf(x,0.0f) + log1pf(__expf(-fabsf(x))); }
static __device__ __forceinline__ float bf2f(unsigned short u){ return __uint_as_float(((unsigned int)u)<<16); }

// ---------------- precompute: reversed walks, anonymized sin/cos, degree max ----------------
__global__ void k_precompute(const int* __restrict__ walks, const int* __restrict__ dstdeg,
                             int* __restrict__ wrev, float* __restrict__ uwbuf, int* __restrict__ degmax)
{
  const int q = blockIdx.x*blockDim.x + threadIdx.x;   // one walk per thread, grid exact
  int wk[L_N], un[L_N];
  #pragma unroll
  for (int t=0;t<L_N;t++) wk[t] = walks[q*L_N+t];
  int ndist = 0;
  #pragma unroll
  for (int t=0;t<L_N;t++){
    int u = -1;
    for (int p=0;p<t;p++) if (wk[p]==wk[t]) { u = un[p]; break; }
    if (u < 0) u = ndist++;
    un[t] = u;
  }
  int dmax = 0;
  #pragma unroll
  for (int tr=0;tr<L_N;tr++){
    const int o = L_N-1-tr;             // reversed timeline
    const int node = wk[o];
    wrev[q*L_N+tr] = node;
    float ang = (float)un[o] * (TWO_PI_F/(float)L_N);
    uwbuf[2*(q*L_N+tr)+0] = __sinf(ang);
    uwbuf[2*(q*L_N+tr)+1] = __cosf(ang);
    dmax = max(dmax, dstdeg[node]);
  }
  for (int off=32; off; off>>=1) dmax = max(dmax, __shfl_down(dmax, off));
  if ((threadIdx.x & 63)==0) atomicMax(degmax, dmax);
}

// ---------------- weight transpose: src[rows][cols] -> dst[cols][rows] ----------------
__global__ void k_transpose(const float* __restrict__ src, float* __restrict__ dst, int rows, int cols)
{
  int i = blockIdx.x*blockDim.x + threadIdx.x;
  if (i < rows*cols){
    int r = i/cols, c = i - r*cols;
    dst[c*rows + r] = src[i];
  }
}

// ---------------- fused 3-GRU kernel ----------------
// block: 256 threads = hidden unit j (0..127) x seq-group sg (0..1); TS=8 seqs/block.
__global__ __launch_bounds__(256) void k_rum(
    const float* __restrict__ x,
    const float* __restrict__ wihf, const float* __restrict__ bihf,
    const float* __restrict__ whhfT, const float* __restrict__ bhhf,
    const float* __restrict__ wihb, const float* __restrict__ bihb,
    const float* __restrict__ whhbT, const float* __restrict__ bhhb,
    const float* __restrict__ wihT, const float* __restrict__ bih,
    const float* __restrict__ whhT, const float* __restrict__ bhh,
    const int* __restrict__ dstdeg, const int* __restrict__ degmax,
    const int* __restrict__ ssidx,
    const int* __restrict__ wrev, const float* __restrict__ uwbuf,
    float* __restrict__ out, float* __restrict__ ysel)
{
  __shared__ __hip_bfloat16 yf_st[L_N][TS][H_N];  // 24.5 KB
  __shared__ __hip_bfloat16 yb_st[L_N][TS][H_N];  // 24.5 KB
  __shared__ float h_lds[TS][H_N];                // 4 KB
  __shared__ float xf_lds[TS][H_N];               // 4 KB
  __shared__ float uw_lds[TS][L_N][2];
  __shared__ float deg_lds[TS][L_N];
  __shared__ int   node_lds[TS][L_N];
  __shared__ int   selcnt[TS];
  __shared__ int   selidx[TS][8];

  const int tid  = threadIdx.x;
  const int j    = tid & (H_N-1);
  const int sg   = tid >> 7;
  const int s0   = sg*4;
  const int seq0 = blockIdx.x*TS;

  if (tid < TS) selcnt[tid] = 0;
  __syncthreads();

  for (int p = tid; p < TS*L_N; p += 256){
    int si = p / L_N, t = p - si*L_N;
    int node = wrev[(seq0+si)*L_N + t];
    node_lds[si][t] = node;
    uw_lds[si][t][0] = uwbuf[2*((seq0+si)*L_N + t)+0];
    uw_lds[si][t][1] = uwbuf[2*((seq0+si)*L_N + t)+1];
  }
  if (tid < NSEL){
    int e = ssidx[tid];       // values in [0,E) -> flat seq index (s==0 block)
    int d = e - seq0;
    if (d >= 0 && d < TS){
      int slot = atomicAdd(&selcnt[d], 1);
      if (slot < 8) selidx[d][slot] = tid;
    }
  }
  for (int p = tid; p < TS*H_N; p += 256) (&h_lds[0][0])[p] = 0.0f;
  __syncthreads();
  const float dmaxf = (float)(*degmax);
  for (int p = tid; p < TS*L_N; p += 256){
    int si = p / L_N, t = p - si*L_N;
    deg_lds[si][t] = (float)dstdeg[node_lds[si][t]] / dmaxf;
  }
  __syncthreads();

  // hoisted per-thread weights/biases (row j of each gate)
  const float wbs0 = wihb[(0*H_N+j)*2+0], wbc0 = wihb[(0*H_N+j)*2+1];
  const float wbs1 = wihb[(1*H_N+j)*2+0], wbc1 = wihb[(1*H_N+j)*2+1];
  const float wbs2 = wihb[(2*H_N+j)*2+0], wbc2 = wihb[(2*H_N+j)*2+1];
  const float bb_r  = bihb[j] + bhhb[j];
  const float bb_z  = bihb[H_N+j] + bhhb[H_N+j];
  const float bb_ni = bihb[2*H_N+j];
  const float bb_nh = bhhb[2*H_N+j];

  const float wfs0 = wihf[(0*H_N+j)*2+0], wfc0 = wihf[(0*H_N+j)*2+1];
  const float wfs1 = wihf[(1*H_N+j)*2+0], wfc1 = wihf[(1*H_N+j)*2+1];
  const float wfs2 = wihf[(2*H_N+j)*2+0], wfc2 = wihf[(2*H_N+j)*2+1];
  const float bf_r  = bihf[j] + bhhf[j];
  const float bf_z  = bihf[H_N+j] + bhhf[H_N+j];
  const float bf_ni = bihf[2*H_N+j];
  const float bf_nh = bhhf[2*H_N+j];

  const float bm_r  = bih[j] + bhh[j];
  const float bm_z  = bih[H_N+j] + bhh[H_N+j];
  const float bm_ni = bih[2*H_N+j];
  const float bm_nh = bhh[2*H_N+j];
  const float wm_d0 = wihT[(DIN_N-1)*G_N + j];
  const float wm_d1 = wihT[(DIN_N-1)*G_N + H_N + j];
  const float wm_d2 = wihT[(DIN_N-1)*G_N + 2*H_N + j];

  float hreg[4], hbk[4];
  #pragma unroll
  for (int q=0;q<4;q++) hreg[q] = 0.0f;

  // ============ backward small GRU (input = uw reversed back to original order) ============
  {
    const float* wr = whhbT + j;
    for (int tau=0; tau<L_N; ++tau){
      const int o = L_N-1-tau;
      float ar[4], az[4], gin[4], anh[4];
      #pragma unroll
      for (int q=0;q<4;q++){
        float sv = uw_lds[s0+q][o][0], cv = uw_lds[s0+q][o][1];
        ar[q]  = fmaf(wbs0, sv, fmaf(wbc0, cv, bb_r));
        az[q]  = fmaf(wbs1, sv, fmaf(wbc1, cv, bb_z));
        gin[q] = fmaf(wbs2, sv, fmaf(wbc2, cv, bb_ni));
        anh[q] = bb_nh;
      }
      #pragma unroll 2
      for (int kk=0; kk<H_N/4; ++kk){
        float4 hv[4];
        #pragma unroll
        for (int q=0;q<4;q++) hv[q] = reinterpret_cast<const float4*>(h_lds[s0+q])[kk];
        #pragma unroll
        for (int u=0;u<4;u++){
          const int k = kk*4+u;
          const float w0 = wr[k*G_N], w1 = wr[k*G_N+H_N], w2 = wr[k*G_N+2*H_N];
          #pragma unroll
          for (int q=0;q<4;q++){
            const float f = ((const float*)&hv[q])[u];
            ar[q]=fmaf(w0,f,ar[q]); az[q]=fmaf(w1,f,az[q]); anh[q]=fmaf(w2,f,anh[q]);
          }
        }
      }
      #pragma unroll
      for (int q=0;q<4;q++){
        float r = sigm(ar[q]), z = sigm(az[q]);
        float n = tanhfast(fmaf(r, anh[q], gin[q]));
        hreg[q] = (1.0f - z)*n + z*hreg[q];
      }
      __syncthreads();
      #pragma unroll
      for (int q=0;q<4;q++){
        h_lds[s0+q][j] = hreg[q];
        yb_st[tau][s0+q][j] = __float2bfloat16(hreg[q]);
      }
      __syncthreads();
    }
  }
  #pragma unroll
  for (int q=0;q<4;q++){ hbk[q]=hreg[q]; hreg[q]=0.0f; h_lds[s0+q][j]=0.0f; }
  __syncthreads();

  // ============ forward small GRU (input = uw as stored, reversed timeline) ============
  {
    const float* wr = whhfT + j;
    for (int t=0; t<L_N; ++t){
      float ar[4], az[4], gin[4], anh[4];
      #pragma unroll
      for (int q=0;q<4;q++){
        float sv = uw_lds[s0+q][t][0], cv = uw_lds[s0+q][t][1];
        ar[q]  = fmaf(wfs0, sv, fmaf(wfc0, cv, bf_r));
        az[q]  = fmaf(wfs1, sv, fmaf(wfc1, cv, bf_z));
        gin[q] = fmaf(wfs2, sv, fmaf(wfc2, cv, bf_ni));
        anh[q] = bf_nh;
      }
      #pragma unroll 2
      for (int kk=0; kk<H_N/4; ++kk){
        float4 hv[4];
        #pragma unroll
        for (int q=0;q<4;q++) hv[q] = reinterpret_cast<const float4*>(h_lds[s0+q])[kk];
        #pragma unroll
        for (int u=0;u<4;u++){
          const int k = kk*4+u;
          const float w0 = wr[k*G_N], w1 = wr[k*G_N+H_N], w2 = wr[k*G_N+2*H_N];
          #pragma unroll
          for (int q=0;q<4;q++){
            const float f = ((const float*)&hv[q])[u];
            ar[q]=fmaf(w0,f,ar[q]); az[q]=fmaf(w1,f,az[q]); anh[q]=fmaf(w2,f,anh[q]);
          }
        }
      }
      #pragma unroll
      for (int q=0;q<4;q++){
        float r = sigm(ar[q]), z = sigm(az[q]);
        float n = tanhfast(fmaf(r, anh[q], gin[q]));
        hreg[q] = (1.0f - z)*n + z*hreg[q];
      }
      __syncthreads();
      #pragma unroll
      for (int q=0;q<4;q++){
        h_lds[s0+q][j] = hreg[q];
        yf_st[t][s0+q][j] = __float2bfloat16(hreg[q]);
      }
      __syncthreads();
    }
  }

  // ============ main GRU: h0 = 0.5*(hf+hb); feat = [xf, yf, yb_rev, deg] ============
  #pragma unroll
  for (int q=0;q<4;q++){ hreg[q] = 0.5f*(hreg[q]+hbk[q]); h_lds[s0+q][j] = hreg[q]; }
  __syncthreads();

  {
    const float* wi = wihT + j;
    const float* wh = whhT + j;
    for (int t=0; t<L_N; ++t){
      // stage gathered x rows for this step
      for (int p = tid; p < TS*H_N; p += 256){
        int si = p >> 7, k = p & (H_N-1);
        xf_lds[si][k] = x[(size_t)node_lds[si][t]*H_N + k];
      }
      __syncthreads();

      const int rb = L_N-1-t;
      float ar[4], az[4], gin[4], anh[4];
      #pragma unroll
      for (int q=0;q<4;q++){
        const float dg = deg_lds[s0+q][t];
        ar[q]  = fmaf(wm_d0, dg, bm_r);
        az[q]  = fmaf(wm_d1, dg, bm_z);
        gin[q] = fmaf(wm_d2, dg, bm_ni);
        anh[q] = bm_nh;
      }
      // segment 1: xf (features 0..127)
      #pragma unroll 2
      for (int kk=0; kk<H_N/4; ++kk){
        float4 fv[4];
        #pragma unroll
        for (int q=0;q<4;q++) fv[q] = reinterpret_cast<const float4*>(xf_lds[s0+q])[kk];
        #pragma unroll
        for (int u=0;u<4;u++){
          const int k = kk*4+u;
          const float w0 = wi[k*G_N], w1 = wi[k*G_N+H_N], w2 = wi[k*G_N+2*H_N];
          #pragma unroll
          for (int q=0;q<4;q++){
            const float f = ((const float*)&fv[q])[u];
            ar[q]=fmaf(w0,f,ar[q]); az[q]=fmaf(w1,f,az[q]); gin[q]=fmaf(w2,f,gin[q]);
          }
        }
      }
      // segment 2: yf (features 128..255)
      #pragma unroll 2
      for (int kk=0; kk<H_N/4; ++kk){
        ushort4 uv[4];
        #pragma unroll
        for (int q=0;q<4;q++) uv[q] = reinterpret_cast<const ushort4*>(yf_st[t][s0+q])[kk];
        #pragma unroll
        for (int u=0;u<4;u++){
          const int k = H_N + kk*4+u;
          const float w0 = wi[k*G_N], w1 = wi[k*G_N+H_N], w2 = wi[k*G_N+2*H_N];
          #pragma unroll
          for (int q=0;q<4;q++){
            const float f = bf2f(((const unsigned short*)&uv[q])[u]);
            ar[q]=fmaf(w0,f,ar[q]); az[q]=fmaf(w1,f,az[q]); gin[q]=fmaf(w2,f,gin[q]);
          }
        }
      }
      // segment 3: yb reversed (features 256..383)
      #pragma unroll 2
      for (int kk=0; kk<H_N/4; ++kk){
        ushort4 uv[4];
        #pragma unroll
        for (int q=0;q<4;q++) uv[q] = reinterpret_cast<const ushort4*>(yb_st[rb][s0+q])[kk];
        #pragma unroll
        for (int u=0;u<4;u++){
          const int k = 2*H_N + kk*4+u;
          const float w0 = wi[k*G_N], w1 = wi[k*G_N+H_N], w2 = wi[k*G_N+2*H_N];
          #pragma unroll
          for (int q=0;q<4;q++){
            const float f = bf2f(((const unsigned short*)&uv[q])[u]);
            ar[q]=fmaf(w0,f,ar[q]); az[q]=fmaf(w1,f,az[q]); gin[q]=fmaf(w2,f,gin[q]);
          }
        }
      }
      // recurrent
      #pragma unroll 2
      for (int kk=0; kk<H_N/4; ++kk){
        float4 hv[4];
        #pragma unroll
        for (int q=0;q<4;q++) hv[q] = reinterpret_cast<const float4*>(h_lds[s0+q])[kk];
        #pragma unroll
        for (int u=0;u<4;u++){
          const int k = kk*4+u;
          const float w0 = wh[k*G_N], w1 = wh[k*G_N+H_N], w2 = wh[k*G_N+2*H_N];
          #pragma unroll
          for (int q=0;q<4;q++){
            const float f = ((const float*)&hv[q])[u];
            ar[q]=fmaf(w0,f,ar[q]); az[q]=fmaf(w1,f,az[q]); anh[q]=fmaf(w2,f,anh[q]);
          }
        }
      }
      #pragma unroll
      for (int q=0;q<4;q++){
        float r = sigm(ar[q]), z = sigm(az[q]);
        float n = tanhfast(fmaf(r, anh[q], gin[q]));
        hreg[q] = (1.0f - z)*n + z*hreg[q];
      }
      __syncthreads();
      #pragma unroll
      for (int q=0;q<4;q++){
        const int si = s0+q;
        h_lds[si][j] = hreg[q];
        if (t < L_N-1){
          int c = selcnt[si]; if (c > 8) c = 8;
          for (int m=0;m<c;m++)
            ysel[((size_t)selidx[si][m]*(L_N-1) + t)*H_N + j] = hreg[q];
        }
      }
      __syncthreads();
    }
  }

  #pragma unroll
  for (int q=0;q<4;q++)
    out[(size_t)(seq0+s0+q)*H_N + j] = hreg[q];
}

// ---------------- loss over 100 selected sequences ----------------
__global__ __launch_bounds__(64) void k_loss(
    const float* __restrict__ ysel, const float* __restrict__ y0,
    const int* __restrict__ wrev, const int* __restrict__ ssidx,
    const float* __restrict__ fcw, const float* __restrict__ fcb,
    float* __restrict__ accum)
{
  const int i = blockIdx.x;     // 0..99
  const int f = threadIdx.x;    // 0..63
  __shared__ float yh[H_N];
  const int seq = ssidx[i];
  float A=0.0f, B=0.0f, Sy=0.0f;
  const float bias = fcb[f];
  for (int t=0;t<L_N-1;t++){
    for (int k=f;k<H_N;k+=64) yh[k] = ysel[((size_t)i*(L_N-1)+t)*H_N + k];
    __syncthreads();
    float lg = bias;
    #pragma unroll 4
    for (int k=0;k<H_N;k++) lg = fmaf(fcw[f*H_N+k], yh[k], lg);
    const int node = wrev[seq*L_N + t + 1];
    const float yt = y0[(size_t)node*F_N + f];
    A += yt * softplusf(-lg);
    B += (1.0f-yt) * softplusf(lg);
    Sy += yt;
    __syncthreads();
  }
  for (int off=32; off; off>>=1){
    A += __shfl_down(A,off); B += __shfl_down(B,off); Sy += __shfl_down(Sy,off);
  }
  if (f==0){ atomicAdd(&accum[1],A); atomicAdd(&accum[2],B); atomicAdd(&accum[3],Sy); }
}

__global__ void k_finalize(const float* __restrict__ accum, float* __restrict__ out){
  if (threadIdx.x==0 && blockIdx.x==0)
    out[(size_t)SEQ_N*H_N] = accum[1]/accum[3] + accum[2]/(float)(NSEL*(L_N-1)*F_N);
}

extern "C" void kernel_launch(void* const* d_in, const int* in_sizes, int n_in,
                              void* d_out, int out_size, void* d_ws, size_t ws_size,
                              hipStream_t stream)
{
  const float* x     = (const float*)d_in[0];
  const float* y0    = (const float*)d_in[1];
  const float* wih_f = (const float*)d_in[2];
  const float* whh_f = (const float*)d_in[3];
  const float* bih_f = (const float*)d_in[4];
  const float* bhh_f = (const float*)d_in[5];
  const float* wih_b = (const float*)d_in[6];
  const float* whh_b = (const float*)d_in[7];
  const float* bih_b = (const float*)d_in[8];
  const float* bhh_b = (const float*)d_in[9];
  const float* wih   = (const float*)d_in[10];
  const float* whh   = (const float*)d_in[11];
  const float* bih   = (const float*)d_in[12];
  const float* bhh   = (const float*)d_in[13];
  const float* fc_w  = (const float*)d_in[14];
  const float* fc_b  = (const float*)d_in[15];
  const int*   walks = (const int*)d_in[16];
  const int*   dstdeg= (const int*)d_in[17];
  const int*   ssidx = (const int*)d_in[18];
  (void)in_sizes; (void)n_in; (void)out_size; (void)ws_size;

  char* ws = (char*)d_ws;
  size_t off = 0;
  auto wsalloc = [&](size_t bytes)->void* {
    void* p = ws + off; off += (bytes + 255) & ~(size_t)255; return p;
  };
  int*   accum_i = (int*)wsalloc(16);   // [0]=degmax(int), [1]=A,[2]=B,[3]=Syt (float)
  float* accum_f = (float*)accum_i;
  int*   wrev  = (int*)  wsalloc(sizeof(int)  * SEQ_N * L_N);
  float* uwbuf = (float*)wsalloc(sizeof(float)* SEQ_N * L_N * 2);
  float* wihT  = (float*)wsalloc(sizeof(float)* DIN_N * G_N);
  float* whhT  = (float*)wsalloc(sizeof(float)* H_N   * G_N);
  float* whhfT = (float*)wsalloc(sizeof(float)* H_N   * G_N);
  float* whhbT = (float*)wsalloc(sizeof(float)* H_N   * G_N);
  float* ysel  = (float*)wsalloc(sizeof(float)* NSEL * (L_N-1) * H_N);

  hipMemsetAsync(accum_i, 0, 16, stream);
  k_precompute<<<SEQ_N/256, 256, 0, stream>>>(walks, dstdeg, wrev, uwbuf, accum_i);
  k_transpose<<<(G_N*DIN_N+255)/256, 256, 0, stream>>>(wih,   wihT,  G_N, DIN_N);
  k_transpose<<<(G_N*H_N  +255)/256, 256, 0, stream>>>(whh,   whhT,  G_N, H_N);
  k_transpose<<<(G_N*H_N  +255)/256, 256, 0, stream>>>(whh_f, whhfT, G_N, H_N);
  k_transpose<<<(G_N*H_N  +255)/256, 256, 0, stream>>>(whh_b, whhbT, G_N, H_N);
  k_rum<<<SEQ_N/TS, 256, 0, stream>>>(x,
      wih_f, bih_f, whhfT, bhh_f,
      wih_b, bih_b, whhbT, bhh_b,
      wihT, bih, whhT, bhh,
      dstdeg, accum_i, ssidx, wrev, uwbuf,
      (float*)d_out, ysel);
  k_loss<<<NSEL, 64, 0, stream>>>(ysel, y0, wrev, ssidx, fc_w, fc_b, accum_f);
  k_finalize<<<1, 1, 0, stream>>>(accum_f, (float*)d_out);
}

// Round 2
// 3381.075 us; speedup vs baseline: 2.7313x; 2.7313x over previous
//
#include <hip/hip_runtime.h>
#include <hip/hip_bf16.h>

#define S_N 4
#define E_N 16384
#define SEQ_N (S_N*E_N)   // 65536
#define L_N 12
#define H_N 128
#define G_N 384           // 3*H
#define DIN_N 385
#define F_N 64
#define NSEL 100
#define BSEQ 16           // seqs per block (one MFMA M-tile)
#define TWO_PI_F 6.28318530717958647692f

typedef __attribute__((ext_vector_type(8))) short s16x8;
typedef __attribute__((ext_vector_type(4))) float f32x4;
#define MFMA(a,b,c) __builtin_amdgcn_mfma_f32_16x16x32_bf16(a,b,c,0,0,0)

// ---- shared memory layout (bytes) ----
#define SMEM_YF   0            // ushort [12][16][128] swizzled  (48 KB)
#define SMEM_YB   49152        // ushort [12][16][128] swizzled  (48 KB)
#define SMEM_GATE 98304        // float  [16][GSTR]              (24.25 KB)
#define GSTR 388
#define SMEM_GHN  123136       // float  [16][HSTR]              (8.25 KB)
#define HSTR 132
#define SMEM_HBF  131584       // ushort [16][128] swizzled      (4 KB)
#define SMEM_UW   135680       // float  [16][12][2]
#define SMEM_DEG  137216       // float  [16][12]
#define SMEM_NODE 137984       // int    [16][12]
#define SMEM_SELC 138752       // int    [16]
#define SMEM_SELI 138816       // int    [16][8]
#define SMEM_TOTAL 139392

static __device__ __forceinline__ float sigm(float x){ return 1.0f/(1.0f+__expf(-x)); }
static __device__ __forceinline__ float tanhfast(float x){ return 1.0f - 2.0f/(__expf(2.0f*x)+1.0f); }
static __device__ __forceinline__ float softplusf(float x){ return fmaxf(x,0.0f) + log1pf(__expf(-fabsf(x))); }
static __device__ __forceinline__ unsigned short f2bf(float f){
  unsigned int u = __float_as_uint(f);
  unsigned int r = (u + 0x7fffu + ((u>>16)&1u)) >> 16;
  return (unsigned short)r;
}
// swizzled byte offset of element (row s, col j) in a [16][128] bf16 A-tile
static __device__ __forceinline__ int swzByte(int s, int j){
  return s*256 + ((j<<1) ^ ((s&7)<<4));
}
static __device__ __forceinline__ void stH(char* base, int s, int j, float v){
  *(unsigned short*)(base + swzByte(s,j)) = f2bf(v);
}
// A-fragment read: lane holds row=lane&15, k=(lane>>4)*8+e  (16B, swizzle-matched)
static __device__ __forceinline__ s16x8 ldsA(const char* base, int lane, int kf){
  const int row = lane & 15;
  const int byte = row*256 + (((kf<<6) + ((lane>>4)<<4)) ^ ((row&7)<<4));
  return *(const s16x8*)(base + byte);
}

// ---------------- precompute: reversed walks, anonymized sin/cos, degree max ----------------
__global__ void k_precompute(const int* __restrict__ walks, const int* __restrict__ dstdeg,
                             int* __restrict__ wrev, float* __restrict__ uwbuf, int* __restrict__ degmax)
{
  const int q = blockIdx.x*blockDim.x + threadIdx.x;
  int wk[L_N], un[L_N];
  #pragma unroll
  for (int t=0;t<L_N;t++) wk[t] = walks[q*L_N+t];
  int ndist = 0;
  #pragma unroll
  for (int t=0;t<L_N;t++){
    int u = -1;
    for (int p=0;p<t;p++) if (wk[p]==wk[t]) { u = un[p]; break; }
    if (u < 0) u = ndist++;
    un[t] = u;
  }
  int dmax = 0;
  #pragma unroll
  for (int tr=0;tr<L_N;tr++){
    const int o = L_N-1-tr;             // reversed timeline
    const int node = wk[o];
    wrev[q*L_N+tr] = node;
    float ang = (float)un[o] * (TWO_PI_F/(float)L_N);
    uwbuf[2*(q*L_N+tr)+0] = __sinf(ang);
    uwbuf[2*(q*L_N+tr)+1] = __cosf(ang);
    dmax = max(dmax, dstdeg[node]);
  }
  for (int off=32; off; off>>=1) dmax = max(dmax, __shfl_down(dmax, off));
  if ((threadIdx.x & 63)==0) atomicMax(degmax, dmax);
}

// ---------------- pack weight W[384][Ksrc] (row-major, gate-major) into MFMA B-fragments ----------------
// frag elem layout: idx = ((nt*KF+kf)*64 + lane)*8 + e ; value = W[nt*16+(lane&15)][kf*32+(lane>>4)*8+e]
__global__ void k_pack(const float* __restrict__ W, unsigned short* __restrict__ dst, int Ksrc, int KF)
{
  int idx = blockIdx.x*256 + threadIdx.x;
  int total = 24*KF*64*8;
  if (idx >= total) return;
  int e = idx & 7, lane = (idx>>3)&63;
  int rem = idx>>9;
  int kf = rem % KF, nt = rem / KF;
  int n = nt*16 + (lane&15);
  int k = kf*32 + (lane>>4)*8 + e;
  dst[idx] = f2bf(W[(size_t)n*Ksrc + k]);
}

// ---------------- small-GRU phase (input dim 2 folded into acc init via VALU) ----------------
static __device__ __forceinline__ void small_gru_phase(
    char* smem, const unsigned short* __restrict__ pk,
    const float* __restrict__ wih2, const float* __restrict__ bih2, const float* __restrict__ bhh2,
    bool bwd, char* ySt, float* hreg, int tid)
{
  const int w = tid>>6, lane = tid&63, col = lane&15, krow = lane>>4;
  const int sg = tid>>7, j = tid&127;
  float* gateF = (float*)(smem + SMEM_GATE);
  float* ghnF  = (float*)(smem + SMEM_GHN);
  char*  hbf   = smem + SMEM_HBF;
  const float* uwF = (const float*)(smem + SMEM_UW);

  s16x8 bw[3][4];
  int n0[3]; bool isN[3]; float cA[3], cB2[3], wsv[3], wcv[3];
  #pragma unroll
  for (int i=0;i<3;i++){
    n0[i] = w*48 + i*16; isN[i] = (n0[i] >= 256);
    int g = n0[i] + col;
    wsv[i] = wih2[g*2]; wcv[i] = wih2[g*2+1];
    if (isN[i]){ cA[i] = bih2[g]; cB2[i] = bhh2[g]; }
    else { cA[i] = bih2[g] + bhh2[g]; cB2[i] = 0.0f; }
    #pragma unroll
    for (int kf=0;kf<4;kf++)
      bw[i][kf] = *(const s16x8*)(pk + (size_t)(((w*3+i)*4 + kf)*64 + lane)*8);
  }

  for (int st=0; st<L_N; ++st){
    const int o = bwd ? (L_N-1-st) : st;
    float sn[4], cs[4];
    #pragma unroll
    for (int q=0;q<4;q++){
      int s = krow*4+q;
      sn[q] = uwF[(s*L_N+o)*2+0]; cs[q] = uwF[(s*L_N+o)*2+1];
    }
    s16x8 a0 = ldsA(hbf,lane,0), a1 = ldsA(hbf,lane,1), a2 = ldsA(hbf,lane,2), a3 = ldsA(hbf,lane,3);
    #pragma unroll
    for (int i=0;i<3;i++){
      f32x4 acc;
      #pragma unroll
      for (int q=0;q<4;q++)
        acc[q] = isN[i] ? cB2[i] : (cA[i] + wsv[i]*sn[q] + wcv[i]*cs[q]);
      acc = MFMA(a0,bw[i][0],acc); acc = MFMA(a1,bw[i][1],acc);
      acc = MFMA(a2,bw[i][2],acc); acc = MFMA(a3,bw[i][3],acc);
      #pragma unroll
      for (int q=0;q<4;q++){
        int row = krow*4+q;
        if (!isN[i]) gateF[row*GSTR + n0[i]+col] = acc[q];
        else {
          gateF[row*GSTR + n0[i]+col] = cA[i] + wsv[i]*sn[q] + wcv[i]*cs[q];
          ghnF [row*HSTR + n0[i]-256+col] = acc[q];
        }
      }
    }
    __syncthreads();
    #pragma unroll
    for (int q=0;q<4;q++){
      int s = sg*4+q;
      float r = sigm(gateF[s*GSTR + j]);
      float z = sigm(gateF[s*GSTR + 128 + j]);
      float n = tanhfast(fmaf(r, ghnF[s*HSTR + j], gateF[s*GSTR + 256 + j]));
      float h = (1.0f - z)*n + z*hreg[q];
      hreg[q] = h;
      stH(hbf, s, j, h);
      *(unsigned short*)(ySt + st*4096 + swzByte(s,j)) = f2bf(h);
    }
    __syncthreads();
  }
}

// ---------------- fused 3-GRU kernel, MFMA ----------------
__global__ __launch_bounds__(512, 2) void k_rum(
    const float* __restrict__ x,
    const unsigned short* __restrict__ pk_whhf, const unsigned short* __restrict__ pk_whhb,
    const unsigned short* __restrict__ pk_whh,  const unsigned short* __restrict__ pk_wih,
    const float* __restrict__ wihf, const float* __restrict__ bihf, const float* __restrict__ bhhf,
    const float* __restrict__ wihb, const float* __restrict__ bihb, const float* __restrict__ bhhb,
    const float* __restrict__ wih,  const float* __restrict__ bih,  const float* __restrict__ bhh,
    const int* __restrict__ dstdeg, const int* __restrict__ degmax,
    const int* __restrict__ ssidx,
    const int* __restrict__ wrev, const float* __restrict__ uwbuf,
    float* __restrict__ out, float* __restrict__ ysel)
{
  extern __shared__ char smem[];
  float* gateF = (float*)(smem + SMEM_GATE);
  float* ghnF  = (float*)(smem + SMEM_GHN);
  char*  hbf   = smem + SMEM_HBF;
  float* uwF   = (float*)(smem + SMEM_UW);
  float* degL  = (float*)(smem + SMEM_DEG);
  int*   nodeL = (int*)(smem + SMEM_NODE);
  int*   selC  = (int*)(smem + SMEM_SELC);
  int*   selI  = (int*)(smem + SMEM_SELI);

  const int tid = threadIdx.x;
  const int w = tid>>6, lane = tid&63, col = lane&15, krow = lane>>4;
  const int sg = tid>>7, j = tid&127;
  const int seq0 = blockIdx.x*BSEQ;

  if (tid < BSEQ) selC[tid] = 0;
  __syncthreads();

  // stage nodes + uw; register selected seqs; zero h_bf16
  for (int p = tid; p < BSEQ*L_N; p += 512){
    nodeL[p] = wrev[(size_t)seq0*L_N + p];
    uwF[2*p+0] = uwbuf[2*((size_t)seq0*L_N + p)+0];
    uwF[2*p+1] = uwbuf[2*((size_t)seq0*L_N + p)+1];
  }
  if (tid < NSEL){
    int e = ssidx[tid];
    int d = e - seq0;
    if (d >= 0 && d < BSEQ){
      int slot = atomicAdd(&selC[d], 1);
      if (slot < 8) selI[d*8+slot] = tid;
    }
  }
  #pragma unroll
  for (int q=0;q<4;q++) stH(hbf, sg*4+q, j, 0.0f);
  __syncthreads();
  const float dmaxf = (float)(*degmax);
  for (int p = tid; p < BSEQ*L_N; p += 512)
    degL[p] = (float)dstdeg[nodeL[p]] / dmaxf;
  __syncthreads();

  float hreg[4] = {0.f,0.f,0.f,0.f};

  // ===== backward small GRU (original timeline), history -> yb_st[tau] =====
  small_gru_phase(smem, pk_whhb, wihb, bihb, bhhb, true,  smem+SMEM_YB, hreg, tid);
  float hb[4];
  #pragma unroll
  for (int q=0;q<4;q++){ hb[q]=hreg[q]; hreg[q]=0.f; stH(hbf, sg*4+q, j, 0.f); }
  __syncthreads();
  // ===== forward small GRU (reversed timeline), history -> yf_st[t] =====
  small_gru_phase(smem, pk_whhf, wihf, bihf, bhhf, false, smem+SMEM_YF, hreg, tid);
  #pragma unroll
  for (int q=0;q<4;q++){ hreg[q] = 0.5f*(hreg[q]+hb[q]); stH(hbf, sg*4+q, j, hreg[q]); }
  __syncthreads();

  // ===== main GRU =====
  int n0[3]; bool isN[3]; float cRZ[3], cI[3], cRn[3], wd[3];
  s16x8 bm[3][4];
  #pragma unroll
  for (int i=0;i<3;i++){
    n0[i] = w*48 + i*16; isN[i] = (n0[i] >= 256);
    int g = n0[i] + col;
    wd[i] = wih[(size_t)g*DIN_N + 384];
    if (isN[i]){ cI[i] = bih[g]; cRn[i] = bhh[g]; cRZ[i]=0.f; }
    else { cRZ[i] = bih[g] + bhh[g]; cI[i]=0.f; cRn[i]=0.f; }
    #pragma unroll
    for (int kf=0;kf<4;kf++)
      bm[i][kf] = *(const s16x8*)(pk_whh + (size_t)(((w*3+i)*4 + kf)*64 + lane)*8);
  }

  #pragma unroll 1
  for (int half=0; half<2; half++){
    const int T0 = half*6;
    // ---- input-transform GEMM for 6 steps: gi held in registers ----
    f32x4 gi[3][6];
    #pragma unroll
    for (int tt=0;tt<6;tt++){
      float dg[4];
      #pragma unroll
      for (int q=0;q<4;q++) dg[q] = degL[(krow*4+q)*L_N + T0+tt];
      #pragma unroll
      for (int i=0;i<3;i++)
        #pragma unroll
        for (int q=0;q<4;q++)
          gi[i][tt][q] = (isN[i] ? cI[i] : cRZ[i]) + wd[i]*dg[q];
    }
    #pragma unroll
    for (int kf=0;kf<12;kf++){
      s16x8 a[6];
      #pragma unroll
      for (int tt=0;tt<6;tt++){
        const int t = T0+tt;
        if (kf < 4){
          int node = nodeL[col*L_N + t];
          const float* xp = x + (size_t)node*H_N + kf*32 + krow*8;
          float4 u0 = *(const float4*)xp;
          float4 u1 = *(const float4*)(xp+4);
          s16x8 av;
          av[0]=(short)f2bf(u0.x); av[1]=(short)f2bf(u0.y); av[2]=(short)f2bf(u0.z); av[3]=(short)f2bf(u0.w);
          av[4]=(short)f2bf(u1.x); av[5]=(short)f2bf(u1.y); av[6]=(short)f2bf(u1.z); av[7]=(short)f2bf(u1.w);
          a[tt]=av;
        } else if (kf < 8){
          a[tt] = ldsA(smem + SMEM_YF + t*4096, lane, kf-4);
        } else {
          a[tt] = ldsA(smem + SMEM_YB + (L_N-1-t)*4096, lane, kf-8);
        }
      }
      #pragma unroll
      for (int i=0;i<3;i++){
        s16x8 b = *(const s16x8*)(pk_wih + (size_t)(((w*3+i)*12 + kf)*64 + lane)*8);
        #pragma unroll
        for (int tt=0;tt<6;tt++) gi[i][tt] = MFMA(a[tt], b, gi[i][tt]);
      }
    }
    // ---- recurrent scan over these 6 steps ----
    #pragma unroll 1
    for (int tt=0; tt<6; ++tt){
      const int t = T0+tt;
      s16x8 a0 = ldsA(hbf,lane,0), a1 = ldsA(hbf,lane,1), a2 = ldsA(hbf,lane,2), a3 = ldsA(hbf,lane,3);
      #pragma unroll
      for (int i=0;i<3;i++){
        f32x4 acc;
        if (!isN[i]) acc = gi[i][tt];
        else { acc[0]=cRn[i]; acc[1]=cRn[i]; acc[2]=cRn[i]; acc[3]=cRn[i]; }
        acc = MFMA(a0,bm[i][0],acc); acc = MFMA(a1,bm[i][1],acc);
        acc = MFMA(a2,bm[i][2],acc); acc = MFMA(a3,bm[i][3],acc);
        #pragma unroll
        for (int q=0;q<4;q++){
          int row = krow*4+q;
          if (!isN[i]) gateF[row*GSTR + n0[i]+col] = acc[q];
          else {
            gateF[row*GSTR + n0[i]+col] = gi[i][tt][q];
            ghnF [row*HSTR + n0[i]-256+col] = acc[q];
          }
        }
      }
      __syncthreads();
      #pragma unroll
      for (int q=0;q<4;q++){
        int s = sg*4+q;
        float r = sigm(gateF[s*GSTR + j]);
        float z = sigm(gateF[s*GSTR + 128 + j]);
        float n = tanhfast(fmaf(r, ghnF[s*HSTR + j], gateF[s*GSTR + 256 + j]));
        float h = (1.0f - z)*n + z*hreg[q];
        hreg[q] = h;
        stH(hbf, s, j, h);
        if (t < L_N-1){
          int c = selC[s]; if (c > 8) c = 8;
          for (int m=0;m<c;m++)
            ysel[((size_t)selI[s*8+m]*(L_N-1) + t)*H_N + j] = h;
        } else {
          out[(size_t)(seq0+s)*H_N + j] = h;
        }
      }
      __syncthreads();
    }
  }
}

// ---------------- loss over 100 selected sequences ----------------
__global__ __launch_bounds__(64) void k_loss(
    const float* __restrict__ ysel, const float* __restrict__ y0,
    const int* __restrict__ wrev, const int* __restrict__ ssidx,
    const float* __restrict__ fcw, const float* __restrict__ fcb,
    float* __restrict__ accum)
{
  const int i = blockIdx.x;
  const int f = threadIdx.x;
  __shared__ float yh[H_N];
  const int seq = ssidx[i];
  float A=0.0f, B=0.0f, Sy=0.0f;
  const float bias = fcb[f];
  for (int t=0;t<L_N-1;t++){
    for (int k=f;k<H_N;k+=64) yh[k] = ysel[((size_t)i*(L_N-1)+t)*H_N + k];
    __syncthreads();
    float lg = bias;
    #pragma unroll 4
    for (int k=0;k<H_N;k++) lg = fmaf(fcw[f*H_N+k], yh[k], lg);
    const int node = wrev[seq*L_N + t + 1];
    const float yt = y0[(size_t)node*F_N + f];
    A += yt * softplusf(-lg);
    B += (1.0f-yt) * softplusf(lg);
    Sy += yt;
    __syncthreads();
  }
  for (int off=32; off; off>>=1){
    A += __shfl_down(A,off); B += __shfl_down(B,off); Sy += __shfl_down(Sy,off);
  }
  if (f==0){ atomicAdd(&accum[1],A); atomicAdd(&accum[2],B); atomicAdd(&accum[3],Sy); }
}

__global__ void k_finalize(const float* __restrict__ accum, float* __restrict__ out){
  if (threadIdx.x==0 && blockIdx.x==0)
    out[(size_t)SEQ_N*H_N] = accum[1]/accum[3] + accum[2]/(float)(NSEL*(L_N-1)*F_N);
}

extern "C" void kernel_launch(void* const* d_in, const int* in_sizes, int n_in,
                              void* d_out, int out_size, void* d_ws, size_t ws_size,
                              hipStream_t stream)
{
  const float* x     = (const float*)d_in[0];
  const float* y0    = (const float*)d_in[1];
  const float* wih_f = (const float*)d_in[2];
  const float* whh_f = (const float*)d_in[3];
  const float* bih_f = (const float*)d_in[4];
  const float* bhh_f = (const float*)d_in[5];
  const float* wih_b = (const float*)d_in[6];
  const float* whh_b = (const float*)d_in[7];
  const float* bih_b = (const float*)d_in[8];
  const float* bhh_b = (const float*)d_in[9];
  const float* wih   = (const float*)d_in[10];
  const float* whh   = (const float*)d_in[11];
  const float* bih   = (const float*)d_in[12];
  const float* bhh   = (const float*)d_in[13];
  const float* fc_w  = (const float*)d_in[14];
  const float* fc_b  = (const float*)d_in[15];
  const int*   walks = (const int*)d_in[16];
  const int*   dstdeg= (const int*)d_in[17];
  const int*   ssidx = (const int*)d_in[18];
  (void)in_sizes; (void)n_in; (void)out_size; (void)ws_size;

  char* ws = (char*)d_ws;
  size_t off = 0;
  auto wsalloc = [&](size_t bytes)->void* {
    void* p = ws + off; off += (bytes + 255) & ~(size_t)255; return p;
  };
  int*   accum_i = (int*)wsalloc(16);
  float* accum_f = (float*)accum_i;
  int*   wrev   = (int*)  wsalloc(sizeof(int)  * SEQ_N * L_N);
  float* uwbuf  = (float*)wsalloc(sizeof(float)* SEQ_N * L_N * 2);
  unsigned short* pk_whhf = (unsigned short*)wsalloc(2u*24*4*64*8);
  unsigned short* pk_whhb = (unsigned short*)wsalloc(2u*24*4*64*8);
  unsigned short* pk_whh  = (unsigned short*)wsalloc(2u*24*4*64*8);
  unsigned short* pk_wih  = (unsigned short*)wsalloc(2u*24*12*64*8);
  float* ysel   = (float*)wsalloc(sizeof(float)* NSEL * (L_N-1) * H_N);

  hipMemsetAsync(accum_i, 0, 16, stream);
  k_precompute<<<SEQ_N/256, 256, 0, stream>>>(walks, dstdeg, wrev, uwbuf, accum_i);
  k_pack<<<(24*4*64*8+255)/256,  256, 0, stream>>>(whh_f, pk_whhf, H_N,   4);
  k_pack<<<(24*4*64*8+255)/256,  256, 0, stream>>>(whh_b, pk_whhb, H_N,   4);
  k_pack<<<(24*4*64*8+255)/256,  256, 0, stream>>>(whh,   pk_whh,  H_N,   4);
  k_pack<<<(24*12*64*8+255)/256, 256, 0, stream>>>(wih,   pk_wih,  DIN_N, 12);

  hipFuncSetAttribute(reinterpret_cast<const void*>(k_rum),
                      hipFuncAttributeMaxDynamicSharedMemorySize, SMEM_TOTAL);
  k_rum<<<SEQ_N/BSEQ, 512, SMEM_TOTAL, stream>>>(x,
      pk_whhf, pk_whhb, pk_whh, pk_wih,
      wih_f, bih_f, bhh_f,
      wih_b, bih_b, bhh_b,
      wih, bih, bhh,
      dstdeg, accum_i, ssidx, wrev, uwbuf,
      (float*)d_out, ysel);
  k_loss<<<NSEL, 64, 0, stream>>>(ysel, y0, wrev, ssidx, fc_w, fc_b, accum_f);
  k_finalize<<<1, 1, 0, stream>>>(accum_f, (float*)d_out);
}

// Round 3
// 2752.244 us; speedup vs baseline: 3.3554x; 1.2285x over previous
//
#include <hip/hip_runtime.h>
#include <hip/hip_bf16.h>

#define S_N 4
#define E_N 16384
#define SEQ_N (S_N*E_N)   // 65536
#define L_N 12
#define H_N 128
#define G_N 384           // 3*H
#define DIN_N 385
#define F_N 64
#define NSEL 100
#define BSEQ 16           // seqs per block (one MFMA M-tile)
#define TWO_PI_F 6.28318530717958647692f

typedef __attribute__((ext_vector_type(8))) short s16x8;
typedef __attribute__((ext_vector_type(4))) float f32x4;
#define MFMA(a,b,c) __builtin_amdgcn_mfma_f32_16x16x32_bf16(a,b,c,0,0,0)

// ---- shared memory layout (bytes) ----
#define SMEM_YF   0            // ushort [12][16][128] swizzled  (48 KB)
#define SMEM_YB   49152        // ushort [12][16][128] swizzled  (48 KB)
#define SMEM_GATE 98304        // float  [16][GSTR]              (24.25 KB)
#define GSTR 388
#define SMEM_GHN  123136       // float  [16][HSTR]              (8.25 KB)
#define HSTR 132
#define SMEM_HBF  131584       // ushort [16][128] swizzled      (4 KB)
#define SMEM_UW   135680       // float  [16][12][2]
#define SMEM_DEG  137216       // float  [16][12]
#define SMEM_NODE 137984       // int    [16][12]
#define SMEM_SELC 138752       // int    [16]
#define SMEM_SELI 138816       // int    [16][8]
#define SMEM_TOTAL 139392

static __device__ __forceinline__ float sigm(float x){ return 1.0f/(1.0f+__expf(-x)); }
static __device__ __forceinline__ float tanhfast(float x){ return 1.0f - 2.0f/(__expf(2.0f*x)+1.0f); }
static __device__ __forceinline__ float softplusf(float x){ return fmaxf(x,0.0f) + log1pf(__expf(-fabsf(x))); }
static __device__ __forceinline__ unsigned short f2bf(float f){
  unsigned int u = __float_as_uint(f);
  unsigned int r = (u + 0x7fffu + ((u>>16)&1u)) >> 16;
  return (unsigned short)r;
}
// swizzled byte offset of element (row s, col j) in a [16][128] bf16 A-tile
static __device__ __forceinline__ int swzByte(int s, int j){
  return s*256 + ((j<<1) ^ ((s&7)<<4));
}
static __device__ __forceinline__ void stH(char* base, int s, int j, float v){
  *(unsigned short*)(base + swzByte(s,j)) = f2bf(v);
}
// A-fragment read: lane holds row=lane&15, k=(lane>>4)*8+e  (16B, swizzle-matched)
static __device__ __forceinline__ s16x8 ldsA(const char* base, int lane, int kf){
  const int row = lane & 15;
  const int byte = row*256 + (((kf<<6) + ((lane>>4)<<4)) ^ ((row&7)<<4));
  return *(const s16x8*)(base + byte);
}

// ---------------- precompute: reversed walks, anonymized sin/cos, degree max ----------------
__global__ void k_precompute(const int* __restrict__ walks, const int* __restrict__ dstdeg,
                             int* __restrict__ wrev, float* __restrict__ uwbuf, int* __restrict__ degmax)
{
  const int q = blockIdx.x*blockDim.x + threadIdx.x;
  int wk[L_N], un[L_N];
  #pragma unroll
  for (int t=0;t<L_N;t++) wk[t] = walks[q*L_N+t];
  int ndist = 0;
  #pragma unroll
  for (int t=0;t<L_N;t++){
    int u = -1;
    for (int p=0;p<t;p++) if (wk[p]==wk[t]) { u = un[p]; break; }
    if (u < 0) u = ndist++;
    un[t] = u;
  }
  int dmax = 0;
  #pragma unroll
  for (int tr=0;tr<L_N;tr++){
    const int o = L_N-1-tr;             // reversed timeline
    const int node = wk[o];
    wrev[q*L_N+tr] = node;
    float ang = (float)un[o] * (TWO_PI_F/(float)L_N);
    uwbuf[2*(q*L_N+tr)+0] = __sinf(ang);
    uwbuf[2*(q*L_N+tr)+1] = __cosf(ang);
    dmax = max(dmax, dstdeg[node]);
  }
  for (int off=32; off; off>>=1) dmax = max(dmax, __shfl_down(dmax, off));
  if ((threadIdx.x & 63)==0) atomicMax(degmax, dmax);
}

// ---------------- pack weight W[384][Ksrc] (row-major, gate-major) into MFMA B-fragments ----------------
// frag elem layout: idx = ((nt*KF+kf)*64 + lane)*8 + e ; value = W[nt*16+(lane&15)][kf*32+(lane>>4)*8+e]
__global__ void k_pack(const float* __restrict__ W, unsigned short* __restrict__ dst, int Ksrc, int KF)
{
  int idx = blockIdx.x*256 + threadIdx.x;
  int total = 24*KF*64*8;
  if (idx >= total) return;
  int e = idx & 7, lane = (idx>>3)&63;
  int rem = idx>>9;
  int kf = rem % KF, nt = rem / KF;
  int n = nt*16 + (lane&15);
  int k = kf*32 + (lane>>4)*8 + e;
  dst[idx] = f2bf(W[(size_t)n*Ksrc + k]);
}

// ---------------- small-GRU phase (input dim 2 folded into acc init via VALU) ----------------
static __device__ __forceinline__ void small_gru_phase(
    char* smem, const unsigned short* __restrict__ pk,
    const float* __restrict__ wih2, const float* __restrict__ bih2, const float* __restrict__ bhh2,
    bool bwd, char* ySt, float* hreg, int tid)
{
  const int w = tid>>6, lane = tid&63, col = lane&15, krow = lane>>4;
  const int sg = tid>>7, j = tid&127;
  float* gateF = (float*)(smem + SMEM_GATE);
  float* ghnF  = (float*)(smem + SMEM_GHN);
  char*  hbf   = smem + SMEM_HBF;
  const float* uwF = (const float*)(smem + SMEM_UW);

  s16x8 bw[3][4];
  int n0[3]; bool isN[3]; float cA[3], cB2[3], wsv[3], wcv[3];
  #pragma unroll
  for (int i=0;i<3;i++){
    n0[i] = w*48 + i*16; isN[i] = (n0[i] >= 256);
    int g = n0[i] + col;
    wsv[i] = wih2[g*2]; wcv[i] = wih2[g*2+1];
    if (isN[i]){ cA[i] = bih2[g]; cB2[i] = bhh2[g]; }
    else { cA[i] = bih2[g] + bhh2[g]; cB2[i] = 0.0f; }
    #pragma unroll
    for (int kf=0;kf<4;kf++)
      bw[i][kf] = *(const s16x8*)(pk + (size_t)(((w*3+i)*4 + kf)*64 + lane)*8);
  }

  for (int st=0; st<L_N; ++st){
    const int o = bwd ? (L_N-1-st) : st;
    float sn[4], cs[4];
    #pragma unroll
    for (int q=0;q<4;q++){
      int s = krow*4+q;
      sn[q] = uwF[(s*L_N+o)*2+0]; cs[q] = uwF[(s*L_N+o)*2+1];
    }
    s16x8 a0 = ldsA(hbf,lane,0), a1 = ldsA(hbf,lane,1), a2 = ldsA(hbf,lane,2), a3 = ldsA(hbf,lane,3);
    #pragma unroll
    for (int i=0;i<3;i++){
      f32x4 acc;
      #pragma unroll
      for (int q=0;q<4;q++)
        acc[q] = isN[i] ? cB2[i] : (cA[i] + wsv[i]*sn[q] + wcv[i]*cs[q]);
      acc = MFMA(a0,bw[i][0],acc); acc = MFMA(a1,bw[i][1],acc);
      acc = MFMA(a2,bw[i][2],acc); acc = MFMA(a3,bw[i][3],acc);
      #pragma unroll
      for (int q=0;q<4;q++){
        int row = krow*4+q;
        if (!isN[i]) gateF[row*GSTR + n0[i]+col] = acc[q];
        else {
          gateF[row*GSTR + n0[i]+col] = cA[i] + wsv[i]*sn[q] + wcv[i]*cs[q];
          ghnF [row*HSTR + n0[i]-256+col] = acc[q];
        }
      }
    }
    __syncthreads();
    #pragma unroll
    for (int q=0;q<4;q++){
      int s = sg*4+q;
      float r = sigm(gateF[s*GSTR + j]);
      float z = sigm(gateF[s*GSTR + 128 + j]);
      float n = tanhfast(fmaf(r, ghnF[s*HSTR + j], gateF[s*GSTR + 256 + j]));
      float h = (1.0f - z)*n + z*hreg[q];
      hreg[q] = h;
      stH(hbf, s, j, h);
      *(unsigned short*)(ySt + st*4096 + swzByte(s,j)) = f2bf(h);
    }
    __syncthreads();
  }
}

// ---------------- fused 3-GRU kernel, MFMA ----------------
__global__ __launch_bounds__(512, 2) void k_rum(
    const float* __restrict__ x,
    const unsigned short* __restrict__ pk_whhf, const unsigned short* __restrict__ pk_whhb,
    const unsigned short* __restrict__ pk_whh,  const unsigned short* __restrict__ pk_wih,
    const float* __restrict__ wihf, const float* __restrict__ bihf, const float* __restrict__ bhhf,
    const float* __restrict__ wihb, const float* __restrict__ bihb, const float* __restrict__ bhhb,
    const float* __restrict__ wih,  const float* __restrict__ bih,  const float* __restrict__ bhh,
    const int* __restrict__ dstdeg, const int* __restrict__ degmax,
    const int* __restrict__ ssidx,
    const int* __restrict__ wrev, const float* __restrict__ uwbuf,
    float* __restrict__ out, float* __restrict__ ysel)
{
  extern __shared__ char smem[];
  float* gateF = (float*)(smem + SMEM_GATE);
  float* ghnF  = (float*)(smem + SMEM_GHN);
  char*  hbf   = smem + SMEM_HBF;
  float* uwF   = (float*)(smem + SMEM_UW);
  float* degL  = (float*)(smem + SMEM_DEG);
  int*   nodeL = (int*)(smem + SMEM_NODE);
  int*   selC  = (int*)(smem + SMEM_SELC);
  int*   selI  = (int*)(smem + SMEM_SELI);

  const int tid = threadIdx.x;
  const int w = tid>>6, lane = tid&63, col = lane&15, krow = lane>>4;
  const int sg = tid>>7, j = tid&127;
  const int seq0 = blockIdx.x*BSEQ;

  if (tid < BSEQ) selC[tid] = 0;
  __syncthreads();

  // stage nodes + uw; register selected seqs; zero h_bf16
  for (int p = tid; p < BSEQ*L_N; p += 512){
    nodeL[p] = wrev[(size_t)seq0*L_N + p];
    uwF[2*p+0] = uwbuf[2*((size_t)seq0*L_N + p)+0];
    uwF[2*p+1] = uwbuf[2*((size_t)seq0*L_N + p)+1];
  }
  if (tid < NSEL){
    int e = ssidx[tid];
    int d = e - seq0;
    if (d >= 0 && d < BSEQ){
      int slot = atomicAdd(&selC[d], 1);
      if (slot < 8) selI[d*8+slot] = tid;
    }
  }
  #pragma unroll
  for (int q=0;q<4;q++) stH(hbf, sg*4+q, j, 0.0f);
  __syncthreads();
  const float dmaxf = (float)(*degmax);
  for (int p = tid; p < BSEQ*L_N; p += 512)
    degL[p] = (float)dstdeg[nodeL[p]] / dmaxf;
  __syncthreads();

  float hreg[4] = {0.f,0.f,0.f,0.f};

  // ===== backward small GRU (original timeline), history -> yb_st[tau] =====
  small_gru_phase(smem, pk_whhb, wihb, bihb, bhhb, true,  smem+SMEM_YB, hreg, tid);
  float hb[4];
  #pragma unroll
  for (int q=0;q<4;q++){ hb[q]=hreg[q]; hreg[q]=0.f; stH(hbf, sg*4+q, j, 0.f); }
  __syncthreads();
  // ===== forward small GRU (reversed timeline), history -> yf_st[t] =====
  small_gru_phase(smem, pk_whhf, wihf, bihf, bhhf, false, smem+SMEM_YF, hreg, tid);
  #pragma unroll
  for (int q=0;q<4;q++){ hreg[q] = 0.5f*(hreg[q]+hb[q]); stH(hbf, sg*4+q, j, hreg[q]); }
  __syncthreads();

  // ===== main GRU =====
  int n0[3]; bool isN[3]; float cRZ[3], cI[3], cRn[3], wd[3];
  #pragma unroll
  for (int i=0;i<3;i++){
    n0[i] = w*48 + i*16; isN[i] = (n0[i] >= 256);
    int g = n0[i] + col;
    wd[i] = wih[(size_t)g*DIN_N + 384];
    if (isN[i]){ cI[i] = bih[g]; cRn[i] = bhh[g]; cRZ[i]=0.f; }
    else { cRZ[i] = bih[g] + bhh[g]; cI[i]=0.f; cRn[i]=0.f; }
  }

  // 6 chunks x 2 steps: input GEMM into registers (STATIC indexing only), then scan.
  #pragma unroll 1
  for (int chunk=0; chunk<6; chunk++){
    const int T0 = chunk*2;
    f32x4 gi0[3], gi1[3];   // gi[i][tt] with tt in {0,1} as separate named arrays
    #pragma unroll
    for (int i=0;i<3;i++){
      const float base = isN[i] ? cI[i] : cRZ[i];
      #pragma unroll
      for (int q=0;q<4;q++){
        gi0[i][q] = base + wd[i]*degL[(krow*4+q)*L_N + T0+0];
        gi1[i][q] = base + wd[i]*degL[(krow*4+q)*L_N + T0+1];
      }
    }
    // ---- x segment (kf 0..3): gather from global, f32->bf16 in flight ----
    {
      const float* xb0 = x + (size_t)nodeL[col*L_N + T0+0]*H_N + krow*8;
      const float* xb1 = x + (size_t)nodeL[col*L_N + T0+1]*H_N + krow*8;
      #pragma unroll
      for (int kf=0;kf<4;kf++){
        s16x8 a0v, a1v;
        {
          float4 u0 = *(const float4*)(xb0 + kf*32);
          float4 u1 = *(const float4*)(xb0 + kf*32 + 4);
          a0v[0]=(short)f2bf(u0.x); a0v[1]=(short)f2bf(u0.y); a0v[2]=(short)f2bf(u0.z); a0v[3]=(short)f2bf(u0.w);
          a0v[4]=(short)f2bf(u1.x); a0v[5]=(short)f2bf(u1.y); a0v[6]=(short)f2bf(u1.z); a0v[7]=(short)f2bf(u1.w);
        }
        {
          float4 u0 = *(const float4*)(xb1 + kf*32);
          float4 u1 = *(const float4*)(xb1 + kf*32 + 4);
          a1v[0]=(short)f2bf(u0.x); a1v[1]=(short)f2bf(u0.y); a1v[2]=(short)f2bf(u0.z); a1v[3]=(short)f2bf(u0.w);
          a1v[4]=(short)f2bf(u1.x); a1v[5]=(short)f2bf(u1.y); a1v[6]=(short)f2bf(u1.z); a1v[7]=(short)f2bf(u1.w);
        }
        #pragma unroll
        for (int i=0;i<3;i++){
          s16x8 b = *(const s16x8*)(pk_wih + (size_t)(((w*3+i)*12 + kf)*64 + lane)*8);
          gi0[i] = MFMA(a0v, b, gi0[i]);
          gi1[i] = MFMA(a1v, b, gi1[i]);
        }
      }
    }
    // ---- yf segment (kf 4..7): LDS A-frags ----
    #pragma unroll
    for (int kf=0;kf<4;kf++){
      s16x8 a0v = ldsA(smem + SMEM_YF + (T0+0)*4096, lane, kf);
      s16x8 a1v = ldsA(smem + SMEM_YF + (T0+1)*4096, lane, kf);
      #pragma unroll
      for (int i=0;i<3;i++){
        s16x8 b = *(const s16x8*)(pk_wih + (size_t)(((w*3+i)*12 + kf+4)*64 + lane)*8);
        gi0[i] = MFMA(a0v, b, gi0[i]);
        gi1[i] = MFMA(a1v, b, gi1[i]);
      }
    }
    // ---- yb segment (kf 8..11): LDS A-frags, reversed timeline ----
    #pragma unroll
    for (int kf=0;kf<4;kf++){
      s16x8 a0v = ldsA(smem + SMEM_YB + (L_N-1-(T0+0))*4096, lane, kf);
      s16x8 a1v = ldsA(smem + SMEM_YB + (L_N-1-(T0+1))*4096, lane, kf);
      #pragma unroll
      for (int i=0;i<3;i++){
        s16x8 b = *(const s16x8*)(pk_wih + (size_t)(((w*3+i)*12 + kf+8)*64 + lane)*8);
        gi0[i] = MFMA(a0v, b, gi0[i]);
        gi1[i] = MFMA(a1v, b, gi1[i]);
      }
    }
    // ---- recurrent weights for the scan (L2-hot reload per chunk keeps them
    //      out of the input-GEMM live range) ----
    s16x8 bm[3][4];
    #pragma unroll
    for (int i=0;i<3;i++)
      #pragma unroll
      for (int kf=0;kf<4;kf++)
        bm[i][kf] = *(const s16x8*)(pk_whh + (size_t)(((w*3+i)*4 + kf)*64 + lane)*8);

    // ---- recurrent scan over the 2 steps, FULLY UNROLLED (static gi indices) ----
    #pragma unroll
    for (int tt=0; tt<2; ++tt){
      const int t = T0+tt;
      s16x8 a0 = ldsA(hbf,lane,0), a1 = ldsA(hbf,lane,1), a2 = ldsA(hbf,lane,2), a3 = ldsA(hbf,lane,3);
      #pragma unroll
      for (int i=0;i<3;i++){
        const f32x4 giv = (tt==0) ? gi0[i] : gi1[i];
        f32x4 acc;
        if (!isN[i]) acc = giv;
        else { acc[0]=cRn[i]; acc[1]=cRn[i]; acc[2]=cRn[i]; acc[3]=cRn[i]; }
        acc = MFMA(a0,bm[i][0],acc); acc = MFMA(a1,bm[i][1],acc);
        acc = MFMA(a2,bm[i][2],acc); acc = MFMA(a3,bm[i][3],acc);
        #pragma unroll
        for (int q=0;q<4;q++){
          int row = krow*4+q;
          if (!isN[i]) gateF[row*GSTR + n0[i]+col] = acc[q];
          else {
            gateF[row*GSTR + n0[i]+col] = giv[q];
            ghnF [row*HSTR + n0[i]-256+col] = acc[q];
          }
        }
      }
      __syncthreads();
      #pragma unroll
      for (int q=0;q<4;q++){
        int s = sg*4+q;
        float r = sigm(gateF[s*GSTR + j]);
        float z = sigm(gateF[s*GSTR + 128 + j]);
        float n = tanhfast(fmaf(r, ghnF[s*HSTR + j], gateF[s*GSTR + 256 + j]));
        float h = (1.0f - z)*n + z*hreg[q];
        hreg[q] = h;
        stH(hbf, s, j, h);
        if (t < L_N-1){
          int c = selC[s]; if (c > 8) c = 8;
          for (int m=0;m<c;m++)
            ysel[((size_t)selI[s*8+m]*(L_N-1) + t)*H_N + j] = h;
        } else {
          out[(size_t)(seq0+s)*H_N + j] = h;
        }
      }
      __syncthreads();
    }
  }
}

// ---------------- loss over 100 selected sequences ----------------
__global__ __launch_bounds__(64) void k_loss(
    const float* __restrict__ ysel, const float* __restrict__ y0,
    const int* __restrict__ wrev, const int* __restrict__ ssidx,
    const float* __restrict__ fcw, const float* __restrict__ fcb,
    float* __restrict__ accum)
{
  const int i = blockIdx.x;
  const int f = threadIdx.x;
  __shared__ float yh[H_N];
  const int seq = ssidx[i];
  float A=0.0f, B=0.0f, Sy=0.0f;
  const float bias = fcb[f];
  for (int t=0;t<L_N-1;t++){
    for (int k=f;k<H_N;k+=64) yh[k] = ysel[((size_t)i*(L_N-1)+t)*H_N + k];
    __syncthreads();
    float lg = bias;
    #pragma unroll 4
    for (int k=0;k<H_N;k++) lg = fmaf(fcw[f*H_N+k], yh[k], lg);
    const int node = wrev[seq*L_N + t + 1];
    const float yt = y0[(size_t)node*F_N + f];
    A += yt * softplusf(-lg);
    B += (1.0f-yt) * softplusf(lg);
    Sy += yt;
    __syncthreads();
  }
  for (int off=32; off; off>>=1){
    A += __shfl_down(A,off); B += __shfl_down(B,off); Sy += __shfl_down(Sy,off);
  }
  if (f==0){ atomicAdd(&accum[1],A); atomicAdd(&accum[2],B); atomicAdd(&accum[3],Sy); }
}

__global__ void k_finalize(const float* __restrict__ accum, float* __restrict__ out){
  if (threadIdx.x==0 && blockIdx.x==0)
    out[(size_t)SEQ_N*H_N] = accum[1]/accum[3] + accum[2]/(float)(NSEL*(L_N-1)*F_N);
}

extern "C" void kernel_launch(void* const* d_in, const int* in_sizes, int n_in,
                              void* d_out, int out_size, void* d_ws, size_t ws_size,
                              hipStream_t stream)
{
  const float* x     = (const float*)d_in[0];
  const float* y0    = (const float*)d_in[1];
  const float* wih_f = (const float*)d_in[2];
  const float* whh_f = (const float*)d_in[3];
  const float* bih_f = (const float*)d_in[4];
  const float* bhh_f = (const float*)d_in[5];
  const float* wih_b = (const float*)d_in[6];
  const float* whh_b = (const float*)d_in[7];
  const float* bih_b = (const float*)d_in[8];
  const float* bhh_b = (const float*)d_in[9];
  const float* wih   = (const float*)d_in[10];
  const float* whh   = (const float*)d_in[11];
  const float* bih   = (const float*)d_in[12];
  const float* bhh   = (const float*)d_in[13];
  const float* fc_w  = (const float*)d_in[14];
  const float* fc_b  = (const float*)d_in[15];
  const int*   walks = (const int*)d_in[16];
  const int*   dstdeg= (const int*)d_in[17];
  const int*   ssidx = (const int*)d_in[18];
  (void)in_sizes; (void)n_in; (void)out_size; (void)ws_size;

  char* ws = (char*)d_ws;
  size_t off = 0;
  auto wsalloc = [&](size_t bytes)->void* {
    void* p = ws + off; off += (bytes + 255) & ~(size_t)255; return p;
  };
  int*   accum_i = (int*)wsalloc(16);
  float* accum_f = (float*)accum_i;
  int*   wrev   = (int*)  wsalloc(sizeof(int)  * SEQ_N * L_N);
  float* uwbuf  = (float*)wsalloc(sizeof(float)* SEQ_N * L_N * 2);
  unsigned short* pk_whhf = (unsigned short*)wsalloc(2u*24*4*64*8);
  unsigned short* pk_whhb = (unsigned short*)wsalloc(2u*24*4*64*8);
  unsigned short* pk_whh  = (unsigned short*)wsalloc(2u*24*4*64*8);
  unsigned short* pk_wih  = (unsigned short*)wsalloc(2u*24*12*64*8);
  float* ysel   = (float*)wsalloc(sizeof(float)* NSEL * (L_N-1) * H_N);

  hipMemsetAsync(accum_i, 0, 16, stream);
  k_precompute<<<SEQ_N/256, 256, 0, stream>>>(walks, dstdeg, wrev, uwbuf, accum_i);
  k_pack<<<(24*4*64*8+255)/256,  256, 0, stream>>>(whh_f, pk_whhf, H_N,   4);
  k_pack<<<(24*4*64*8+255)/256,  256, 0, stream>>>(whh_b, pk_whhb, H_N,   4);
  k_pack<<<(24*4*64*8+255)/256,  256, 0, stream>>>(whh,   pk_whh,  H_N,   4);
  k_pack<<<(24*12*64*8+255)/256, 256, 0, stream>>>(wih,   pk_wih,  DIN_N, 12);

  hipFuncSetAttribute(reinterpret_cast<const void*>(k_rum),
                      hipFuncAttributeMaxDynamicSharedMemorySize, SMEM_TOTAL);
  k_rum<<<SEQ_N/BSEQ, 512, SMEM_TOTAL, stream>>>(x,
      pk_whhf, pk_whhb, pk_whh, pk_wih,
      wih_f, bih_f, bhh_f,
      wih_b, bih_b, bhh_b,
      wih, bih, bhh,
      dstdeg, accum_i, ssidx, wrev, uwbuf,
      (float*)d_out, ysel);
  k_loss<<<NSEL, 64, 0, stream>>>(ysel, y0, wrev, ssidx, fc_w, fc_b, accum_f);
  k_finalize<<<1, 1, 0, stream>>>(accum_f, (float*)d_out);
}

// Round 4
// 1094.304 us; speedup vs baseline: 8.4390x; 2.5151x over previous
//
#include <hip/hip_runtime.h>
#include <hip/hip_bf16.h>

#define S_N 4
#define E_N 16384
#define SEQ_N (S_N*E_N)   // 65536
#define L_N 12
#define H_N 128
#define G_N 384           // 3*H
#define DIN_N 385
#define F_N 64
#define N_NODES 50000
#define NSEL 100
#define BSEQ 16           // seqs per block (one MFMA M-tile)
#define TWO_PI_F 6.28318530717958647692f

typedef __attribute__((ext_vector_type(8))) short s16x8;
typedef __attribute__((ext_vector_type(4))) float f32x4;
#define MFMA(a,b,c) __builtin_amdgcn_mfma_f32_16x16x32_bf16(a,b,c,0,0,0)

// ---- shared memory layout (bytes) ----
#define SMEM_YF   0            // ushort [12][16][128] swizzled  (48 KB)
#define SMEM_YB   49152        // ushort [12][16][128] swizzled  (48 KB)
#define SMEM_HBF  98304        // ushort [2][16][128] swizzled   (8 KB, double-buffered h)
#define SMEM_UW   106496       // float  [12][16][2]  (1536 B)
#define SMEM_DEG  108032       // float  [12][16]     (768 B)
#define SMEM_NODE 108800       // int    [16][12]     (768 B)
#define SMEM_SELC 109568       // int    [16]
#define SMEM_SELI 109632       // int    [16][8]
#define SMEM_TOTAL 110144

static __device__ __forceinline__ float sigm(float x){ return 1.0f/(1.0f+__expf(-x)); }
static __device__ __forceinline__ float tanhfast(float x){ return 1.0f - 2.0f/(__expf(2.0f*x)+1.0f); }
static __device__ __forceinline__ float softplusf(float x){ return fmaxf(x,0.0f) + log1pf(__expf(-fabsf(x))); }
static __device__ __forceinline__ unsigned short f2bf(float f){
  unsigned int u = __float_as_uint(f);
  unsigned int r = (u + 0x7fffu + ((u>>16)&1u)) >> 16;
  return (unsigned short)r;
}
static __device__ __forceinline__ float bf2f(unsigned short u){ return __uint_as_float(((unsigned int)u)<<16); }
// swizzled byte offset of element (row s, col j) in a [16][128] bf16 A-tile
static __device__ __forceinline__ int swzByte(int s, int j){
  return s*256 + ((j<<1) ^ ((s&7)<<4));
}
// A-fragment read: lane holds row=lane&15, k=(lane>>4)*8+e  (16B, swizzle-matched)
static __device__ __forceinline__ s16x8 ldsA(const char* base, int lane, int kf){
  const int row = lane & 15;
  const int byte = row*256 + (((kf<<6) + ((lane>>4)<<4)) ^ ((row&7)<<4));
  return *(const s16x8*)(base + byte);
}
static __device__ __forceinline__ s16x8 pack8(float4 u0, float4 u1){
  s16x8 v;
  v[0]=(short)f2bf(u0.x); v[1]=(short)f2bf(u0.y); v[2]=(short)f2bf(u0.z); v[3]=(short)f2bf(u0.w);
  v[4]=(short)f2bf(u1.x); v[5]=(short)f2bf(u1.y); v[6]=(short)f2bf(u1.z); v[7]=(short)f2bf(u1.w);
  return v;
}

// ---------------- precompute: reversed walks, anonymized sin/cos, degree max ----------------
__global__ void k_precompute(const int* __restrict__ walks, const int* __restrict__ dstdeg,
                             int* __restrict__ wrev, float* __restrict__ uwbuf, int* __restrict__ degmax)
{
  const int q = blockIdx.x*blockDim.x + threadIdx.x;
  int wk[L_N], un[L_N];
  #pragma unroll
  for (int t=0;t<L_N;t++) wk[t] = walks[q*L_N+t];
  int ndist = 0;
  #pragma unroll
  for (int t=0;t<L_N;t++){
    int u = -1;
    for (int p=0;p<t;p++) if (wk[p]==wk[t]) { u = un[p]; break; }
    if (u < 0) u = ndist++;
    un[t] = u;
  }
  int dmax = 0;
  #pragma unroll
  for (int tr=0;tr<L_N;tr++){
    const int o = L_N-1-tr;             // reversed timeline
    const int node = wk[o];
    wrev[q*L_N+tr] = node;
    float ang = (float)un[o] * (TWO_PI_F/(float)L_N);
    uwbuf[2*(q*L_N+tr)+0] = __sinf(ang);
    uwbuf[2*(q*L_N+tr)+1] = __cosf(ang);
    dmax = max(dmax, dstdeg[node]);
  }
  for (int off=32; off; off>>=1) dmax = max(dmax, __shfl_down(dmax, off));
  if ((threadIdx.x & 63)==0) atomicMax(degmax, dmax);
}

// ---------------- pack weight W[384][Ksrc] (row-major, gate-major) into MFMA B-fragments ----------------
// frag elem layout: idx = ((nt*KF+kf)*64 + lane)*8 + e ; value = W[nt*16+(lane&15)][kf*32+(lane>>4)*8+e]
__global__ void k_pack(const float* __restrict__ W, unsigned short* __restrict__ dst, int Ksrc, int KF)
{
  int idx = blockIdx.x*256 + threadIdx.x;
  int total = 24*KF*64*8;
  if (idx >= total) return;
  int e = idx & 7, lane = (idx>>3)&63;
  int rem = idx>>9;
  int kf = rem % KF, nt = rem / KF;
  int n = nt*16 + (lane&15);
  int k = kf*32 + (lane>>4)*8 + e;
  dst[idx] = f2bf(W[(size_t)n*Ksrc + k]);
}

// ---------------- gx = x @ Wih_x^T per node (bf16 out), M=50000, N=384, K=128 ----------------
__global__ __launch_bounds__(512) void k_gx(const float* __restrict__ x,
                                            const unsigned short* __restrict__ pk_wih,
                                            unsigned short* __restrict__ gx)
{
  const int tid = threadIdx.x;
  const int w = tid>>6, lane = tid&63, col = lane&15, krow = lane>>4;
  const int m0 = blockIdx.x*16;
  s16x8 a[4];
  #pragma unroll
  for (int kf=0;kf<4;kf++){
    const float* xp = x + (size_t)(m0+col)*H_N + kf*32 + krow*8;
    a[kf] = pack8(*(const float4*)xp, *(const float4*)(xp+4));
  }
  #pragma unroll
  for (int i=0;i<3;i++){
    f32x4 acc; acc[0]=0.f; acc[1]=0.f; acc[2]=0.f; acc[3]=0.f;
    #pragma unroll
    for (int kf=0;kf<4;kf++){
      s16x8 b = *(const s16x8*)(pk_wih + (size_t)(((i*8+w)*12 + kf)*64 + lane)*8);
      acc = MFMA(a[kf], b, acc);
    }
    #pragma unroll
    for (int q=0;q<4;q++)
      gx[(size_t)(m0 + krow*4+q)*G_N + i*128 + w*16 + col] = f2bf(acc[q]);
  }
}

// ---------------- small-GRU phase: gate-triple per wave, lane-local nonlinearity ----------------
static __device__ __forceinline__ void small_gru_phase(
    char* smem, const unsigned short* __restrict__ pk,
    const float* __restrict__ wih2, const float* __restrict__ bih2, const float* __restrict__ bhh2,
    bool bwd, char* ySt, float* hreg, int tid)
{
  const int w = tid>>6, lane = tid&63, col = lane&15, krow = lane>>4;
  const int unit = w*16 + col;
  char* hbf = smem + SMEM_HBF;
  const float* uwF = (const float*)(smem + SMEM_UW);

  const float cR  = bih2[unit]     + bhh2[unit];
  const float cZ  = bih2[128+unit] + bhh2[128+unit];
  const float cNI = bih2[256+unit];
  const float cNH = bhh2[256+unit];
  const float wsr = wih2[unit*2],       wcr = wih2[unit*2+1];
  const float wsz = wih2[(128+unit)*2], wcz = wih2[(128+unit)*2+1];
  const float wsn = wih2[(256+unit)*2], wcn = wih2[(256+unit)*2+1];

  s16x8 bw[3][4];
  #pragma unroll
  for (int i=0;i<3;i++)
    #pragma unroll
    for (int kf=0;kf<4;kf++)
      bw[i][kf] = *(const s16x8*)(pk + (size_t)(((i*8+w)*4 + kf)*64 + lane)*8);

  #pragma unroll 1
  for (int st=0; st<L_N; ++st){
    const int o = bwd ? (L_N-1-st) : st;
    const char* hr = hbf + (st&1)*4096;
    char*       hw = hbf + ((st+1)&1)*4096;
    float sn[4], cs[4];
    #pragma unroll
    for (int q=0;q<4;q++){
      int row = krow*4+q;
      sn[q] = uwF[(o*16+row)*2+0]; cs[q] = uwF[(o*16+row)*2+1];
    }
    s16x8 a0 = ldsA(hr,lane,0), a1 = ldsA(hr,lane,1), a2 = ldsA(hr,lane,2), a3 = ldsA(hr,lane,3);
    f32x4 aR, aZ, aNH;
    #pragma unroll
    for (int q=0;q<4;q++){
      aR[q]  = cR + wsr*sn[q] + wcr*cs[q];
      aZ[q]  = cZ + wsz*sn[q] + wcz*cs[q];
      aNH[q] = cNH;
    }
    aR  = MFMA(a0,bw[0][0],aR);  aR  = MFMA(a1,bw[0][1],aR);  aR  = MFMA(a2,bw[0][2],aR);  aR  = MFMA(a3,bw[0][3],aR);
    aZ  = MFMA(a0,bw[1][0],aZ);  aZ  = MFMA(a1,bw[1][1],aZ);  aZ  = MFMA(a2,bw[1][2],aZ);  aZ  = MFMA(a3,bw[1][3],aZ);
    aNH = MFMA(a0,bw[2][0],aNH); aNH = MFMA(a1,bw[2][1],aNH); aNH = MFMA(a2,bw[2][2],aNH); aNH = MFMA(a3,bw[2][3],aNH);
    #pragma unroll
    for (int q=0;q<4;q++){
      int row = krow*4+q;
      float r = sigm(aR[q]), z = sigm(aZ[q]);
      float ni = cNI + wsn*sn[q] + wcn*cs[q];
      float n = tanhfast(fmaf(r, aNH[q], ni));
      float h = (1.0f - z)*n + z*hreg[q];
      hreg[q] = h;
      unsigned short hb16 = f2bf(h);
      *(unsigned short*)(hw + swzByte(row,unit)) = hb16;
      *(unsigned short*)(ySt + st*4096 + swzByte(row,unit)) = hb16;
    }
    __syncthreads();
  }
}

// ---------------- fused 3-GRU kernel, MFMA, single barrier per step ----------------
__global__ __launch_bounds__(512, 2) void k_rum(
    const unsigned short* __restrict__ gx,
    const unsigned short* __restrict__ pk_whhf, const unsigned short* __restrict__ pk_whhb,
    const unsigned short* __restrict__ pk_whh,  const unsigned short* __restrict__ pk_wih,
    const float* __restrict__ wihf, const float* __restrict__ bihf, const float* __restrict__ bhhf,
    const float* __restrict__ wihb, const float* __restrict__ bihb, const float* __restrict__ bhhb,
    const float* __restrict__ wih,  const float* __restrict__ bih,  const float* __restrict__ bhh,
    const int* __restrict__ dstdeg, const int* __restrict__ degmax,
    const int* __restrict__ ssidx,
    const int* __restrict__ wrev, const float* __restrict__ uwbuf,
    float* __restrict__ out, float* __restrict__ ysel)
{
  extern __shared__ char smem[];
  char*  hbf   = smem + SMEM_HBF;
  float* uwF   = (float*)(smem + SMEM_UW);
  float* degL  = (float*)(smem + SMEM_DEG);
  int*   nodeL = (int*)(smem + SMEM_NODE);
  int*   selC  = (int*)(smem + SMEM_SELC);
  int*   selI  = (int*)(smem + SMEM_SELI);

  const int tid = threadIdx.x;
  const int w = tid>>6, lane = tid&63, col = lane&15, krow = lane>>4;
  const int unit = w*16 + col;
  const int seq0 = blockIdx.x*BSEQ;

  if (tid < BSEQ) selC[tid] = 0;
  __syncthreads();

  // stage nodes + uw + deg; register selected seqs; zero h buffer 0
  for (int p = tid; p < BSEQ*L_N; p += 512){
    int si = p / L_N, t = p - si*L_N;
    nodeL[p] = wrev[(size_t)seq0*L_N + p];
    uwF[(t*16+si)*2+0] = uwbuf[2*((size_t)seq0*L_N + p)+0];
    uwF[(t*16+si)*2+1] = uwbuf[2*((size_t)seq0*L_N + p)+1];
  }
  if (tid < NSEL){
    int e = ssidx[tid];
    int d = e - seq0;
    if (d >= 0 && d < BSEQ){
      int slot = atomicAdd(&selC[d], 1);
      if (slot < 8) selI[d*8+slot] = tid;
    }
  }
  #pragma unroll
  for (int q=0;q<4;q++)
    *(unsigned short*)(hbf + swzByte(krow*4+q, unit)) = 0;
  __syncthreads();
  const float dmaxf = (float)(*degmax);
  for (int p = tid; p < BSEQ*L_N; p += 512){
    int si = p / L_N, t = p - si*L_N;
    degL[t*16+si] = (float)dstdeg[nodeL[p]] / dmaxf;
  }
  __syncthreads();

  float hreg[4] = {0.f,0.f,0.f,0.f};

  // ===== backward small GRU (original timeline), history -> yb_st[tau] =====
  small_gru_phase(smem, pk_whhb, wihb, bihb, bhhb, true,  smem+SMEM_YB, hreg, tid);
  float hb[4];
  #pragma unroll
  for (int q=0;q<4;q++){
    hb[q]=hreg[q]; hreg[q]=0.f;
    *(unsigned short*)(hbf + swzByte(krow*4+q, unit)) = 0;
  }
  __syncthreads();
  // ===== forward small GRU (reversed timeline), history -> yf_st[t] =====
  small_gru_phase(smem, pk_whhf, wihf, bihf, bhhf, false, smem+SMEM_YF, hreg, tid);
  #pragma unroll
  for (int q=0;q<4;q++){
    hreg[q] = 0.5f*(hreg[q]+hb[q]);
    *(unsigned short*)(hbf + swzByte(krow*4+q, unit)) = f2bf(hreg[q]);
  }
  __syncthreads();

  // ===== main GRU =====
  const float cR  = bih[unit]     + bhh[unit];
  const float cZ  = bih[128+unit] + bhh[128+unit];
  const float cNI = bih[256+unit];
  const float cNH = bhh[256+unit];
  const float wdr = wih[(size_t)(unit)*DIN_N     + 384];
  const float wdz = wih[(size_t)(128+unit)*DIN_N + 384];
  const float wdn = wih[(size_t)(256+unit)*DIN_N + 384];

  // resident weight fragments: yf-seg (kf4..7), yb-seg (kf8..11), whh (kf0..3)
  s16x8 byf[3][4], byb[3][4], bhw[3][4];
  #pragma unroll
  for (int i=0;i<3;i++){
    #pragma unroll
    for (int kf=0;kf<4;kf++){
      byf[i][kf] = *(const s16x8*)(pk_wih + (size_t)(((i*8+w)*12 + 4+kf)*64 + lane)*8);
      byb[i][kf] = *(const s16x8*)(pk_wih + (size_t)(((i*8+w)*12 + 8+kf)*64 + lane)*8);
      bhw[i][kf] = *(const s16x8*)(pk_whh + (size_t)(((i*8+w)*4  +   kf)*64 + lane)*8);
    }
  }

  // prologue: prefetch gx for t=0
  unsigned short gxu[3][4];
  #pragma unroll
  for (int q=0;q<4;q++){
    const size_t nb = (size_t)nodeL[(krow*4+q)*L_N + 0]*G_N + unit;
    gxu[0][q] = gx[nb]; gxu[1][q] = gx[nb+128]; gxu[2][q] = gx[nb+256];
  }

  #pragma unroll 1
  for (int t=0; t<L_N; ++t){
    const char* hr = hbf + (t&1)*4096;
    char*       hw = hbf + ((t+1)&1)*4096;
    f32x4 aR, aZ, aNI, aNH;
    #pragma unroll
    for (int q=0;q<4;q++){
      const float dg = degL[t*16 + krow*4+q];
      aR[q]  = cR  + wdr*dg + bf2f(gxu[0][q]);
      aZ[q]  = cZ  + wdz*dg + bf2f(gxu[1][q]);
      aNI[q] = cNI + wdn*dg + bf2f(gxu[2][q]);
      aNH[q] = cNH;
    }
    if (t+1 < L_N){
      #pragma unroll
      for (int q=0;q<4;q++){
        const size_t nb = (size_t)nodeL[(krow*4+q)*L_N + t+1]*G_N + unit;
        gxu[0][q] = gx[nb]; gxu[1][q] = gx[nb+128]; gxu[2][q] = gx[nb+256];
      }
    }
    // recurrent term
    {
      s16x8 a0 = ldsA(hr,lane,0), a1 = ldsA(hr,lane,1), a2 = ldsA(hr,lane,2), a3 = ldsA(hr,lane,3);
      aR  = MFMA(a0,bhw[0][0],aR);  aR  = MFMA(a1,bhw[0][1],aR);  aR  = MFMA(a2,bhw[0][2],aR);  aR  = MFMA(a3,bhw[0][3],aR);
      aZ  = MFMA(a0,bhw[1][0],aZ);  aZ  = MFMA(a1,bhw[1][1],aZ);  aZ  = MFMA(a2,bhw[1][2],aZ);  aZ  = MFMA(a3,bhw[1][3],aZ);
      aNH = MFMA(a0,bhw[2][0],aNH); aNH = MFMA(a1,bhw[2][1],aNH); aNH = MFMA(a2,bhw[2][2],aNH); aNH = MFMA(a3,bhw[2][3],aNH);
    }
    // yf segment
    {
      const char* yfb = smem + SMEM_YF + t*4096;
      s16x8 f0 = ldsA(yfb,lane,0), f1 = ldsA(yfb,lane,1), f2 = ldsA(yfb,lane,2), f3 = ldsA(yfb,lane,3);
      aR  = MFMA(f0,byf[0][0],aR);  aR  = MFMA(f1,byf[0][1],aR);  aR  = MFMA(f2,byf[0][2],aR);  aR  = MFMA(f3,byf[0][3],aR);
      aZ  = MFMA(f0,byf[1][0],aZ);  aZ  = MFMA(f1,byf[1][1],aZ);  aZ  = MFMA(f2,byf[1][2],aZ);  aZ  = MFMA(f3,byf[1][3],aZ);
      aNI = MFMA(f0,byf[2][0],aNI); aNI = MFMA(f1,byf[2][1],aNI); aNI = MFMA(f2,byf[2][2],aNI); aNI = MFMA(f3,byf[2][3],aNI);
    }
    // yb segment (reversed)
    {
      const char* ybb = smem + SMEM_YB + (L_N-1-t)*4096;
      s16x8 g0 = ldsA(ybb,lane,0), g1 = ldsA(ybb,lane,1), g2 = ldsA(ybb,lane,2), g3 = ldsA(ybb,lane,3);
      aR  = MFMA(g0,byb[0][0],aR);  aR  = MFMA(g1,byb[0][1],aR);  aR  = MFMA(g2,byb[0][2],aR);  aR  = MFMA(g3,byb[0][3],aR);
      aZ  = MFMA(g0,byb[1][0],aZ);  aZ  = MFMA(g1,byb[1][1],aZ);  aZ  = MFMA(g2,byb[1][2],aZ);  aZ  = MFMA(g3,byb[1][3],aZ);
      aNI = MFMA(g0,byb[2][0],aNI); aNI = MFMA(g1,byb[2][1],aNI); aNI = MFMA(g2,byb[2][2],aNI); aNI = MFMA(g3,byb[2][3],aNI);
    }
    #pragma unroll
    for (int q=0;q<4;q++){
      const int row = krow*4+q;
      float r = sigm(aR[q]), z = sigm(aZ[q]);
      float n = tanhfast(fmaf(r, aNH[q], aNI[q]));
      float h = (1.0f - z)*n + z*hreg[q];
      hreg[q] = h;
      *(unsigned short*)(hw + swzByte(row,unit)) = f2bf(h);
      if (t < L_N-1){
        int c = selC[row]; if (c > 8) c = 8;
        for (int m=0;m<c;m++)
          ysel[((size_t)selI[row*8+m]*(L_N-1) + t)*H_N + unit] = h;
      } else {
        out[(size_t)(seq0+row)*H_N + unit] = h;
      }
    }
    __syncthreads();
  }
}

// ---------------- loss over 100 selected sequences ----------------
__global__ __launch_bounds__(64) void k_loss(
    const float* __restrict__ ysel, const float* __restrict__ y0,
    const int* __restrict__ wrev, const int* __restrict__ ssidx,
    const float* __restrict__ fcw, const float* __restrict__ fcb,
    float* __restrict__ accum)
{
  const int i = blockIdx.x;
  const int f = threadIdx.x;
  __shared__ float yh[H_N];
  const int seq = ssidx[i];
  float A=0.0f, B=0.0f, Sy=0.0f;
  const float bias = fcb[f];
  for (int t=0;t<L_N-1;t++){
    for (int k=f;k<H_N;k+=64) yh[k] = ysel[((size_t)i*(L_N-1)+t)*H_N + k];
    __syncthreads();
    float lg = bias;
    #pragma unroll 4
    for (int k=0;k<H_N;k++) lg = fmaf(fcw[f*H_N+k], yh[k], lg);
    const int node = wrev[seq*L_N + t + 1];
    const float yt = y0[(size_t)node*F_N + f];
    A += yt * softplusf(-lg);
    B += (1.0f-yt) * softplusf(lg);
    Sy += yt;
    __syncthreads();
  }
  for (int off=32; off; off>>=1){
    A += __shfl_down(A,off); B += __shfl_down(B,off); Sy += __shfl_down(Sy,off);
  }
  if (f==0){ atomicAdd(&accum[1],A); atomicAdd(&accum[2],B); atomicAdd(&accum[3],Sy); }
}

__global__ void k_finalize(const float* __restrict__ accum, float* __restrict__ out){
  if (threadIdx.x==0 && blockIdx.x==0)
    out[(size_t)SEQ_N*H_N] = accum[1]/accum[3] + accum[2]/(float)(NSEL*(L_N-1)*F_N);
}

extern "C" void kernel_launch(void* const* d_in, const int* in_sizes, int n_in,
                              void* d_out, int out_size, void* d_ws, size_t ws_size,
                              hipStream_t stream)
{
  const float* x     = (const float*)d_in[0];
  const float* y0    = (const float*)d_in[1];
  const float* wih_f = (const float*)d_in[2];
  const float* whh_f = (const float*)d_in[3];
  const float* bih_f = (const float*)d_in[4];
  const float* bhh_f = (const float*)d_in[5];
  const float* wih_b = (const float*)d_in[6];
  const float* whh_b = (const float*)d_in[7];
  const float* bih_b = (const float*)d_in[8];
  const float* bhh_b = (const float*)d_in[9];
  const float* wih   = (const float*)d_in[10];
  const float* whh   = (const float*)d_in[11];
  const float* bih   = (const float*)d_in[12];
  const float* bhh   = (const float*)d_in[13];
  const float* fc_w  = (const float*)d_in[14];
  const float* fc_b  = (const float*)d_in[15];
  const int*   walks = (const int*)d_in[16];
  const int*   dstdeg= (const int*)d_in[17];
  const int*   ssidx = (const int*)d_in[18];
  (void)in_sizes; (void)n_in; (void)out_size; (void)ws_size;

  char* ws = (char*)d_ws;
  size_t off = 0;
  auto wsalloc = [&](size_t bytes)->void* {
    void* p = ws + off; off += (bytes + 255) & ~(size_t)255; return p;
  };
  int*   accum_i = (int*)wsalloc(16);
  float* accum_f = (float*)accum_i;
  int*   wrev   = (int*)  wsalloc(sizeof(int)  * SEQ_N * L_N);
  float* uwbuf  = (float*)wsalloc(sizeof(float)* SEQ_N * L_N * 2);
  unsigned short* pk_whhf = (unsigned short*)wsalloc(2u*24*4*64*8);
  unsigned short* pk_whhb = (unsigned short*)wsalloc(2u*24*4*64*8);
  unsigned short* pk_whh  = (unsigned short*)wsalloc(2u*24*4*64*8);
  unsigned short* pk_wih  = (unsigned short*)wsalloc(2u*24*12*64*8);
  float* ysel   = (float*)wsalloc(sizeof(float)* NSEL * (L_N-1) * H_N);
  unsigned short* gxbuf = (unsigned short*)wsalloc(2u*(size_t)N_NODES*G_N);

  hipMemsetAsync(accum_i, 0, 16, stream);
  k_precompute<<<SEQ_N/256, 256, 0, stream>>>(walks, dstdeg, wrev, uwbuf, accum_i);
  k_pack<<<(24*4*64*8+255)/256,  256, 0, stream>>>(whh_f, pk_whhf, H_N,   4);
  k_pack<<<(24*4*64*8+255)/256,  256, 0, stream>>>(whh_b, pk_whhb, H_N,   4);
  k_pack<<<(24*4*64*8+255)/256,  256, 0, stream>>>(whh,   pk_whh,  H_N,   4);
  k_pack<<<(24*12*64*8+255)/256, 256, 0, stream>>>(wih,   pk_wih,  DIN_N, 12);
  k_gx<<<N_NODES/16, 512, 0, stream>>>(x, pk_wih, gxbuf);

  hipFuncSetAttribute(reinterpret_cast<const void*>(k_rum),
                      hipFuncAttributeMaxDynamicSharedMemorySize, SMEM_TOTAL);
  k_rum<<<SEQ_N/BSEQ, 512, SMEM_TOTAL, stream>>>(gxbuf,
      pk_whhf, pk_whhb, pk_whh, pk_wih,
      wih_f, bih_f, bhh_f,
      wih_b, bih_b, bhh_b,
      wih, bih, bhh,
      dstdeg, accum_i, ssidx, wrev, uwbuf,
      (float*)d_out, ysel);
  k_loss<<<NSEL, 64, 0, stream>>>(ysel, y0, wrev, ssidx, fc_w, fc_b, accum_f);
  k_finalize<<<1, 1, 0, stream>>>(accum_f, (float*)d_out);
}

// Round 5
// 709.537 us; speedup vs baseline: 13.0152x; 1.5423x over previous
//
#include <hip/hip_runtime.h>
#include <hip/hip_bf16.h>

#define S_N 4
#define E_N 16384
#define SEQ_N (S_N*E_N)   // 65536
#define L_N 12
#define H_N 128
#define G_N 384           // 3*H
#define DIN_N 385
#define F_N 64
#define N_NODES 50000
#define NSEL 100
#define BSEQ 16           // seqs per block (one MFMA M-tile)
#define TWO_PI_F 6.28318530717958647692f

typedef __attribute__((ext_vector_type(8))) short s16x8;
typedef __attribute__((ext_vector_type(4))) float f32x4;
#define MFMA(a,b,c) __builtin_amdgcn_mfma_f32_16x16x32_bf16(a,b,c,0,0,0)

// ---- shared memory layout for k_slow (bytes) ----
#define SMEM_YF   0            // ushort [12][16][128] swizzled  (48 KB)
#define SMEM_YB   49152        // ushort [12][16][128] swizzled  (48 KB)
#define SMEM_HBF  98304        // ushort [2][16][128] swizzled   (8 KB, double-buffered h)
#define SMEM_UW   106496       // float  [12][16][2]  (1536 B)
#define SMEM_DEG  108032       // float  [12][16]     (768 B)
#define SMEM_NODE 108800       // int    [16][12]     (768 B)
#define SMEM_SELC 109568       // int    [16]
#define SMEM_SELI 109632       // int    [16][8]
#define SMEM_SEQV 110144       // int    [16]
#define SMEM_VALID 110208      // int    [16]
#define SMEM_TOTAL 110272

static __device__ __forceinline__ float sigm(float x){ return 1.0f/(1.0f+__expf(-x)); }
static __device__ __forceinline__ float sigmp(float x){ return 1.0f/(1.0f+expf(-x)); }
static __device__ __forceinline__ float tanhfast(float x){ return 1.0f - 2.0f/(__expf(2.0f*x)+1.0f); }
static __device__ __forceinline__ float softplusf(float x){ return fmaxf(x,0.0f) + log1pf(__expf(-fabsf(x))); }
static __device__ __forceinline__ unsigned short f2bf(float f){
  unsigned int u = __float_as_uint(f);
  unsigned int r = (u + 0x7fffu + ((u>>16)&1u)) >> 16;
  return (unsigned short)r;
}
static __device__ __forceinline__ float bf2f(unsigned short u){ return __uint_as_float(((unsigned int)u)<<16); }
static __device__ __forceinline__ int swzByte(int s, int j){
  return s*256 + ((j<<1) ^ ((s&7)<<4));
}
static __device__ __forceinline__ s16x8 ldsA(const char* base, int lane, int kf){
  const int row = lane & 15;
  const int byte = row*256 + (((kf<<6) + ((lane>>4)<<4)) ^ ((row&7)<<4));
  return *(const s16x8*)(base + byte);
}
static __device__ __forceinline__ s16x8 pack8(float4 u0, float4 u1){
  s16x8 v;
  v[0]=(short)f2bf(u0.x); v[1]=(short)f2bf(u0.y); v[2]=(short)f2bf(u0.z); v[3]=(short)f2bf(u0.w);
  v[4]=(short)f2bf(u1.x); v[5]=(short)f2bf(u1.y); v[6]=(short)f2bf(u1.z); v[7]=(short)f2bf(u1.w);
  return v;
}

// ---------------- precompute ----------------
__global__ void k_precompute(const int* __restrict__ walks, const int* __restrict__ dstdeg,
                             int* __restrict__ wrev, float* __restrict__ uwbuf, int* __restrict__ accum,
                             int* __restrict__ canonFlag, int* __restrict__ slowIdx)
{
  const int q = blockIdx.x*blockDim.x + threadIdx.x;
  int wk[L_N], un[L_N];
  #pragma unroll
  for (int t=0;t<L_N;t++) wk[t] = walks[q*L_N+t];
  int ndist = 0;
  #pragma unroll
  for (int t=0;t<L_N;t++){
    int u = -1;
    for (int p=0;p<t;p++) if (wk[p]==wk[t]) { u = un[p]; break; }
    if (u < 0) u = ndist++;
    un[t] = u;
  }
  canonFlag[q] = (ndist == L_N) ? 1 : 0;
  if (ndist != L_N){
    int p = atomicAdd(&accum[4], 1);
    slowIdx[p] = q;
  }
  int dmax = 0;
  #pragma unroll
  for (int tr=0;tr<L_N;tr++){
    const int o = L_N-1-tr;
    const int node = wk[o];
    wrev[q*L_N+tr] = node;
    float ang = (float)un[o] * (TWO_PI_F/(float)L_N);
    uwbuf[2*(q*L_N+tr)+0] = __sinf(ang);
    uwbuf[2*(q*L_N+tr)+1] = __cosf(ang);
    dmax = max(dmax, dstdeg[node]);
  }
  for (int off=32; off; off>>=1) dmax = max(dmax, __shfl_down(dmax, off));
  if ((threadIdx.x & 63)==0) atomicMax(&accum[0], dmax);
}

// ---------------- pack weights into MFMA B-fragments ----------------
__global__ void k_pack(const float* __restrict__ W, unsigned short* __restrict__ dst, int Ksrc, int KF)
{
  int idx = blockIdx.x*256 + threadIdx.x;
  int total = 24*KF*64*8;
  if (idx >= total) return;
  int e = idx & 7, lane = (idx>>3)&63;
  int rem = idx>>9;
  int kf = rem % KF, nt = rem / KF;
  int n = nt*16 + (lane&15);
  int k = kf*32 + (lane>>4)*8 + e;
  dst[idx] = f2bf(W[(size_t)n*Ksrc + k]);
}

// ---------------- gx = x @ Wih_x^T per node ----------------
__global__ __launch_bounds__(512) void k_gx(const float* __restrict__ x,
                                            const unsigned short* __restrict__ pk_wih,
                                            unsigned short* __restrict__ gx)
{
  const int tid = threadIdx.x;
  const int w = tid>>6, lane = tid&63, col = lane&15, krow = lane>>4;
  const int m0 = blockIdx.x*16;
  s16x8 a[4];
  #pragma unroll
  for (int kf=0;kf<4;kf++){
    const float* xp = x + (size_t)(m0+col)*H_N + kf*32 + krow*8;
    a[kf] = pack8(*(const float4*)xp, *(const float4*)(xp+4));
  }
  #pragma unroll
  for (int i=0;i<3;i++){
    f32x4 acc; acc[0]=0.f; acc[1]=0.f; acc[2]=0.f; acc[3]=0.f;
    #pragma unroll
    for (int kf=0;kf<4;kf++){
      s16x8 b = *(const s16x8*)(pk_wih + (size_t)(((i*8+w)*12 + kf)*64 + lane)*8);
      acc = MFMA(a[kf], b, acc);
    }
    #pragma unroll
    for (int q=0;q<4;q++)
      gx[(size_t)(m0 + krow*4+q)*G_N + i*128 + w*16 + col] = f2bf(acc[q]);
  }
}

// ---------------- canonical trajectory (exact f32) ----------------
__global__ __launch_bounds__(384) void k_canon(
    const float* __restrict__ wih_f, const float* __restrict__ whh_f,
    const float* __restrict__ bih_f, const float* __restrict__ bhh_f,
    const float* __restrict__ wih_b, const float* __restrict__ whh_b,
    const float* __restrict__ bih_b, const float* __restrict__ bhh_b,
    const float* __restrict__ wih,
    float* __restrict__ gyfb, float* __restrict__ hc0)
{
  __shared__ float h[H_N];
  __shared__ float ga[G_N];
  __shared__ float yf[L_N][H_N];
  __shared__ float yb[L_N][H_N];
  const int g = threadIdx.x;

  // backward GRU: step st consumes canonical uw[11-st] -> angle = st*2pi/12
  if (g < H_N) h[g] = 0.f;
  __syncthreads();
  for (int st=0; st<L_N; ++st){
    float ang = (float)st * (TWO_PI_F/(float)L_N);
    float sn = sinf(ang), cs = cosf(ang);
    float acc = 0.f;
    const float* wr = whh_b + (size_t)g*H_N;
    #pragma unroll 8
    for (int k=0;k<H_N;k++) acc += wr[k]*h[k];
    float gh = acc + bhh_b[g];
    float gi = wih_b[g*2]*sn + wih_b[g*2+1]*cs + bih_b[g];
    ga[g] = (g < 2*H_N) ? (gi + gh) : gh;
    __syncthreads();
    if (g < H_N){
      float r = sigmp(ga[g]);
      float z = sigmp(ga[H_N+g]);
      float gin = wih_b[(2*H_N+g)*2]*sn + wih_b[(2*H_N+g)*2+1]*cs + bih_b[2*H_N+g];
      float n = tanhf(gin + r*ga[2*H_N+g]);
      float hn = (1.f-z)*n + z*h[g];
      h[g] = hn; yb[st][g] = hn;
    }
    __syncthreads();
  }
  if (g < H_N) h[g] = 0.f;
  __syncthreads();
  // forward GRU: step st consumes canonical uw[st] -> angle = (11-st)*2pi/12
  for (int st=0; st<L_N; ++st){
    float ang = (float)(L_N-1-st) * (TWO_PI_F/(float)L_N);
    float sn = sinf(ang), cs = cosf(ang);
    float acc = 0.f;
    const float* wr = whh_f + (size_t)g*H_N;
    #pragma unroll 8
    for (int k=0;k<H_N;k++) acc += wr[k]*h[k];
    float gh = acc + bhh_f[g];
    float gi = wih_f[g*2]*sn + wih_f[g*2+1]*cs + bih_f[g];
    ga[g] = (g < 2*H_N) ? (gi + gh) : gh;
    __syncthreads();
    if (g < H_N){
      float r = sigmp(ga[g]);
      float z = sigmp(ga[H_N+g]);
      float gin = wih_f[(2*H_N+g)*2]*sn + wih_f[(2*H_N+g)*2+1]*cs + bih_f[2*H_N+g];
      float n = tanhf(gin + r*ga[2*H_N+g]);
      float hn = (1.f-z)*n + z*h[g];
      h[g] = hn; yf[st][g] = hn;
    }
    __syncthreads();
  }

  {
    float acc[L_N];
    #pragma unroll
    for (int t=0;t<L_N;t++) acc[t] = 0.f;
    const float* wr = wih + (size_t)g*DIN_N;
    for (int k=0;k<H_N;k++){
      float wf = wr[H_N+k];
      float wb = wr[2*H_N+k];
      #pragma unroll
      for (int t=0;t<L_N;t++)
        acc[t] += wf*yf[t][k] + wb*yb[L_N-1-t][k];
    }
    #pragma unroll
    for (int t=0;t<L_N;t++) gyfb[t*G_N + g] = acc[t];
  }
  if (g < H_N) hc0[g] = 0.5f*(yf[L_N-1][g] + yb[L_N-1][g]);
}

// ---------------- fast path: main GRU only, canonical walks ----------------
__global__ __launch_bounds__(512, 4) void k_fast(
    const unsigned short* __restrict__ gx,
    const unsigned short* __restrict__ pk_whh,
    const float* __restrict__ bih, const float* __restrict__ bhh,
    const float* __restrict__ wih,
    const float* __restrict__ gyfb, const float* __restrict__ hc0,
    const int* __restrict__ dstdeg, const int* __restrict__ degmax,
    const int* __restrict__ ssidx,
    const int* __restrict__ wrev, const int* __restrict__ canonFlag,
    float* __restrict__ out, float* __restrict__ ysel)
{
  __shared__ float gposL[L_N*G_N];
  __shared__ char  hbf[2*4096];
  __shared__ float hc0L[H_N];
  __shared__ int   nodeL[BSEQ*L_N];
  __shared__ float degL[L_N*BSEQ];
  __shared__ int   canonL[BSEQ];
  __shared__ int   selC[BSEQ];
  __shared__ int   selI[BSEQ*8];

  const int tid = threadIdx.x;
  const int w = tid>>6, lane = tid&63, col = lane&15, krow = lane>>4;
  const int unit = w*16 + col;
  const int seq0 = blockIdx.x*BSEQ;

  if (tid < BSEQ){ selC[tid] = 0; canonL[tid] = canonFlag[seq0+tid]; }
  __syncthreads();

  for (int p = tid; p < L_N*G_N; p += 512) gposL[p] = gyfb[p];
  if (tid < H_N) hc0L[tid] = hc0[tid];
  for (int p = tid; p < BSEQ*L_N; p += 512)
    nodeL[p] = wrev[(size_t)seq0*L_N + p];
  if (tid < NSEL){
    int e = ssidx[tid];
    int d = e - seq0;
    if (d >= 0 && d < BSEQ){
      int slot = atomicAdd(&selC[d], 1);
      if (slot < 8) selI[d*8+slot] = tid;
    }
  }
  __syncthreads();
  const float dmaxf = (float)(*degmax);
  for (int p = tid; p < BSEQ*L_N; p += 512){
    int si = p / L_N, t = p - si*L_N;
    degL[t*16+si] = (float)dstdeg[nodeL[p]] / dmaxf;
  }
  {
    float h0 = hc0L[unit];
    #pragma unroll
    for (int q=0;q<4;q++)
      *(unsigned short*)(hbf + swzByte(krow*4+q, unit)) = f2bf(h0);
  }
  __syncthreads();

  const float cR  = bih[unit]     + bhh[unit];
  const float cZ  = bih[128+unit] + bhh[128+unit];
  const float cNI = bih[256+unit];
  const float cNH = bhh[256+unit];
  const float wdr = wih[(size_t)(unit)*DIN_N     + 384];
  const float wdz = wih[(size_t)(128+unit)*DIN_N + 384];
  const float wdn = wih[(size_t)(256+unit)*DIN_N + 384];

  s16x8 bhw[3][4];
  #pragma unroll
  for (int i=0;i<3;i++)
    #pragma unroll
    for (int kf=0;kf<4;kf++)
      bhw[i][kf] = *(const s16x8*)(pk_whh + (size_t)(((i*8+w)*4 + kf)*64 + lane)*8);

  float hreg[4];
  int cf[4], scnt[4];
  #pragma unroll
  for (int q=0;q<4;q++){
    hreg[q] = hc0L[unit];
    cf[q] = canonL[krow*4+q];
    int c = selC[krow*4+q]; if (c > 8) c = 8;
    scnt[q] = c;
  }

  unsigned short gxu[3][4];
  #pragma unroll
  for (int q=0;q<4;q++){
    const size_t nb = (size_t)nodeL[(krow*4+q)*L_N + 0]*G_N + unit;
    gxu[0][q] = gx[nb]; gxu[1][q] = gx[nb+128]; gxu[2][q] = gx[nb+256];
  }

  #pragma unroll 1
  for (int t=0; t<L_N; ++t){
    const char* hr = hbf + (t&1)*4096;
    char*       hw = hbf + ((t+1)&1)*4096;
    const float gpR = gposL[t*G_N + unit];
    const float gpZ = gposL[t*G_N + 128 + unit];
    const float gpN = gposL[t*G_N + 256 + unit];
    f32x4 aR, aZ, aNI, aNH;
    #pragma unroll
    for (int q=0;q<4;q++){
      const float dg = degL[t*16 + krow*4+q];
      aR[q]  = cR  + wdr*dg + gpR + bf2f(gxu[0][q]);
      aZ[q]  = cZ  + wdz*dg + gpZ + bf2f(gxu[1][q]);
      aNI[q] = cNI + wdn*dg + gpN + bf2f(gxu[2][q]);
      aNH[q] = cNH;
    }
    if (t+1 < L_N){
      #pragma unroll
      for (int q=0;q<4;q++){
        const size_t nb = (size_t)nodeL[(krow*4+q)*L_N + t+1]*G_N + unit;
        gxu[0][q] = gx[nb]; gxu[1][q] = gx[nb+128]; gxu[2][q] = gx[nb+256];
      }
    }
    {
      s16x8 a0 = ldsA(hr,lane,0), a1 = ldsA(hr,lane,1), a2 = ldsA(hr,lane,2), a3 = ldsA(hr,lane,3);
      aR  = MFMA(a0,bhw[0][0],aR);  aR  = MFMA(a1,bhw[0][1],aR);  aR  = MFMA(a2,bhw[0][2],aR);  aR  = MFMA(a3,bhw[0][3],aR);
      aZ  = MFMA(a0,bhw[1][0],aZ);  aZ  = MFMA(a1,bhw[1][1],aZ);  aZ  = MFMA(a2,bhw[1][2],aZ);  aZ  = MFMA(a3,bhw[1][3],aZ);
      aNH = MFMA(a0,bhw[2][0],aNH); aNH = MFMA(a1,bhw[2][1],aNH); aNH = MFMA(a2,bhw[2][2],aNH); aNH = MFMA(a3,bhw[2][3],aNH);
    }
    #pragma unroll
    for (int q=0;q<4;q++){
      const int row = krow*4+q;
      float r = sigm(aR[q]), z = sigm(aZ[q]);
      float n = tanhfast(fmaf(r, aNH[q], aNI[q]));
      float h = (1.0f - z)*n + z*hreg[q];
      hreg[q] = h;
      *(unsigned short*)(hw + swzByte(row,unit)) = f2bf(h);
      if (cf[q]){
        if (t < L_N-1){
          for (int m=0;m<scnt[q];m++)
            ysel[((size_t)selI[row*8+m]*(L_N-1) + t)*H_N + unit] = h;
        } else {
          out[(size_t)(seq0+row)*H_N + unit] = h;
        }
      }
    }
    __syncthreads();
  }
}

// ---------------- slow path small-GRU phase ----------------
static __device__ __forceinline__ void small_gru_phase(
    char* smem, const unsigned short* __restrict__ pk,
    const float* __restrict__ wih2, const float* __restrict__ bih2, const float* __restrict__ bhh2,
    bool bwd, char* ySt, float* hreg, int tid)
{
  const int w = tid>>6, lane = tid&63, col = lane&15, krow = lane>>4;
  const int unit = w*16 + col;
  char* hbf = smem + SMEM_HBF;
  const float* uwF = (const float*)(smem + SMEM_UW);

  const float cR  = bih2[unit]     + bhh2[unit];
  const float cZ  = bih2[128+unit] + bhh2[128+unit];
  const float cNI = bih2[256+unit];
  const float cNH = bhh2[256+unit];
  const float wsr = wih2[unit*2],       wcr = wih2[unit*2+1];
  const float wsz = wih2[(128+unit)*2], wcz = wih2[(128+unit)*2+1];
  const float wsn = wih2[(256+unit)*2], wcn = wih2[(256+unit)*2+1];

  s16x8 bw[3][4];
  #pragma unroll
  for (int i=0;i<3;i++)
    #pragma unroll
    for (int kf=0;kf<4;kf++)
      bw[i][kf] = *(const s16x8*)(pk + (size_t)(((i*8+w)*4 + kf)*64 + lane)*8);

  #pragma unroll 1
  for (int st=0; st<L_N; ++st){
    const int o = bwd ? (L_N-1-st) : st;
    const char* hr = hbf + (st&1)*4096;
    char*       hw = hbf + ((st+1)&1)*4096;
    float sn[4], cs[4];
    #pragma unroll
    for (int q=0;q<4;q++){
      int row = krow*4+q;
      sn[q] = uwF[(o*16+row)*2+0]; cs[q] = uwF[(o*16+row)*2+1];
    }
    s16x8 a0 = ldsA(hr,lane,0), a1 = ldsA(hr,lane,1), a2 = ldsA(hr,lane,2), a3 = ldsA(hr,lane,3);
    f32x4 aR, aZ, aNH;
    #pragma unroll
    for (int q=0;q<4;q++){
      aR[q]  = cR + wsr*sn[q] + wcr*cs[q];
      aZ[q]  = cZ + wsz*sn[q] + wcz*cs[q];
      aNH[q] = cNH;
    }
    aR  = MFMA(a0,bw[0][0],aR);  aR  = MFMA(a1,bw[0][1],aR);  aR  = MFMA(a2,bw[0][2],aR);  aR  = MFMA(a3,bw[0][3],aR);
    aZ  = MFMA(a0,bw[1][0],aZ);  aZ  = MFMA(a1,bw[1][1],aZ);  aZ  = MFMA(a2,bw[1][2],aZ);  aZ  = MFMA(a3,bw[1][3],aZ);
    aNH = MFMA(a0,bw[2][0],aNH); aNH = MFMA(a1,bw[2][1],aNH); aNH = MFMA(a2,bw[2][2],aNH); aNH = MFMA(a3,bw[2][3],aNH);
    #pragma unroll
    for (int q=0;q<4;q++){
      int row = krow*4+q;
      float r = sigm(aR[q]), z = sigm(aZ[q]);
      float ni = cNI + wsn*sn[q] + wcn*cs[q];
      float n = tanhfast(fmaf(r, aNH[q], ni));
      float h = (1.0f - z)*n + z*hreg[q];
      hreg[q] = h;
      unsigned short hb16 = f2bf(h);
      *(unsigned short*)(hw + swzByte(row,unit)) = hb16;
      *(unsigned short*)(ySt + st*4096 + swzByte(row,unit)) = hb16;
    }
    __syncthreads();
  }
}

// ---------------- slow path: full pipeline for non-canonical walks ----------------
__global__ __launch_bounds__(512, 2) void k_slow(
    const unsigned short* __restrict__ gx,
    const unsigned short* __restrict__ pk_whhf, const unsigned short* __restrict__ pk_whhb,
    const unsigned short* __restrict__ pk_whh,  const unsigned short* __restrict__ pk_wih,
    const float* __restrict__ wihf, const float* __restrict__ bihf, const float* __restrict__ bhhf,
    const float* __restrict__ wihb, const float* __restrict__ bihb, const float* __restrict__ bhhb,
    const float* __restrict__ wih,  const float* __restrict__ bih,  const float* __restrict__ bhh,
    const int* __restrict__ dstdeg, const int* __restrict__ degmax,
    const int* __restrict__ ssidx,
    const int* __restrict__ wrev, const float* __restrict__ uwbuf,
    const int* __restrict__ slowIdx, const int* __restrict__ slowCnt,
    float* __restrict__ out, float* __restrict__ ysel)
{
  extern __shared__ char smem[];
  char*  hbf   = smem + SMEM_HBF;
  float* uwF   = (float*)(smem + SMEM_UW);
  float* degL  = (float*)(smem + SMEM_DEG);
  int*   nodeL = (int*)(smem + SMEM_NODE);
  int*   selC  = (int*)(smem + SMEM_SELC);
  int*   selI  = (int*)(smem + SMEM_SELI);
  int*   seqV  = (int*)(smem + SMEM_SEQV);
  int*   validL= (int*)(smem + SMEM_VALID);

  const int cnt = *slowCnt;
  const int base = blockIdx.x*BSEQ;
  if (base >= cnt) return;

  const int tid = threadIdx.x;
  const int w = tid>>6, lane = tid&63, col = lane&15, krow = lane>>4;
  const int unit = w*16 + col;

  if (tid < BSEQ){
    int idx = base + tid;
    int v = (idx < cnt) ? 1 : 0;
    seqV[tid]   = v ? slowIdx[idx] : slowIdx[base];
    validL[tid] = v;
    selC[tid] = 0;
  }
  __syncthreads();

  for (int p = tid; p < BSEQ*L_N; p += 512){
    int si = p / L_N, t = p - si*L_N;
    int sq = seqV[si];
    nodeL[p] = wrev[(size_t)sq*L_N + t];
    uwF[(t*16+si)*2+0] = uwbuf[2*((size_t)sq*L_N + t)+0];
    uwF[(t*16+si)*2+1] = uwbuf[2*((size_t)sq*L_N + t)+1];
  }
  if (tid < NSEL){
    int e = ssidx[tid];
    for (int si=0; si<BSEQ; si++){
      if (validL[si] && seqV[si]==e){
        int slot = atomicAdd(&selC[si], 1);
        if (slot < 8) selI[si*8+slot] = tid;
      }
    }
  }
  #pragma unroll
  for (int q=0;q<4;q++)
    *(unsigned short*)(hbf + swzByte(krow*4+q, unit)) = 0;
  __syncthreads();
  const float dmaxf = (float)(*degmax);
  for (int p = tid; p < BSEQ*L_N; p += 512){
    int si = p / L_N, t = p - si*L_N;
    degL[t*16+si] = (float)dstdeg[nodeL[p]] / dmaxf;
  }
  __syncthreads();

  float hreg[4] = {0.f,0.f,0.f,0.f};

  small_gru_phase(smem, pk_whhb, wihb, bihb, bhhb, true,  smem+SMEM_YB, hreg, tid);
  float hb[4];
  #pragma unroll
  for (int q=0;q<4;q++){
    hb[q]=hreg[q]; hreg[q]=0.f;
    *(unsigned short*)(hbf + swzByte(krow*4+q, unit)) = 0;
  }
  __syncthreads();
  small_gru_phase(smem, pk_whhf, wihf, bihf, bhhf, false, smem+SMEM_YF, hreg, tid);
  #pragma unroll
  for (int q=0;q<4;q++){
    hreg[q] = 0.5f*(hreg[q]+hb[q]);
    *(unsigned short*)(hbf + swzByte(krow*4+q, unit)) = f2bf(hreg[q]);
  }
  __syncthreads();

  const float cR  = bih[unit]     + bhh[unit];
  const float cZ  = bih[128+unit] + bhh[128+unit];
  const float cNI = bih[256+unit];
  const float cNH = bhh[256+unit];
  const float wdr = wih[(size_t)(unit)*DIN_N     + 384];
  const float wdz = wih[(size_t)(128+unit)*DIN_N + 384];
  const float wdn = wih[(size_t)(256+unit)*DIN_N + 384];

  s16x8 byf[3][4], byb[3][4], bhw[3][4];
  #pragma unroll
  for (int i=0;i<3;i++){
    #pragma unroll
    for (int kf=0;kf<4;kf++){
      byf[i][kf] = *(const s16x8*)(pk_wih + (size_t)(((i*8+w)*12 + 4+kf)*64 + lane)*8);
      byb[i][kf] = *(const s16x8*)(pk_wih + (size_t)(((i*8+w)*12 + 8+kf)*64 + lane)*8);
      bhw[i][kf] = *(const s16x8*)(pk_whh + (size_t)(((i*8+w)*4  +   kf)*64 + lane)*8);
    }
  }

  unsigned short gxu[3][4];
  #pragma unroll
  for (int q=0;q<4;q++){
    const size_t nb = (size_t)nodeL[(krow*4+q)*L_N + 0]*G_N + unit;
    gxu[0][q] = gx[nb]; gxu[1][q] = gx[nb+128]; gxu[2][q] = gx[nb+256];
  }

  #pragma unroll 1
  for (int t=0; t<L_N; ++t){
    const char* hr = hbf + (t&1)*4096;
    char*       hw = hbf + ((t+1)&1)*4096;
    f32x4 aR, aZ, aNI, aNH;
    #pragma unroll
    for (int q=0;q<4;q++){
      const float dg = degL[t*16 + krow*4+q];
      aR[q]  = cR  + wdr*dg + bf2f(gxu[0][q]);
      aZ[q]  = cZ  + wdz*dg + bf2f(gxu[1][q]);
      aNI[q] = cNI + wdn*dg + bf2f(gxu[2][q]);
      aNH[q] = cNH;
    }
    if (t+1 < L_N){
      #pragma unroll
      for (int q=0;q<4;q++){
        const size_t nb = (size_t)nodeL[(krow*4+q)*L_N + t+1]*G_N + unit;
        gxu[0][q] = gx[nb]; gxu[1][q] = gx[nb+128]; gxu[2][q] = gx[nb+256];
      }
    }
    {
      s16x8 a0 = ldsA(hr,lane,0), a1 = ldsA(hr,lane,1), a2 = ldsA(hr,lane,2), a3 = ldsA(hr,lane,3);
      aR  = MFMA(a0,bhw[0][0],aR);  aR  = MFMA(a1,bhw[0][1],aR);  aR  = MFMA(a2,bhw[0][2],aR);  aR  = MFMA(a3,bhw[0][3],aR);
      aZ  = MFMA(a0,bhw[1][0],aZ);  aZ  = MFMA(a1,bhw[1][1],aZ);  aZ  = MFMA(a2,bhw[1][2],aZ);  aZ  = MFMA(a3,bhw[1][3],aZ);
      aNH = MFMA(a0,bhw[2][0],aNH); aNH = MFMA(a1,bhw[2][1],aNH); aNH = MFMA(a2,bhw[2][2],aNH); aNH = MFMA(a3,bhw[2][3],aNH);
    }
    {
      const char* yfb = smem + SMEM_YF + t*4096;
      s16x8 f0 = ldsA(yfb,lane,0), f1 = ldsA(yfb,lane,1), f2 = ldsA(yfb,lane,2), f3 = ldsA(yfb,lane,3);
      aR  = MFMA(f0,byf[0][0],aR);  aR  = MFMA(f1,byf[0][1],aR);  aR  = MFMA(f2,byf[0][2],aR);  aR  = MFMA(f3,byf[0][3],aR);
      aZ  = MFMA(f0,byf[1][0],aZ);  aZ  = MFMA(f1,byf[1][1],aZ);  aZ  = MFMA(f2,byf[1][2],aZ);  aZ  = MFMA(f3,byf[1][3],aZ);
      aNI = MFMA(f0,byf[2][0],aNI); aNI = MFMA(f1,byf[2][1],aNI); aNI = MFMA(f2,byf[2][2],aNI); aNI = MFMA(f3,byf[2][3],aNI);
    }
    {
      const char* ybb = smem + SMEM_YB + (L_N-1-t)*4096;
      s16x8 g0 = ldsA(ybb,lane,0), g1 = ldsA(ybb,lane,1), g2 = ldsA(ybb,lane,2), g3 = ldsA(ybb,lane,3);
      aR  = MFMA(g0,byb[0][0],aR);  aR  = MFMA(g1,byb[0][1],aR);  aR  = MFMA(g2,byb[0][2],aR);  aR  = MFMA(g3,byb[0][3],aR);
      aZ  = MFMA(g0,byb[1][0],aZ);  aZ  = MFMA(g1,byb[1][1],aZ);  aZ  = MFMA(g2,byb[1][2],aZ);  aZ  = MFMA(g3,byb[1][3],aZ);
      aNI = MFMA(g0,byb[2][0],aNI); aNI = MFMA(g1,byb[2][1],aNI); aNI = MFMA(g2,byb[2][2],aNI); aNI = MFMA(g3,byb[2][3],aNI);
    }
    #pragma unroll
    for (int q=0;q<4;q++){
      const int row = krow*4+q;
      float r = sigm(aR[q]), z = sigm(aZ[q]);
      float n = tanhfast(fmaf(r, aNH[q], aNI[q]));
      float h = (1.0f - z)*n + z*hreg[q];
      hreg[q] = h;
      *(unsigned short*)(hw + swzByte(row,unit)) = f2bf(h);
      if (t < L_N-1){
        int c = selC[row]; if (c > 8) c = 8;
        for (int m=0;m<c;m++)
          ysel[((size_t)selI[row*8+m]*(L_N-1) + t)*H_N + unit] = h;
      } else {
        if (validL[row])
          out[(size_t)seqV[row]*H_N + unit] = h;
      }
    }
    __syncthreads();
  }
}

// ---------------- loss ----------------
__global__ __launch_bounds__(64) void k_loss(
    const float* __restrict__ ysel, const float* __restrict__ y0,
    const int* __restrict__ wrev, const int* __restrict__ ssidx,
    const float* __restrict__ fcw, const float* __restrict__ fcb,
    float* __restrict__ accum)
{
  const int i = blockIdx.x;
  const int f = threadIdx.x;
  __shared__ float yh[H_N];
  const int seq = ssidx[i];
  float A=0.0f, B=0.0f, Sy=0.0f;
  const float bias = fcb[f];
  for (int t=0;t<L_N-1;t++){
    for (int k=f;k<H_N;k+=64) yh[k] = ysel[((size_t)i*(L_N-1)+t)*H_N + k];
    __syncthreads();
    float lg = bias;
    #pragma unroll 4
    for (int k=0;k<H_N;k++) lg = fmaf(fcw[f*H_N+k], yh[k], lg);
    const int node = wrev[seq*L_N + t + 1];
    const float yt = y0[(size_t)node*F_N + f];
    A += yt * softplusf(-lg);
    B += (1.0f-yt) * softplusf(lg);
    Sy += yt;
    __syncthreads();
  }
  for (int off=32; off; off>>=1){
    A += __shfl_down(A,off); B += __shfl_down(B,off); Sy += __shfl_down(Sy,off);
  }
  if (f==0){ atomicAdd(&accum[1],A); atomicAdd(&accum[2],B); atomicAdd(&accum[3],Sy); }
}

__global__ void k_finalize(const float* __restrict__ accum, float* __restrict__ out){
  if (threadIdx.x==0 && blockIdx.x==0)
    out[(size_t)SEQ_N*H_N] = accum[1]/accum[3] + accum[2]/(float)(NSEL*(L_N-1)*F_N);
}

extern "C" void kernel_launch(void* const* d_in, const int* in_sizes, int n_in,
                              void* d_out, int out_size, void* d_ws, size_t ws_size,
                              hipStream_t stream)
{
  const float* x     = (const float*)d_in[0];
  const float* y0    = (const float*)d_in[1];
  const float* wih_f = (const float*)d_in[2];
  const float* whh_f = (const float*)d_in[3];
  const float* bih_f = (const float*)d_in[4];
  const float* bhh_f = (const float*)d_in[5];
  const float* wih_b = (const float*)d_in[6];
  const float* whh_b = (const float*)d_in[7];
  const float* bih_b = (const float*)d_in[8];
  const float* bhh_b = (const float*)d_in[9];
  const float* wih   = (const float*)d_in[10];
  const float* whh   = (const float*)d_in[11];
  const float* bih   = (const float*)d_in[12];
  const float* bhh   = (const float*)d_in[13];
  const float* fc_w  = (const float*)d_in[14];
  const float* fc_b  = (const float*)d_in[15];
  const int*   walks = (const int*)d_in[16];
  const int*   dstdeg= (const int*)d_in[17];
  const int*   ssidx = (const int*)d_in[18];
  (void)in_sizes; (void)n_in; (void)out_size; (void)ws_size;

  char* ws = (char*)d_ws;
  size_t off = 0;
  auto wsalloc = [&](size_t bytes)->void* {
    void* p = ws + off; off += (bytes + 255) & ~(size_t)255; return p;
  };
  int*   accum_i = (int*)wsalloc(32);   // [0]=degmax [1..3]=loss [4]=slowCount
  float* accum_f = (float*)accum_i;
  int*   wrev   = (int*)  wsalloc(sizeof(int)  * SEQ_N * L_N);
  float* uwbuf  = (float*)wsalloc(sizeof(float)* SEQ_N * L_N * 2);
  unsigned short* pk_whhf = (unsigned short*)wsalloc(2u*24*4*64*8);
  unsigned short* pk_whhb = (unsigned short*)wsalloc(2u*24*4*64*8);
  unsigned short* pk_whh  = (unsigned short*)wsalloc(2u*24*4*64*8);
  unsigned short* pk_wih  = (unsigned short*)wsalloc(2u*24*12*64*8);
  float* ysel   = (float*)wsalloc(sizeof(float)* NSEL * (L_N-1) * H_N);
  unsigned short* gxbuf = (unsigned short*)wsalloc(2u*(size_t)N_NODES*G_N);
  int*   canonFlag = (int*)wsalloc(sizeof(int)*SEQ_N);
  int*   slowIdxA  = (int*)wsalloc(sizeof(int)*SEQ_N);
  float* gyfb  = (float*)wsalloc(sizeof(float)*L_N*G_N);
  float* hc0   = (float*)wsalloc(sizeof(float)*H_N);

  hipMemsetAsync(accum_i, 0, 32, stream);
  k_precompute<<<SEQ_N/256, 256, 0, stream>>>(walks, dstdeg, wrev, uwbuf, accum_i, canonFlag, slowIdxA);
  k_pack<<<(24*4*64*8+255)/256,  256, 0, stream>>>(whh_f, pk_whhf, H_N,   4);
  k_pack<<<(24*4*64*8+255)/256,  256, 0, stream>>>(whh_b, pk_whhb, H_N,   4);
  k_pack<<<(24*4*64*8+255)/256,  256, 0, stream>>>(whh,   pk_whh,  H_N,   4);
  k_pack<<<(24*12*64*8+255)/256, 256, 0, stream>>>(wih,   pk_wih,  DIN_N, 12);
  k_gx<<<N_NODES/16, 512, 0, stream>>>(x, pk_wih, gxbuf);
  k_canon<<<1, 384, 0, stream>>>(wih_f, whh_f, bih_f, bhh_f,
                                 wih_b, whh_b, bih_b, bhh_b,
                                 wih, gyfb, hc0);
  k_fast<<<SEQ_N/BSEQ, 512, 0, stream>>>(gxbuf, pk_whh, bih, bhh, wih,
      gyfb, hc0, dstdeg, accum_i, ssidx, wrev, canonFlag,
      (float*)d_out, ysel);
  hipFuncSetAttribute(reinterpret_cast<const void*>(k_slow),
                      hipFuncAttributeMaxDynamicSharedMemorySize, SMEM_TOTAL);
  k_slow<<<SEQ_N/BSEQ, 512, SMEM_TOTAL, stream>>>(gxbuf,
      pk_whhf, pk_whhb, pk_whh, pk_wih,
      wih_f, bih_f, bhh_f,
      wih_b, bih_b, bhh_b,
      wih, bih, bhh,
      dstdeg, accum_i, ssidx, wrev, uwbuf,
      slowIdxA, accum_i+4,
      (float*)d_out, ysel);
  k_loss<<<NSEL, 64, 0, stream>>>(ysel, y0, wrev, ssidx, fc_w, fc_b, accum_f);
  k_finalize<<<1, 1, 0, stream>>>(accum_f, (float*)d_out);
}

// Round 6
// 547.285 us; speedup vs baseline: 16.8738x; 1.2965x over previous
//
#include <hip/hip_runtime.h>
#include <hip/hip_bf16.h>

#define S_N 4
#define E_N 16384
#define SEQ_N (S_N*E_N)   // 65536
#define L_N 12
#define H_N 128
#define G_N 384           // 3*H
#define DIN_N 385
#define F_N 64
#define N_NODES 50000
#define NSEL 100
#define BSEQ 16           // seqs per block (one MFMA M-tile)
#define TWO_PI_F 6.28318530717958647692f

typedef __attribute__((ext_vector_type(8))) short s16x8;
typedef __attribute__((ext_vector_type(4))) float f32x4;
#define MFMA(a,b,c) __builtin_amdgcn_mfma_f32_16x16x32_bf16(a,b,c,0,0,0)

// ---- shared memory layout for k_slow (bytes) ----
#define SMEM_YF   0            // ushort [12][16][128] swizzled  (48 KB)
#define SMEM_YB   49152        // ushort [12][16][128] swizzled  (48 KB)
#define SMEM_HBF  98304        // ushort [2][16][128] swizzled   (8 KB)
#define SMEM_UW   106496       // float  [12][16][2]
#define SMEM_NODE 108032       // int    [16][12]
#define SMEM_SELC 108800       // int    [16]
#define SMEM_SELI 108864       // int    [16][8]
#define SMEM_SEQV 109376       // int    [16]
#define SMEM_VALID 109440      // int    [16]
#define SMEM_ANY  109504       // int
#define SMEM_TOTAL 109568

static __device__ __forceinline__ float sigm(float x){ return 1.0f/(1.0f+__expf(-x)); }
static __device__ __forceinline__ float sigmp(float x){ return 1.0f/(1.0f+expf(-x)); }
static __device__ __forceinline__ float tanhfast(float x){ return 1.0f - 2.0f/(__expf(2.0f*x)+1.0f); }
static __device__ __forceinline__ float softplusf(float x){ return fmaxf(x,0.0f) + log1pf(__expf(-fabsf(x))); }
static __device__ __forceinline__ unsigned short f2bf(float f){
  unsigned int u = __float_as_uint(f);
  unsigned int r = (u + 0x7fffu + ((u>>16)&1u)) >> 16;
  return (unsigned short)r;
}
static __device__ __forceinline__ float bf2f(unsigned short u){ return __uint_as_float(((unsigned int)u)<<16); }
static __device__ __forceinline__ int swzByte(int s, int j){
  return s*256 + ((j<<1) ^ ((s&7)<<4));
}
static __device__ __forceinline__ s16x8 ldsA(const char* base, int lane, int kf){
  const int row = lane & 15;
  const int byte = row*256 + (((kf<<6) + ((lane>>4)<<4)) ^ ((row&7)<<4));
  return *(const s16x8*)(base + byte);
}
static __device__ __forceinline__ s16x8 pack8(float4 u0, float4 u1){
  s16x8 v;
  v[0]=(short)f2bf(u0.x); v[1]=(short)f2bf(u0.y); v[2]=(short)f2bf(u0.z); v[3]=(short)f2bf(u0.w);
  v[4]=(short)f2bf(u1.x); v[5]=(short)f2bf(u1.y); v[6]=(short)f2bf(u1.z); v[7]=(short)f2bf(u1.w);
  return v;
}
static __device__ __forceinline__ void pack_one(const float* __restrict__ W,
                                                unsigned short* __restrict__ dst,
                                                int Ksrc, int KF, int idx){
  int e = idx & 7, lane = (idx>>3)&63;
  int rem = idx>>9;
  int kf = rem % KF, nt = rem / KF;
  dst[idx] = f2bf(W[(size_t)(nt*16+(lane&15))*Ksrc + kf*32+(lane>>4)*8+e]);
}

// ================= k_prep: canon(block0) + 4 packs + precompute =================
__global__ __launch_bounds__(512) void k_prep(
    const float* __restrict__ wih_f, const float* __restrict__ whh_f,
    const float* __restrict__ bih_f, const float* __restrict__ bhh_f,
    const float* __restrict__ wih_b, const float* __restrict__ whh_b,
    const float* __restrict__ bih_b, const float* __restrict__ bhh_b,
    const float* __restrict__ wih,   const float* __restrict__ whh,
    const float* __restrict__ bih,   const float* __restrict__ bhh,
    const int* __restrict__ walks,   const int* __restrict__ dstdeg,
    unsigned short* __restrict__ pk_whhf, unsigned short* __restrict__ pk_whhb,
    unsigned short* __restrict__ pk_whh,  unsigned short* __restrict__ pk_wih,
    float* __restrict__ gposb, float* __restrict__ hc0,
    int* __restrict__ wrev, float* __restrict__ uwbuf, int* __restrict__ accum,
    int* __restrict__ canonFlag, int* __restrict__ slowIdx)
{
  __shared__ float h[H_N];
  __shared__ float ga[G_N];
  __shared__ float yfs[L_N][H_N];
  __shared__ float ybs[L_N][H_N];

  const int b = blockIdx.x;
  const int tid = threadIdx.x;

  if (b == 0){
    // ---- canonical trajectory (exact f32), 384 active lanes ----
    const int g = tid;
    if (g < H_N) h[g] = 0.f;
    __syncthreads();
    // backward GRU: step st consumes canonical uw[11-st] -> angle = st*2pi/12
    for (int st=0; st<L_N; ++st){
      float ang = (float)st * (TWO_PI_F/(float)L_N);
      float sn = sinf(ang), cs = cosf(ang);
      if (g < G_N){
        float acc = 0.f;
        const float* wr = whh_b + (size_t)g*H_N;
        #pragma unroll 8
        for (int k=0;k<H_N;k++) acc += wr[k]*h[k];
        float gh = acc + bhh_b[g];
        float gi = wih_b[g*2]*sn + wih_b[g*2+1]*cs + bih_b[g];
        ga[g] = (g < 2*H_N) ? (gi + gh) : gh;
      }
      __syncthreads();
      if (g < H_N){
        float r = sigmp(ga[g]);
        float z = sigmp(ga[H_N+g]);
        float gin = wih_b[(2*H_N+g)*2]*sn + wih_b[(2*H_N+g)*2+1]*cs + bih_b[2*H_N+g];
        float n = tanhf(gin + r*ga[2*H_N+g]);
        float hn = (1.f-z)*n + z*h[g];
        h[g] = hn; ybs[st][g] = hn;
      }
      __syncthreads();
    }
    if (g < H_N) h[g] = 0.f;
    __syncthreads();
    // forward GRU: step st consumes canonical uw[st] -> angle = (11-st)*2pi/12
    for (int st=0; st<L_N; ++st){
      float ang = (float)(L_N-1-st) * (TWO_PI_F/(float)L_N);
      float sn = sinf(ang), cs = cosf(ang);
      if (g < G_N){
        float acc = 0.f;
        const float* wr = whh_f + (size_t)g*H_N;
        #pragma unroll 8
        for (int k=0;k<H_N;k++) acc += wr[k]*h[k];
        float gh = acc + bhh_f[g];
        float gi = wih_f[g*2]*sn + wih_f[g*2+1]*cs + bih_f[g];
        ga[g] = (g < 2*H_N) ? (gi + gh) : gh;
      }
      __syncthreads();
      if (g < H_N){
        float r = sigmp(ga[g]);
        float z = sigmp(ga[H_N+g]);
        float gin = wih_f[(2*H_N+g)*2]*sn + wih_f[(2*H_N+g)*2+1]*cs + bih_f[2*H_N+g];
        float n = tanhf(gin + r*ga[2*H_N+g]);
        float hn = (1.f-z)*n + z*h[g];
        h[g] = hn; yfs[st][g] = hn;
      }
      __syncthreads();
    }
    // gposb[t][g] = sum_k wih[g][128+k]*yf[t][k] + wih[g][256+k]*yb[11-t][k]  + bias
    if (g < G_N){
      float acc[L_N];
      #pragma unroll
      for (int t=0;t<L_N;t++) acc[t] = 0.f;
      const float* wr = wih + (size_t)g*DIN_N;
      for (int k=0;k<H_N;k++){
        float wf = wr[H_N+k];
        float wb = wr[2*H_N+k];
        #pragma unroll
        for (int t=0;t<L_N;t++)
          acc[t] += wf*yfs[t][k] + wb*ybs[L_N-1-t][k];
      }
      const float bia = (g < 2*H_N) ? (bih[g] + bhh[g]) : bih[g];
      #pragma unroll
      for (int t=0;t<L_N;t++) gposb[t*G_N + g] = acc[t] + bia;
    }
    if (g < H_N) hc0[g] = 0.5f*(yfs[L_N-1][g] + ybs[L_N-1][g]);
  } else if (b <= 288){
    // ---- packs of whh_f / whh_b / whh (96 blocks each) ----
    int seg = (b-1)/96;           // 0,1,2
    int idx = ((b-1) - seg*96)*512 + tid;
    const float* W = (seg==0) ? whh_f : (seg==1) ? whh_b : whh;
    unsigned short* D = (seg==0) ? pk_whhf : (seg==1) ? pk_whhb : pk_whh;
    pack_one(W, D, H_N, 4, idx);
  } else if (b <= 864){
    int idx = (b-289)*512 + tid;
    pack_one(wih, pk_wih, DIN_N, 12, idx);
  } else {
    // ---- precompute: one walk per thread ----
    const int q = (b-865)*512 + tid;
    int wk[L_N], un[L_N];
    const int4* wp = (const int4*)(walks + (size_t)q*L_N);
    int4 w0 = wp[0], w1 = wp[1], w2 = wp[2];
    wk[0]=w0.x; wk[1]=w0.y; wk[2]=w0.z; wk[3]=w0.w;
    wk[4]=w1.x; wk[5]=w1.y; wk[6]=w1.z; wk[7]=w1.w;
    wk[8]=w2.x; wk[9]=w2.y; wk[10]=w2.z; wk[11]=w2.w;
    int ndist = 0;
    #pragma unroll
    for (int t=0;t<L_N;t++){
      int u = -1;
      for (int p=0;p<t;p++) if (wk[p]==wk[t]) { u = un[p]; break; }
      if (u < 0) u = ndist++;
      un[t] = u;
    }
    canonFlag[q] = (ndist == L_N) ? 1 : 0;
    if (ndist != L_N){
      int p = atomicAdd(&accum[4], 1);
      slowIdx[p] = q;
    }
    int dmax = 0;
    #pragma unroll
    for (int tr=0;tr<L_N;tr++){
      const int o = L_N-1-tr;
      const int node = wk[o];
      wrev[(size_t)q*L_N+tr] = node;
      float ang = (float)un[o] * (TWO_PI_F/(float)L_N);
      uwbuf[2*((size_t)q*L_N+tr)+0] = __sinf(ang);
      uwbuf[2*((size_t)q*L_N+tr)+1] = __cosf(ang);
      dmax = max(dmax, dstdeg[node]);
    }
    for (int off=32; off; off>>=1) dmax = max(dmax, __shfl_down(dmax, off));
    if ((tid & 63)==0) atomicMax(&accum[0], dmax);
  }
}

// ================= k_gx: gx2[node][unit][4] = x@Wih_x^T + wd*deg (bf16) =================
__global__ __launch_bounds__(512) void k_gx(const float* __restrict__ x,
                                            const unsigned short* __restrict__ pk_wih,
                                            const float* __restrict__ wih,
                                            const int* __restrict__ dstdeg,
                                            const int* __restrict__ accum,
                                            unsigned short* __restrict__ gx)
{
  const int tid = threadIdx.x;
  const int w = tid>>6, lane = tid&63, col = lane&15, krow = lane>>4;
  const int unit = w*16 + col;
  const int m0 = blockIdx.x*16;
  const float dmaxf = (float)accum[0];
  s16x8 a[4];
  #pragma unroll
  for (int kf=0;kf<4;kf++){
    const float* xp = x + (size_t)(m0+col)*H_N + kf*32 + krow*8;
    a[kf] = pack8(*(const float4*)xp, *(const float4*)(xp+4));
  }
  float degn[4];
  #pragma unroll
  for (int q=0;q<4;q++) degn[q] = (float)dstdeg[m0 + krow*4+q] / dmaxf;
  #pragma unroll
  for (int i=0;i<3;i++){
    const float wd = wih[(size_t)(i*128+unit)*DIN_N + 384];
    f32x4 acc; acc[0]=0.f; acc[1]=0.f; acc[2]=0.f; acc[3]=0.f;
    #pragma unroll
    for (int kf=0;kf<4;kf++){
      s16x8 bfr = *(const s16x8*)(pk_wih + (size_t)(((i*8+w)*12 + kf)*64 + lane)*8);
      acc = MFMA(a[kf], bfr, acc);
    }
    #pragma unroll
    for (int q=0;q<4;q++)
      gx[(size_t)(m0 + krow*4+q)*512 + unit*4 + i] = f2bf(acc[q] + wd*degn[q]);
  }
}

// ================= k_fast: main GRU only, canonical walks, fully unrolled =================
__global__ __launch_bounds__(512, 4) void k_fast(
    const unsigned short* __restrict__ gx,
    const unsigned short* __restrict__ pk_whh,
    const float* __restrict__ bhh,
    const float* __restrict__ gposb, const float* __restrict__ hc0,
    const int* __restrict__ ssidx,
    const int* __restrict__ wrev, const int* __restrict__ canonFlag,
    float* __restrict__ out, float* __restrict__ ysel)
{
  __shared__ float gposL[L_N*G_N];
  __shared__ char  hbf[2*4096];
  __shared__ float hc0L[H_N];
  __shared__ int   nodeL[BSEQ*L_N];
  __shared__ int   canonL[BSEQ];
  __shared__ int   selC[BSEQ];
  __shared__ int   selI[BSEQ*8];
  __shared__ int   selAny;

  const int tid = threadIdx.x;
  const int w = tid>>6, lane = tid&63, col = lane&15, krow = lane>>4;
  const int unit = w*16 + col;
  const int seq0 = blockIdx.x*BSEQ;

  if (tid < BSEQ){ selC[tid] = 0; canonL[tid] = canonFlag[seq0+tid]; }
  if (tid == 0) selAny = 0;
  __syncthreads();

  for (int p = tid; p < L_N*G_N; p += 512) gposL[p] = gposb[p];
  if (tid < H_N) hc0L[tid] = hc0[tid];
  for (int p = tid; p < BSEQ*L_N; p += 512)
    nodeL[p] = wrev[(size_t)seq0*L_N + p];
  if (tid < NSEL){
    int e = ssidx[tid];
    int d = e - seq0;
    if (d >= 0 && d < BSEQ){
      int slot = atomicAdd(&selC[d], 1);
      if (slot < 8) selI[d*8+slot] = tid;
      atomicOr(&selAny, 1);
    }
  }
  __syncthreads();
  {
    float h0 = hc0L[unit];
    #pragma unroll
    for (int q=0;q<4;q++)
      *(unsigned short*)(hbf + swzByte(krow*4+q, unit)) = f2bf(h0);
  }
  __syncthreads();

  const float cNH = bhh[256+unit];
  const int hasSel = selAny;   // block-uniform

  s16x8 bhw[3][4];
  #pragma unroll
  for (int i=0;i<3;i++)
    #pragma unroll
    for (int kf=0;kf<4;kf++)
      bhw[i][kf] = *(const s16x8*)(pk_whh + (size_t)(((i*8+w)*4 + kf)*64 + lane)*8);

  float hreg[4];
  int cf[4], scnt[4];
  #pragma unroll
  for (int q=0;q<4;q++){
    hreg[q] = hc0L[unit];
    cf[q] = canonL[krow*4+q];
    int c = selC[krow*4+q]; if (c > 8) c = 8;
    scnt[q] = c;
  }

  ushort4 gv[4];
  #pragma unroll
  for (int q=0;q<4;q++)
    gv[q] = *(const ushort4*)(gx + (size_t)nodeL[(krow*4+q)*L_N + 0]*512 + unit*4);

  #pragma unroll
  for (int t=0; t<L_N; ++t){
    const char* hr = hbf + (t&1)*4096;
    char*       hw = hbf + ((t+1)&1)*4096;
    const float gpR = gposL[t*G_N + unit];
    const float gpZ = gposL[t*G_N + 128 + unit];
    const float gpN = gposL[t*G_N + 256 + unit];
    f32x4 aR, aZ, aNI, aNH;
    #pragma unroll
    for (int q=0;q<4;q++){
      aR[q]  = gpR + bf2f(gv[q].x);
      aZ[q]  = gpZ + bf2f(gv[q].y);
      aNI[q] = gpN + bf2f(gv[q].z);
      aNH[q] = cNH;
    }
    if (t+1 < L_N){
      #pragma unroll
      for (int q=0;q<4;q++)
        gv[q] = *(const ushort4*)(gx + (size_t)nodeL[(krow*4+q)*L_N + t+1]*512 + unit*4);
    }
    {
      s16x8 a0 = ldsA(hr,lane,0), a1 = ldsA(hr,lane,1), a2 = ldsA(hr,lane,2), a3 = ldsA(hr,lane,3);
      aR  = MFMA(a0,bhw[0][0],aR);  aR  = MFMA(a1,bhw[0][1],aR);  aR  = MFMA(a2,bhw[0][2],aR);  aR  = MFMA(a3,bhw[0][3],aR);
      aZ  = MFMA(a0,bhw[1][0],aZ);  aZ  = MFMA(a1,bhw[1][1],aZ);  aZ  = MFMA(a2,bhw[1][2],aZ);  aZ  = MFMA(a3,bhw[1][3],aZ);
      aNH = MFMA(a0,bhw[2][0],aNH); aNH = MFMA(a1,bhw[2][1],aNH); aNH = MFMA(a2,bhw[2][2],aNH); aNH = MFMA(a3,bhw[2][3],aNH);
    }
    #pragma unroll
    for (int q=0;q<4;q++){
      float r = sigm(aR[q]), z = sigm(aZ[q]);
      float n = tanhfast(fmaf(r, aNH[q], aNI[q]));
      float h = (1.0f - z)*n + z*hreg[q];
      hreg[q] = h;
      if (t < L_N-1)
        *(unsigned short*)(hw + swzByte(krow*4+q,unit)) = f2bf(h);
    }
    if (t < L_N-1){
      if (hasSel){
        #pragma unroll
        for (int q=0;q<4;q++){
          const int row = krow*4+q;
          if (cf[q])
            for (int m=0;m<scnt[q];m++)
              ysel[((size_t)selI[row*8+m]*(L_N-1) + t)*H_N + unit] = hreg[q];
        }
      }
      __syncthreads();
    }
  }
  #pragma unroll
  for (int q=0;q<4;q++)
    if (cf[q])
      out[(size_t)(seq0+krow*4+q)*H_N + unit] = hreg[q];
}

// ================= slow path small-GRU phase =================
static __device__ __forceinline__ void small_gru_phase(
    char* smem, const unsigned short* __restrict__ pk,
    const float* __restrict__ wih2, const float* __restrict__ bih2, const float* __restrict__ bhh2,
    bool bwd, char* ySt, float* hreg, int tid)
{
  const int w = tid>>6, lane = tid&63, col = lane&15, krow = lane>>4;
  const int unit = w*16 + col;
  char* hbf = smem + SMEM_HBF;
  const float* uwF = (const float*)(smem + SMEM_UW);

  const float cR  = bih2[unit]     + bhh2[unit];
  const float cZ  = bih2[128+unit] + bhh2[128+unit];
  const float cNI = bih2[256+unit];
  const float cNH = bhh2[256+unit];
  const float wsr = wih2[unit*2],       wcr = wih2[unit*2+1];
  const float wsz = wih2[(128+unit)*2], wcz = wih2[(128+unit)*2+1];
  const float wsn = wih2[(256+unit)*2], wcn = wih2[(256+unit)*2+1];

  s16x8 bw[3][4];
  #pragma unroll
  for (int i=0;i<3;i++)
    #pragma unroll
    for (int kf=0;kf<4;kf++)
      bw[i][kf] = *(const s16x8*)(pk + (size_t)(((i*8+w)*4 + kf)*64 + lane)*8);

  #pragma unroll 1
  for (int st=0; st<L_N; ++st){
    const int o = bwd ? (L_N-1-st) : st;
    const char* hr = hbf + (st&1)*4096;
    char*       hw = hbf + ((st+1)&1)*4096;
    float sn[4], cs[4];
    #pragma unroll
    for (int q=0;q<4;q++){
      int row = krow*4+q;
      sn[q] = uwF[(o*16+row)*2+0]; cs[q] = uwF[(o*16+row)*2+1];
    }
    s16x8 a0 = ldsA(hr,lane,0), a1 = ldsA(hr,lane,1), a2 = ldsA(hr,lane,2), a3 = ldsA(hr,lane,3);
    f32x4 aR, aZ, aNH;
    #pragma unroll
    for (int q=0;q<4;q++){
      aR[q]  = cR + wsr*sn[q] + wcr*cs[q];
      aZ[q]  = cZ + wsz*sn[q] + wcz*cs[q];
      aNH[q] = cNH;
    }
    aR  = MFMA(a0,bw[0][0],aR);  aR  = MFMA(a1,bw[0][1],aR);  aR  = MFMA(a2,bw[0][2],aR);  aR  = MFMA(a3,bw[0][3],aR);
    aZ  = MFMA(a0,bw[1][0],aZ);  aZ  = MFMA(a1,bw[1][1],aZ);  aZ  = MFMA(a2,bw[1][2],aZ);  aZ  = MFMA(a3,bw[1][3],aZ);
    aNH = MFMA(a0,bw[2][0],aNH); aNH = MFMA(a1,bw[2][1],aNH); aNH = MFMA(a2,bw[2][2],aNH); aNH = MFMA(a3,bw[2][3],aNH);
    #pragma unroll
    for (int q=0;q<4;q++){
      int row = krow*4+q;
      float r = sigm(aR[q]), z = sigm(aZ[q]);
      float ni = cNI + wsn*sn[q] + wcn*cs[q];
      float n = tanhfast(fmaf(r, aNH[q], ni));
      float h = (1.0f - z)*n + z*hreg[q];
      hreg[q] = h;
      unsigned short hb16 = f2bf(h);
      *(unsigned short*)(hw + swzByte(row,unit)) = hb16;
      *(unsigned short*)(ySt + st*4096 + swzByte(row,unit)) = hb16;
    }
    __syncthreads();
  }
}

// ================= k_slow: full pipeline for non-canonical walks =================
__global__ __launch_bounds__(512, 2) void k_slow(
    const unsigned short* __restrict__ gx,
    const unsigned short* __restrict__ pk_whhf, const unsigned short* __restrict__ pk_whhb,
    const unsigned short* __restrict__ pk_whh,  const unsigned short* __restrict__ pk_wih,
    const float* __restrict__ wihf, const float* __restrict__ bihf, const float* __restrict__ bhhf,
    const float* __restrict__ wihb, const float* __restrict__ bihb, const float* __restrict__ bhhb,
    const float* __restrict__ bih,  const float* __restrict__ bhh,
    const int* __restrict__ ssidx,
    const int* __restrict__ wrev, const float* __restrict__ uwbuf,
    const int* __restrict__ slowIdx, const int* __restrict__ slowCnt,
    float* __restrict__ out, float* __restrict__ ysel)
{
  extern __shared__ char smem[];
  char*  hbf   = smem + SMEM_HBF;
  float* uwF   = (float*)(smem + SMEM_UW);
  int*   nodeL = (int*)(smem + SMEM_NODE);
  int*   selC  = (int*)(smem + SMEM_SELC);
  int*   selI  = (int*)(smem + SMEM_SELI);
  int*   seqV  = (int*)(smem + SMEM_SEQV);
  int*   validL= (int*)(smem + SMEM_VALID);
  int*   anyP  = (int*)(smem + SMEM_ANY);

  const int cnt = *slowCnt;
  const int base = blockIdx.x*BSEQ;
  if (base >= cnt) return;

  const int tid = threadIdx.x;
  const int w = tid>>6, lane = tid&63, col = lane&15, krow = lane>>4;
  const int unit = w*16 + col;

  if (tid < BSEQ){
    int idx = base + tid;
    int v = (idx < cnt) ? 1 : 0;
    seqV[tid]   = v ? slowIdx[idx] : slowIdx[base];
    validL[tid] = v;
    selC[tid] = 0;
  }
  if (tid == 0) *anyP = 0;
  __syncthreads();

  for (int p = tid; p < BSEQ*L_N; p += 512){
    int si = p / L_N, t = p - si*L_N;
    int sq = seqV[si];
    nodeL[p] = wrev[(size_t)sq*L_N + t];
    uwF[(t*16+si)*2+0] = uwbuf[2*((size_t)sq*L_N + t)+0];
    uwF[(t*16+si)*2+1] = uwbuf[2*((size_t)sq*L_N + t)+1];
  }
  if (tid < NSEL){
    int e = ssidx[tid];
    for (int si=0; si<BSEQ; si++){
      if (validL[si] && seqV[si]==e){
        int slot = atomicAdd(&selC[si], 1);
        if (slot < 8) selI[si*8+slot] = tid;
        atomicOr(anyP, 1);
      }
    }
  }
  #pragma unroll
  for (int q=0;q<4;q++)
    *(unsigned short*)(hbf + swzByte(krow*4+q, unit)) = 0;
  __syncthreads();
  const int hasSel = *anyP;

  float hreg[4] = {0.f,0.f,0.f,0.f};

  small_gru_phase(smem, pk_whhb, wihb, bihb, bhhb, true,  smem+SMEM_YB, hreg, tid);
  float hb[4];
  #pragma unroll
  for (int q=0;q<4;q++){
    hb[q]=hreg[q]; hreg[q]=0.f;
    *(unsigned short*)(hbf + swzByte(krow*4+q, unit)) = 0;
  }
  __syncthreads();
  small_gru_phase(smem, pk_whhf, wihf, bihf, bhhf, false, smem+SMEM_YF, hreg, tid);
  #pragma unroll
  for (int q=0;q<4;q++){
    hreg[q] = 0.5f*(hreg[q]+hb[q]);
    *(unsigned short*)(hbf + swzByte(krow*4+q, unit)) = f2bf(hreg[q]);
  }
  __syncthreads();

  const float cR  = bih[unit]     + bhh[unit];
  const float cZ  = bih[128+unit] + bhh[128+unit];
  const float cNI = bih[256+unit];
  const float cNH = bhh[256+unit];

  s16x8 byf[3][4], byb[3][4], bhw[3][4];
  #pragma unroll
  for (int i=0;i<3;i++){
    #pragma unroll
    for (int kf=0;kf<4;kf++){
      byf[i][kf] = *(const s16x8*)(pk_wih + (size_t)(((i*8+w)*12 + 4+kf)*64 + lane)*8);
      byb[i][kf] = *(const s16x8*)(pk_wih + (size_t)(((i*8+w)*12 + 8+kf)*64 + lane)*8);
      bhw[i][kf] = *(const s16x8*)(pk_whh + (size_t)(((i*8+w)*4  +   kf)*64 + lane)*8);
    }
  }

  ushort4 gv[4];
  #pragma unroll
  for (int q=0;q<4;q++)
    gv[q] = *(const ushort4*)(gx + (size_t)nodeL[(krow*4+q)*L_N + 0]*512 + unit*4);

  #pragma unroll 1
  for (int t=0; t<L_N; ++t){
    const char* hr = hbf + (t&1)*4096;
    char*       hw = hbf + ((t+1)&1)*4096;
    f32x4 aR, aZ, aNI, aNH;
    #pragma unroll
    for (int q=0;q<4;q++){
      aR[q]  = cR  + bf2f(gv[q].x);
      aZ[q]  = cZ  + bf2f(gv[q].y);
      aNI[q] = cNI + bf2f(gv[q].z);
      aNH[q] = cNH;
    }
    if (t+1 < L_N){
      #pragma unroll
      for (int q=0;q<4;q++)
        gv[q] = *(const ushort4*)(gx + (size_t)nodeL[(krow*4+q)*L_N + t+1]*512 + unit*4);
    }
    {
      s16x8 a0 = ldsA(hr,lane,0), a1 = ldsA(hr,lane,1), a2 = ldsA(hr,lane,2), a3 = ldsA(hr,lane,3);
      aR  = MFMA(a0,bhw[0][0],aR);  aR  = MFMA(a1,bhw[0][1],aR);  aR  = MFMA(a2,bhw[0][2],aR);  aR  = MFMA(a3,bhw[0][3],aR);
      aZ  = MFMA(a0,bhw[1][0],aZ);  aZ  = MFMA(a1,bhw[1][1],aZ);  aZ  = MFMA(a2,bhw[1][2],aZ);  aZ  = MFMA(a3,bhw[1][3],aZ);
      aNH = MFMA(a0,bhw[2][0],aNH); aNH = MFMA(a1,bhw[2][1],aNH); aNH = MFMA(a2,bhw[2][2],aNH); aNH = MFMA(a3,bhw[2][3],aNH);
    }
    {
      const char* yfb = smem + SMEM_YF + t*4096;
      s16x8 f0 = ldsA(yfb,lane,0), f1 = ldsA(yfb,lane,1), f2 = ldsA(yfb,lane,2), f3 = ldsA(yfb,lane,3);
      aR  = MFMA(f0,byf[0][0],aR);  aR  = MFMA(f1,byf[0][1],aR);  aR  = MFMA(f2,byf[0][2],aR);  aR  = MFMA(f3,byf[0][3],aR);
      aZ  = MFMA(f0,byf[1][0],aZ);  aZ  = MFMA(f1,byf[1][1],aZ);  aZ  = MFMA(f2,byf[1][2],aZ);  aZ  = MFMA(f3,byf[1][3],aZ);
      aNI = MFMA(f0,byf[2][0],aNI); aNI = MFMA(f1,byf[2][1],aNI); aNI = MFMA(f2,byf[2][2],aNI); aNI = MFMA(f3,byf[2][3],aNI);
    }
    {
      const char* ybb = smem + SMEM_YB + (L_N-1-t)*4096;
      s16x8 g0 = ldsA(ybb,lane,0), g1 = ldsA(ybb,lane,1), g2 = ldsA(ybb,lane,2), g3 = ldsA(ybb,lane,3);
      aR  = MFMA(g0,byb[0][0],aR);  aR  = MFMA(g1,byb[0][1],aR);  aR  = MFMA(g2,byb[0][2],aR);  aR  = MFMA(g3,byb[0][3],aR);
      aZ  = MFMA(g0,byb[1][0],aZ);  aZ  = MFMA(g1,byb[1][1],aZ);  aZ  = MFMA(g2,byb[1][2],aZ);  aZ  = MFMA(g3,byb[1][3],aZ);
      aNI = MFMA(g0,byb[2][0],aNI); aNI = MFMA(g1,byb[2][1],aNI); aNI = MFMA(g2,byb[2][2],aNI); aNI = MFMA(g3,byb[2][3],aNI);
    }
    #pragma unroll
    for (int q=0;q<4;q++){
      const int row = krow*4+q;
      float r = sigm(aR[q]), z = sigm(aZ[q]);
      float n = tanhfast(fmaf(r, aNH[q], aNI[q]));
      float h = (1.0f - z)*n + z*hreg[q];
      hreg[q] = h;
      *(unsigned short*)(hw + swzByte(row,unit)) = f2bf(h);
      if (t == L_N-1){
        if (validL[row])
          out[(size_t)seqV[row]*H_N + unit] = h;
      }
    }
    if (hasSel && t < L_N-1){
      #pragma unroll
      for (int q=0;q<4;q++){
        const int row = krow*4+q;
        int c = selC[row]; if (c > 8) c = 8;
        for (int m=0;m<c;m++)
          ysel[((size_t)selI[row*8+m]*(L_N-1) + t)*H_N + unit] = hreg[q];
      }
    }
    __syncthreads();
  }
}

// ================= loss =================
__global__ __launch_bounds__(64) void k_loss(
    const float* __restrict__ ysel, const float* __restrict__ y0,
    const int* __restrict__ wrev, const int* __restrict__ ssidx,
    const float* __restrict__ fcw, const float* __restrict__ fcb,
    float* __restrict__ accum)
{
  const int i = blockIdx.x;
  const int f = threadIdx.x;
  __shared__ float yh[H_N];
  const int seq = ssidx[i];
  float A=0.0f, B=0.0f, Sy=0.0f;
  const float bias = fcb[f];
  for (int t=0;t<L_N-1;t++){
    for (int k=f;k<H_N;k+=64) yh[k] = ysel[((size_t)i*(L_N-1)+t)*H_N + k];
    __syncthreads();
    float lg = bias;
    #pragma unroll 4
    for (int k=0;k<H_N;k++) lg = fmaf(fcw[f*H_N+k], yh[k], lg);
    const int node = wrev[(size_t)seq*L_N + t + 1];
    const float yt = y0[(size_t)node*F_N + f];
    A += yt * softplusf(-lg);
    B += (1.0f-yt) * softplusf(lg);
    Sy += yt;
    __syncthreads();
  }
  for (int off=32; off; off>>=1){
    A += __shfl_down(A,off); B += __shfl_down(B,off); Sy += __shfl_down(Sy,off);
  }
  if (f==0){ atomicAdd(&accum[1],A); atomicAdd(&accum[2],B); atomicAdd(&accum[3],Sy); }
}

__global__ void k_finalize(const float* __restrict__ accum, float* __restrict__ out){
  if (threadIdx.x==0 && blockIdx.x==0)
    out[(size_t)SEQ_N*H_N] = accum[1]/accum[3] + accum[2]/(float)(NSEL*(L_N-1)*F_N);
}

extern "C" void kernel_launch(void* const* d_in, const int* in_sizes, int n_in,
                              void* d_out, int out_size, void* d_ws, size_t ws_size,
                              hipStream_t stream)
{
  const float* x     = (const float*)d_in[0];
  const float* y0    = (const float*)d_in[1];
  const float* wih_f = (const float*)d_in[2];
  const float* whh_f = (const float*)d_in[3];
  const float* bih_f = (const float*)d_in[4];
  const float* bhh_f = (const float*)d_in[5];
  const float* wih_b = (const float*)d_in[6];
  const float* whh_b = (const float*)d_in[7];
  const float* bih_b = (const float*)d_in[8];
  const float* bhh_b = (const float*)d_in[9];
  const float* wih   = (const float*)d_in[10];
  const float* whh   = (const float*)d_in[11];
  const float* bih   = (const float*)d_in[12];
  const float* bhh   = (const float*)d_in[13];
  const float* fc_w  = (const float*)d_in[14];
  const float* fc_b  = (const float*)d_in[15];
  const int*   walks = (const int*)d_in[16];
  const int*   dstdeg= (const int*)d_in[17];
  const int*   ssidx = (const int*)d_in[18];
  (void)in_sizes; (void)n_in; (void)out_size; (void)ws_size;

  char* ws = (char*)d_ws;
  size_t off = 0;
  auto wsalloc = [&](size_t bytes)->void* {
    void* p = ws + off; off += (bytes + 255) & ~(size_t)255; return p;
  };
  int*   accum_i = (int*)wsalloc(32);   // [0]=degmax [1..3]=loss [4]=slowCount
  float* accum_f = (float*)accum_i;
  int*   wrev   = (int*)  wsalloc(sizeof(int)  * SEQ_N * L_N);
  float* uwbuf  = (float*)wsalloc(sizeof(float)* SEQ_N * L_N * 2);
  unsigned short* pk_whhf = (unsigned short*)wsalloc(2u*24*4*64*8);
  unsigned short* pk_whhb = (unsigned short*)wsalloc(2u*24*4*64*8);
  unsigned short* pk_whh  = (unsigned short*)wsalloc(2u*24*4*64*8);
  unsigned short* pk_wih  = (unsigned short*)wsalloc(2u*24*12*64*8);
  float* ysel   = (float*)wsalloc(sizeof(float)* NSEL * (L_N-1) * H_N);
  unsigned short* gxbuf = (unsigned short*)wsalloc(2u*(size_t)N_NODES*512);
  int*   canonFlag = (int*)wsalloc(sizeof(int)*SEQ_N);
  int*   slowIdxA  = (int*)wsalloc(sizeof(int)*SEQ_N);
  float* gposb = (float*)wsalloc(sizeof(float)*L_N*G_N);
  float* hc0   = (float*)wsalloc(sizeof(float)*H_N);

  hipMemsetAsync(accum_i, 0, 32, stream);
  k_prep<<<993, 512, 0, stream>>>(
      wih_f, whh_f, bih_f, bhh_f,
      wih_b, whh_b, bih_b, bhh_b,
      wih, whh, bih, bhh,
      walks, dstdeg,
      pk_whhf, pk_whhb, pk_whh, pk_wih,
      gposb, hc0, wrev, uwbuf, accum_i, canonFlag, slowIdxA);
  k_gx<<<N_NODES/16, 512, 0, stream>>>(x, pk_wih, wih, dstdeg, accum_i, gxbuf);
  k_fast<<<SEQ_N/BSEQ, 512, 0, stream>>>(gxbuf, pk_whh, bhh,
      gposb, hc0, ssidx, wrev, canonFlag,
      (float*)d_out, ysel);
  hipFuncSetAttribute(reinterpret_cast<const void*>(k_slow),
                      hipFuncAttributeMaxDynamicSharedMemorySize, SMEM_TOTAL);
  k_slow<<<SEQ_N/BSEQ, 512, SMEM_TOTAL, stream>>>(gxbuf,
      pk_whhf, pk_whhb, pk_whh, pk_wih,
      wih_f, bih_f, bhh_f,
      wih_b, bih_b, bhh_b,
      bih, bhh,
      ssidx, wrev, uwbuf,
      slowIdxA, accum_i+4,
      (float*)d_out, ysel);
  k_loss<<<NSEL, 64, 0, stream>>>(ysel, y0, wrev, ssidx, fc_w, fc_b, accum_f);
  k_finalize<<<1, 1, 0, stream>>>(accum_f, (float*)d_out);
}

// Round 7
// 538.837 us; speedup vs baseline: 17.1384x; 1.0157x over previous
//
#include <hip/hip_runtime.h>
#include <hip/hip_bf16.h>

#define S_N 4
#define E_N 16384
#define SEQ_N (S_N*E_N)   // 65536
#define L_N 12
#define H_N 128
#define G_N 384           // 3*H
#define DIN_N 385
#define F_N 64
#define N_NODES 50000
#define NSEL 100
#define BSEQ 16           // seqs per block (one MFMA M-tile)
#define TWO_PI_F 6.28318530717958647692f
#define LOG2E_F 1.44269504088896340736f

typedef __attribute__((ext_vector_type(8))) short s16x8;
typedef __attribute__((ext_vector_type(4))) float f32x4;
#define MFMA(a,b,c) __builtin_amdgcn_mfma_f32_16x16x32_bf16(a,b,c,0,0,0)

// ---- shared memory layout for k_slow (bytes) ----
#define SMEM_YF   0            // ushort [12][16][128] swizzled  (48 KB)
#define SMEM_YB   49152        // ushort [12][16][128] swizzled  (48 KB)
#define SMEM_HBF  98304        // ushort [2][16][128] swizzled   (8 KB)
#define SMEM_UW   106496       // float  [12][16][2]
#define SMEM_NODE 108032       // int    [16][12]  (node*512 byte offsets)
#define SMEM_SELC 108800       // int    [16]
#define SMEM_SELI 108864       // int    [16][8]
#define SMEM_SEQV 109376       // int    [16]
#define SMEM_VALID 109440      // int    [16]
#define SMEM_ANY  109504       // int
#define SMEM_TOTAL 109568

static __device__ __forceinline__ float softplusf(float x){ return fmaxf(x,0.0f) + log1pf(__expf(-fabsf(x))); }
// pre-scaled (log2e folded) nonlinearities
static __device__ __forceinline__ float sigm2(float x){
  return __builtin_amdgcn_rcpf(1.0f + __builtin_amdgcn_exp2f(-x));
}
static __device__ __forceinline__ float ntanh2(float x2){   // tanh(y), x2 = 2*log2e*y
  return fmaf(-2.0f, __builtin_amdgcn_rcpf(1.0f + __builtin_amdgcn_exp2f(x2)), 1.0f);
}
static __device__ __forceinline__ float sigmp(float x){ return 1.0f/(1.0f+expf(-x)); }
static __device__ __forceinline__ unsigned short f2bf(float f){
  unsigned int u = __float_as_uint(f);
  unsigned int r = (u + 0x7fffu + ((u>>16)&1u)) >> 16;
  return (unsigned short)r;
}
static __device__ __forceinline__ unsigned int cvtpk(float lo, float hi){
  unsigned int r;
  asm("v_cvt_pk_bf16_f32 %0, %1, %2" : "=v"(r) : "v"(lo), "v"(hi));
  return r;
}
static __device__ __forceinline__ float bfl(unsigned int u){ return __uint_as_float(u<<16); }          // low bf16
static __device__ __forceinline__ float bfh(unsigned int u){ return __uint_as_float(u & 0xffff0000u); }// high bf16
static __device__ __forceinline__ int swzByte(int s, int j){
  return s*256 + ((j<<1) ^ ((s&7)<<4));
}
static __device__ __forceinline__ s16x8 ldsA(const char* base, int lane, int kf){
  const int row = lane & 15;
  const int byte = row*256 + (((kf<<6) + ((lane>>4)<<4)) ^ ((row&7)<<4));
  return *(const s16x8*)(base + byte);
}
static __device__ __forceinline__ s16x8 pack8(float4 u0, float4 u1){
  union { s16x8 v; unsigned int u[4]; } r;
  r.u[0]=cvtpk(u0.x,u0.y); r.u[1]=cvtpk(u0.z,u0.w);
  r.u[2]=cvtpk(u1.x,u1.y); r.u[3]=cvtpk(u1.z,u1.w);
  return r.v;
}
// pack with gate-dependent log2e prescale: gate blocks nt: 0..7=r, 8..15=z (x log2e), 16..23=n (x 2log2e)
static __device__ __forceinline__ void pack_one(const float* __restrict__ W,
                                                unsigned short* __restrict__ dst,
                                                int Ksrc, int KF, int idx){
  int e = idx & 7, lane = (idx>>3)&63;
  int rem = idx>>9;
  int kf = rem % KF, nt = rem / KF;
  float sc = (nt < 16) ? LOG2E_F : (2.0f*LOG2E_F);
  dst[idx] = f2bf(sc * W[(size_t)(nt*16+(lane&15))*Ksrc + kf*32+(lane>>4)*8+e]);
}

// ================= k_prep: canon(block0) + 4 packs + precompute =================
__global__ __launch_bounds__(512) void k_prep(
    const float* __restrict__ wih_f, const float* __restrict__ whh_f,
    const float* __restrict__ bih_f, const float* __restrict__ bhh_f,
    const float* __restrict__ wih_b, const float* __restrict__ whh_b,
    const float* __restrict__ bih_b, const float* __restrict__ bhh_b,
    const float* __restrict__ wih,   const float* __restrict__ whh,
    const float* __restrict__ bih,   const float* __restrict__ bhh,
    const int* __restrict__ walks,   const int* __restrict__ dstdeg,
    unsigned short* __restrict__ pk_whhf, unsigned short* __restrict__ pk_whhb,
    unsigned short* __restrict__ pk_whh,  unsigned short* __restrict__ pk_wih,
    float* __restrict__ gposb, float* __restrict__ hc0,
    int* __restrict__ wrev, float* __restrict__ uwbuf, int* __restrict__ accum,
    int* __restrict__ canonFlag, int* __restrict__ slowIdx)
{
  __shared__ float h[H_N];
  __shared__ float ga[G_N];
  __shared__ float yfs[L_N][H_N];
  __shared__ float ybs[L_N][H_N];

  const int b = blockIdx.x;
  const int tid = threadIdx.x;

  if (b == 0){
    const int g = tid;
    if (g < H_N) h[g] = 0.f;
    __syncthreads();
    // backward GRU: step st consumes canonical uw[11-st] -> angle = st*2pi/12
    for (int st=0; st<L_N; ++st){
      float ang = (float)st * (TWO_PI_F/(float)L_N);
      float sn = sinf(ang), cs = cosf(ang);
      if (g < G_N){
        float acc = 0.f;
        const float* wr = whh_b + (size_t)g*H_N;
        #pragma unroll 8
        for (int k=0;k<H_N;k++) acc += wr[k]*h[k];
        float gh = acc + bhh_b[g];
        float gi = wih_b[g*2]*sn + wih_b[g*2+1]*cs + bih_b[g];
        ga[g] = (g < 2*H_N) ? (gi + gh) : gh;
      }
      __syncthreads();
      if (g < H_N){
        float r = sigmp(ga[g]);
        float z = sigmp(ga[H_N+g]);
        float gin = wih_b[(2*H_N+g)*2]*sn + wih_b[(2*H_N+g)*2+1]*cs + bih_b[2*H_N+g];
        float n = tanhf(gin + r*ga[2*H_N+g]);
        float hn = (1.f-z)*n + z*h[g];
        h[g] = hn; ybs[st][g] = hn;
      }
      __syncthreads();
    }
    if (g < H_N) h[g] = 0.f;
    __syncthreads();
    // forward GRU: step st consumes canonical uw[st] -> angle = (11-st)*2pi/12
    for (int st=0; st<L_N; ++st){
      float ang = (float)(L_N-1-st) * (TWO_PI_F/(float)L_N);
      float sn = sinf(ang), cs = cosf(ang);
      if (g < G_N){
        float acc = 0.f;
        const float* wr = whh_f + (size_t)g*H_N;
        #pragma unroll 8
        for (int k=0;k<H_N;k++) acc += wr[k]*h[k];
        float gh = acc + bhh_f[g];
        float gi = wih_f[g*2]*sn + wih_f[g*2+1]*cs + bih_f[g];
        ga[g] = (g < 2*H_N) ? (gi + gh) : gh;
      }
      __syncthreads();
      if (g < H_N){
        float r = sigmp(ga[g]);
        float z = sigmp(ga[H_N+g]);
        float gin = wih_f[(2*H_N+g)*2]*sn + wih_f[(2*H_N+g)*2+1]*cs + bih_f[2*H_N+g];
        float n = tanhf(gin + r*ga[2*H_N+g]);
        float hn = (1.f-z)*n + z*h[g];
        h[g] = hn; yfs[st][g] = hn;
      }
      __syncthreads();
    }
    // gposb[t][g] = (sum_k wihf-part + bias) * gate-scale
    if (g < G_N){
      float acc[L_N];
      #pragma unroll
      for (int t=0;t<L_N;t++) acc[t] = 0.f;
      const float* wr = wih + (size_t)g*DIN_N;
      for (int k=0;k<H_N;k++){
        float wf = wr[H_N+k];
        float wb = wr[2*H_N+k];
        #pragma unroll
        for (int t=0;t<L_N;t++)
          acc[t] += wf*yfs[t][k] + wb*ybs[L_N-1-t][k];
      }
      const float bia = (g < 2*H_N) ? (bih[g] + bhh[g]) : bih[g];
      const float sc  = (g < 2*H_N) ? LOG2E_F : 2.0f*LOG2E_F;
      #pragma unroll
      for (int t=0;t<L_N;t++) gposb[t*G_N + g] = (acc[t] + bia)*sc;
    }
    if (g < H_N) hc0[g] = 0.5f*(yfs[L_N-1][g] + ybs[L_N-1][g]);
  } else if (b <= 288){
    int seg = (b-1)/96;
    int idx = ((b-1) - seg*96)*512 + tid;
    const float* W = (seg==0) ? whh_f : (seg==1) ? whh_b : whh;
    unsigned short* D = (seg==0) ? pk_whhf : (seg==1) ? pk_whhb : pk_whh;
    pack_one(W, D, H_N, 4, idx);
  } else if (b <= 864){
    int idx = (b-289)*512 + tid;
    pack_one(wih, pk_wih, DIN_N, 12, idx);
  } else {
    const int q = (b-865)*512 + tid;
    int wk[L_N], un[L_N];
    const int4* wp = (const int4*)(walks + (size_t)q*L_N);
    int4 w0 = wp[0], w1 = wp[1], w2 = wp[2];
    wk[0]=w0.x; wk[1]=w0.y; wk[2]=w0.z; wk[3]=w0.w;
    wk[4]=w1.x; wk[5]=w1.y; wk[6]=w1.z; wk[7]=w1.w;
    wk[8]=w2.x; wk[9]=w2.y; wk[10]=w2.z; wk[11]=w2.w;
    int ndist = 0;
    #pragma unroll
    for (int t=0;t<L_N;t++){
      int u = -1;
      for (int p=0;p<t;p++) if (wk[p]==wk[t]) { u = un[p]; break; }
      if (u < 0) u = ndist++;
      un[t] = u;
    }
    canonFlag[q] = (ndist == L_N) ? 1 : 0;
    if (ndist != L_N){
      int p = atomicAdd(&accum[4], 1);
      slowIdx[p] = q;
    }
    int dmax = 0;
    #pragma unroll
    for (int tr=0;tr<L_N;tr++){
      const int o = L_N-1-tr;
      const int node = wk[o];
      wrev[(size_t)q*L_N+tr] = node;
      float ang = (float)un[o] * (TWO_PI_F/(float)L_N);
      uwbuf[2*((size_t)q*L_N+tr)+0] = __sinf(ang);
      uwbuf[2*((size_t)q*L_N+tr)+1] = __cosf(ang);
      dmax = max(dmax, dstdeg[node]);
    }
    for (int off=32; off; off>>=1) dmax = max(dmax, __shfl_down(dmax, off));
    if ((tid & 63)==0) atomicMax(&accum[0], dmax);
  }
}

// ================= k_gx: two planes, pre-scaled =================
// gxrz[node*512 + unit*4] : u32 {bf16 r | bf16 z<<16}   (x log2e, deg folded)
// gxn [node*256 + unit*2] : u16 bf16 n                  (x 2log2e, deg folded)
__global__ __launch_bounds__(512) void k_gx(const float* __restrict__ x,
                                            const unsigned short* __restrict__ pk_wih,
                                            const float* __restrict__ wih,
                                            const int* __restrict__ dstdeg,
                                            const int* __restrict__ accum,
                                            char* __restrict__ gxrz, char* __restrict__ gxn)
{
  const int tid = threadIdx.x;
  const int w = tid>>6, lane = tid&63, col = lane&15, krow = lane>>4;
  const int unit = w*16 + col;
  const int m0 = blockIdx.x*16;
  const float dmaxf = (float)accum[0];
  s16x8 a[4];
  #pragma unroll
  for (int kf=0;kf<4;kf++){
    const float* xp = x + (size_t)(m0+col)*H_N + kf*32 + krow*8;
    a[kf] = pack8(*(const float4*)xp, *(const float4*)(xp+4));
  }
  float degn[4];
  #pragma unroll
  for (int q=0;q<4;q++) degn[q] = (float)dstdeg[m0 + krow*4+q] / dmaxf;
  f32x4 accg[3];
  #pragma unroll
  for (int i=0;i<3;i++){
    f32x4 acc; acc[0]=0.f; acc[1]=0.f; acc[2]=0.f; acc[3]=0.f;
    #pragma unroll
    for (int kf=0;kf<4;kf++){
      s16x8 bfr = *(const s16x8*)(pk_wih + (size_t)(((i*8+w)*12 + kf)*64 + lane)*8);
      acc = MFMA(a[kf], bfr, acc);
    }
    accg[i] = acc;
  }
  const float wdR = wih[(size_t)(unit)*DIN_N     + 384] * LOG2E_F;
  const float wdZ = wih[(size_t)(128+unit)*DIN_N + 384] * LOG2E_F;
  const float wdN = wih[(size_t)(256+unit)*DIN_N + 384] * (2.0f*LOG2E_F);
  #pragma unroll
  for (int q=0;q<4;q++){
    const size_t row = (size_t)(m0 + krow*4+q);
    float rv = accg[0][q] + wdR*degn[q];
    float zv = accg[1][q] + wdZ*degn[q];
    float nv = accg[2][q] + wdN*degn[q];
    *(unsigned int*)(gxrz + row*512 + unit*4) = cvtpk(rv, zv);
    *(unsigned short*)(gxn + row*256 + unit*2) = (unsigned short)cvtpk(nv, nv);
  }
}

// ================= k_fast: main GRU only, canonical walks =================
__global__ __launch_bounds__(512, 4) void k_fast(
    const char* __restrict__ gxrz, const char* __restrict__ gxn,
    const unsigned short* __restrict__ pk_whh,
    const float* __restrict__ bhh,
    const float* __restrict__ gposb, const float* __restrict__ hc0,
    const int* __restrict__ ssidx,
    const int* __restrict__ wrev, const int* __restrict__ canonFlag,
    float* __restrict__ out, float* __restrict__ ysel)
{
  __shared__ float gposL[L_N*G_N];
  __shared__ char  hbf[2*4096];
  __shared__ float hc0L[H_N];
  __shared__ int   nodeL[BSEQ*L_N];    // node*512 byte offsets
  __shared__ int   canonL[BSEQ];
  __shared__ int   selC[BSEQ];
  __shared__ int   selI[BSEQ*8];
  __shared__ int   selAny;

  const int tid = threadIdx.x;
  const int w = tid>>6, lane = tid&63, col = lane&15, krow = lane>>4;
  const int unit = w*16 + col;
  const int unit4 = unit*4, unit2 = unit*2;
  const int seq0 = blockIdx.x*BSEQ;

  if (tid < BSEQ){ selC[tid] = 0; canonL[tid] = canonFlag[seq0+tid]; }
  if (tid == 0) selAny = 0;
  __syncthreads();

  for (int p = tid; p < L_N*G_N; p += 512) gposL[p] = gposb[p];
  if (tid < H_N) hc0L[tid] = hc0[tid];
  for (int p = tid; p < BSEQ*L_N; p += 512)
    nodeL[p] = wrev[(size_t)seq0*L_N + p] << 9;
  if (tid < NSEL){
    int e = ssidx[tid];
    int d = e - seq0;
    if (d >= 0 && d < BSEQ){
      int slot = atomicAdd(&selC[d], 1);
      if (slot < 8) selI[d*8+slot] = tid;
      atomicOr(&selAny, 1);
    }
  }
  __syncthreads();
  {
    float h0 = hc0L[unit];
    unsigned int p0 = cvtpk(h0, h0);
    #pragma unroll
    for (int q=0;q<4;q++)
      *(unsigned short*)(hbf + swzByte(krow*4+q, unit)) = (unsigned short)p0;
  }
  __syncthreads();

  const float cNH = bhh[256+unit] * (2.0f*LOG2E_F);
  const int hasSel = selAny;

  s16x8 bhw[3][4];
  #pragma unroll
  for (int i=0;i<3;i++)
    #pragma unroll
    for (int kf=0;kf<4;kf++)
      bhw[i][kf] = *(const s16x8*)(pk_whh + (size_t)(((i*8+w)*4 + kf)*64 + lane)*8);

  float hreg[4];
  int cf[4], scnt[4], hoff[4];
  #pragma unroll
  for (int q=0;q<4;q++){
    hreg[q] = hc0L[unit];
    cf[q] = canonL[krow*4+q];
    int c = selC[krow*4+q]; if (c > 8) c = 8;
    scnt[q] = c;
    hoff[q] = swzByte(krow*4+q, unit);
  }

  // depth-2 prefetch buffers
  unsigned int rzA[4], rzB[4], nA[4], nB[4];
  #pragma unroll
  for (int q=0;q<4;q++){
    int nb0 = nodeL[(krow*4+q)*L_N + 0];
    int nb1 = nodeL[(krow*4+q)*L_N + 1];
    rzA[q] = *(const unsigned int*)(gxrz + nb0 + unit4);
    nA[q]  = *(const unsigned short*)(gxn + (nb0>>1) + unit2);
    rzB[q] = *(const unsigned int*)(gxrz + nb1 + unit4);
    nB[q]  = *(const unsigned short*)(gxn + (nb1>>1) + unit2);
  }

  #pragma unroll
  for (int t=0; t<L_N; ++t){
    const char* hr = hbf + (t&1)*4096;
    char*       hw = hbf + ((t+1)&1)*4096;
    const float gpR = gposL[t*G_N + unit];
    const float gpZ = gposL[t*G_N + 128 + unit];
    const float gpN = gposL[t*G_N + 256 + unit];
    f32x4 aR, aZ, aNI, aNH;
    #pragma unroll
    for (int q=0;q<4;q++){
      const unsigned int rz = (t&1) ? rzB[q] : rzA[q];
      const unsigned int nn = (t&1) ? nB[q]  : nA[q];
      aR[q]  = gpR + bfl(rz);
      aZ[q]  = gpZ + bfh(rz);
      aNI[q] = gpN + bfl(nn);
      aNH[q] = cNH;
    }
    if (t+2 < L_N){
      #pragma unroll
      for (int q=0;q<4;q++){
        int nb = nodeL[(krow*4+q)*L_N + t+2];
        if (t&1){ rzB[q] = *(const unsigned int*)(gxrz + nb + unit4);
                  nB[q]  = *(const unsigned short*)(gxn + (nb>>1) + unit2); }
        else    { rzA[q] = *(const unsigned int*)(gxrz + nb + unit4);
                  nA[q]  = *(const unsigned short*)(gxn + (nb>>1) + unit2); }
      }
    }
    {
      s16x8 a0 = ldsA(hr,lane,0), a1 = ldsA(hr,lane,1), a2 = ldsA(hr,lane,2), a3 = ldsA(hr,lane,3);
      aR  = MFMA(a0,bhw[0][0],aR);  aR  = MFMA(a1,bhw[0][1],aR);  aR  = MFMA(a2,bhw[0][2],aR);  aR  = MFMA(a3,bhw[0][3],aR);
      aZ  = MFMA(a0,bhw[1][0],aZ);  aZ  = MFMA(a1,bhw[1][1],aZ);  aZ  = MFMA(a2,bhw[1][2],aZ);  aZ  = MFMA(a3,bhw[1][3],aZ);
      aNH = MFMA(a0,bhw[2][0],aNH); aNH = MFMA(a1,bhw[2][1],aNH); aNH = MFMA(a2,bhw[2][2],aNH); aNH = MFMA(a3,bhw[2][3],aNH);
    }
    #pragma unroll
    for (int q=0;q<4;q++){
      float r = sigm2(aR[q]), z = sigm2(aZ[q]);
      float n = ntanh2(fmaf(r, aNH[q], aNI[q]));
      hreg[q] = fmaf(z, hreg[q]-n, n);
    }
    if (t < L_N-1){
      unsigned int p01 = cvtpk(hreg[0], hreg[1]);
      unsigned int p23 = cvtpk(hreg[2], hreg[3]);
      *(unsigned short*)(hw + hoff[0]) = (unsigned short)p01;
      *(unsigned short*)(hw + hoff[1]) = (unsigned short)(p01>>16);
      *(unsigned short*)(hw + hoff[2]) = (unsigned short)p23;
      *(unsigned short*)(hw + hoff[3]) = (unsigned short)(p23>>16);
      if (hasSel){
        #pragma unroll
        for (int q=0;q<4;q++){
          const int row = krow*4+q;
          if (cf[q])
            for (int m=0;m<scnt[q];m++)
              ysel[((size_t)selI[row*8+m]*(L_N-1) + t)*H_N + unit] = hreg[q];
        }
      }
      __syncthreads();
    }
  }
  #pragma unroll
  for (int q=0;q<4;q++)
    if (cf[q])
      out[(size_t)(seq0+krow*4+q)*H_N + unit] = hreg[q];
}

// ================= slow path small-GRU phase (pre-scaled) =================
static __device__ __forceinline__ void small_gru_phase(
    char* smem, const unsigned short* __restrict__ pk,
    const float* __restrict__ wih2, const float* __restrict__ bih2, const float* __restrict__ bhh2,
    bool bwd, char* ySt, float* hreg, int tid)
{
  const int w = tid>>6, lane = tid&63, col = lane&15, krow = lane>>4;
  const int unit = w*16 + col;
  char* hbf = smem + SMEM_HBF;
  const float* uwF = (const float*)(smem + SMEM_UW);

  const float cR  = (bih2[unit]     + bhh2[unit])     * LOG2E_F;
  const float cZ  = (bih2[128+unit] + bhh2[128+unit]) * LOG2E_F;
  const float cNI = bih2[256+unit] * (2.0f*LOG2E_F);
  const float cNH = bhh2[256+unit] * (2.0f*LOG2E_F);
  const float wsr = wih2[unit*2]*LOG2E_F,       wcr = wih2[unit*2+1]*LOG2E_F;
  const float wsz = wih2[(128+unit)*2]*LOG2E_F, wcz = wih2[(128+unit)*2+1]*LOG2E_F;
  const float wsn = wih2[(256+unit)*2]*(2.0f*LOG2E_F), wcn = wih2[(256+unit)*2+1]*(2.0f*LOG2E_F);

  s16x8 bw[3][4];
  #pragma unroll
  for (int i=0;i<3;i++)
    #pragma unroll
    for (int kf=0;kf<4;kf++)
      bw[i][kf] = *(const s16x8*)(pk + (size_t)(((i*8+w)*4 + kf)*64 + lane)*8);

  #pragma unroll 1
  for (int st=0; st<L_N; ++st){
    const int o = bwd ? (L_N-1-st) : st;
    const char* hr = hbf + (st&1)*4096;
    char*       hw = hbf + ((st+1)&1)*4096;
    float sn[4], cs[4];
    #pragma unroll
    for (int q=0;q<4;q++){
      int row = krow*4+q;
      sn[q] = uwF[(o*16+row)*2+0]; cs[q] = uwF[(o*16+row)*2+1];
    }
    s16x8 a0 = ldsA(hr,lane,0), a1 = ldsA(hr,lane,1), a2 = ldsA(hr,lane,2), a3 = ldsA(hr,lane,3);
    f32x4 aR, aZ, aNH;
    #pragma unroll
    for (int q=0;q<4;q++){
      aR[q]  = cR + wsr*sn[q] + wcr*cs[q];
      aZ[q]  = cZ + wsz*sn[q] + wcz*cs[q];
      aNH[q] = cNH;
    }
    aR  = MFMA(a0,bw[0][0],aR);  aR  = MFMA(a1,bw[0][1],aR);  aR  = MFMA(a2,bw[0][2],aR);  aR  = MFMA(a3,bw[0][3],aR);
    aZ  = MFMA(a0,bw[1][0],aZ);  aZ  = MFMA(a1,bw[1][1],aZ);  aZ  = MFMA(a2,bw[1][2],aZ);  aZ  = MFMA(a3,bw[1][3],aZ);
    aNH = MFMA(a0,bw[2][0],aNH); aNH = MFMA(a1,bw[2][1],aNH); aNH = MFMA(a2,bw[2][2],aNH); aNH = MFMA(a3,bw[2][3],aNH);
    #pragma unroll
    for (int q=0;q<4;q++){
      int row = krow*4+q;
      float r = sigm2(aR[q]), z = sigm2(aZ[q]);
      float ni = cNI + wsn*sn[q] + wcn*cs[q];
      float n = ntanh2(fmaf(r, aNH[q], ni));
      float h = fmaf(z, hreg[q]-n, n);
      hreg[q] = h;
      unsigned int pp = cvtpk(h, h);
      *(unsigned short*)(hw + swzByte(row,unit)) = (unsigned short)pp;
      *(unsigned short*)(ySt + st*4096 + swzByte(row,unit)) = (unsigned short)pp;
    }
    __syncthreads();
  }
}

// ================= k_slow: full pipeline for non-canonical walks =================
__global__ __launch_bounds__(512, 2) void k_slow(
    const char* __restrict__ gxrz, const char* __restrict__ gxn,
    const unsigned short* __restrict__ pk_whhf, const unsigned short* __restrict__ pk_whhb,
    const unsigned short* __restrict__ pk_whh,  const unsigned short* __restrict__ pk_wih,
    const float* __restrict__ wihf, const float* __restrict__ bihf, const float* __restrict__ bhhf,
    const float* __restrict__ wihb, const float* __restrict__ bihb, const float* __restrict__ bhhb,
    const float* __restrict__ bih,  const float* __restrict__ bhh,
    const int* __restrict__ ssidx,
    const int* __restrict__ wrev, const float* __restrict__ uwbuf,
    const int* __restrict__ slowIdx, const int* __restrict__ slowCnt,
    float* __restrict__ out, float* __restrict__ ysel)
{
  extern __shared__ char smem[];
  char*  hbf   = smem + SMEM_HBF;
  float* uwF   = (float*)(smem + SMEM_UW);
  int*   nodeL = (int*)(smem + SMEM_NODE);
  int*   selC  = (int*)(smem + SMEM_SELC);
  int*   selI  = (int*)(smem + SMEM_SELI);
  int*   seqV  = (int*)(smem + SMEM_SEQV);
  int*   validL= (int*)(smem + SMEM_VALID);
  int*   anyP  = (int*)(smem + SMEM_ANY);

  const int cnt = *slowCnt;
  const int base = blockIdx.x*BSEQ;
  if (base >= cnt) return;

  const int tid = threadIdx.x;
  const int w = tid>>6, lane = tid&63, col = lane&15, krow = lane>>4;
  const int unit = w*16 + col;
  const int unit4 = unit*4, unit2 = unit*2;

  if (tid < BSEQ){
    int idx = base + tid;
    int v = (idx < cnt) ? 1 : 0;
    seqV[tid]   = v ? slowIdx[idx] : slowIdx[base];
    validL[tid] = v;
    selC[tid] = 0;
  }
  if (tid == 0) *anyP = 0;
  __syncthreads();

  for (int p = tid; p < BSEQ*L_N; p += 512){
    int si = p / L_N, t = p - si*L_N;
    int sq = seqV[si];
    nodeL[p] = wrev[(size_t)sq*L_N + t] << 9;
    uwF[(t*16+si)*2+0] = uwbuf[2*((size_t)sq*L_N + t)+0];
    uwF[(t*16+si)*2+1] = uwbuf[2*((size_t)sq*L_N + t)+1];
  }
  if (tid < NSEL){
    int e = ssidx[tid];
    for (int si=0; si<BSEQ; si++){
      if (validL[si] && seqV[si]==e){
        int slot = atomicAdd(&selC[si], 1);
        if (slot < 8) selI[si*8+slot] = tid;
        atomicOr(anyP, 1);
      }
    }
  }
  #pragma unroll
  for (int q=0;q<4;q++)
    *(unsigned short*)(hbf + swzByte(krow*4+q, unit)) = 0;
  __syncthreads();
  const int hasSel = *anyP;

  float hreg[4] = {0.f,0.f,0.f,0.f};

  small_gru_phase(smem, pk_whhb, wihb, bihb, bhhb, true,  smem+SMEM_YB, hreg, tid);
  float hb[4];
  #pragma unroll
  for (int q=0;q<4;q++){
    hb[q]=hreg[q]; hreg[q]=0.f;
    *(unsigned short*)(hbf + swzByte(krow*4+q, unit)) = 0;
  }
  __syncthreads();
  small_gru_phase(smem, pk_whhf, wihf, bihf, bhhf, false, smem+SMEM_YF, hreg, tid);
  #pragma unroll
  for (int q=0;q<4;q++){
    hreg[q] = 0.5f*(hreg[q]+hb[q]);
    *(unsigned short*)(hbf + swzByte(krow*4+q, unit)) = (unsigned short)cvtpk(hreg[q], hreg[q]);
  }
  __syncthreads();

  const float cR  = (bih[unit]     + bhh[unit])     * LOG2E_F;
  const float cZ  = (bih[128+unit] + bhh[128+unit]) * LOG2E_F;
  const float cNI = bih[256+unit] * (2.0f*LOG2E_F);
  const float cNH = bhh[256+unit] * (2.0f*LOG2E_F);

  s16x8 byf[3][4], byb[3][4], bhw[3][4];
  #pragma unroll
  for (int i=0;i<3;i++){
    #pragma unroll
    for (int kf=0;kf<4;kf++){
      byf[i][kf] = *(const s16x8*)(pk_wih + (size_t)(((i*8+w)*12 + 4+kf)*64 + lane)*8);
      byb[i][kf] = *(const s16x8*)(pk_wih + (size_t)(((i*8+w)*12 + 8+kf)*64 + lane)*8);
      bhw[i][kf] = *(const s16x8*)(pk_whh + (size_t)(((i*8+w)*4  +   kf)*64 + lane)*8);
    }
  }

  unsigned int rzv[4], nv[4];
  #pragma unroll
  for (int q=0;q<4;q++){
    int nb = nodeL[(krow*4+q)*L_N + 0];
    rzv[q] = *(const unsigned int*)(gxrz + nb + unit4);
    nv[q]  = *(const unsigned short*)(gxn + (nb>>1) + unit2);
  }

  #pragma unroll 1
  for (int t=0; t<L_N; ++t){
    const char* hr = hbf + (t&1)*4096;
    char*       hw = hbf + ((t+1)&1)*4096;
    f32x4 aR, aZ, aNI, aNH;
    #pragma unroll
    for (int q=0;q<4;q++){
      aR[q]  = cR  + bfl(rzv[q]);
      aZ[q]  = cZ  + bfh(rzv[q]);
      aNI[q] = cNI + bfl(nv[q]);
      aNH[q] = cNH;
    }
    if (t+1 < L_N){
      #pragma unroll
      for (int q=0;q<4;q++){
        int nb = nodeL[(krow*4+q)*L_N + t+1];
        rzv[q] = *(const unsigned int*)(gxrz + nb + unit4);
        nv[q]  = *(const unsigned short*)(gxn + (nb>>1) + unit2);
      }
    }
    {
      s16x8 a0 = ldsA(hr,lane,0), a1 = ldsA(hr,lane,1), a2 = ldsA(hr,lane,2), a3 = ldsA(hr,lane,3);
      aR  = MFMA(a0,bhw[0][0],aR);  aR  = MFMA(a1,bhw[0][1],aR);  aR  = MFMA(a2,bhw[0][2],aR);  aR  = MFMA(a3,bhw[0][3],aR);
      aZ  = MFMA(a0,bhw[1][0],aZ);  aZ  = MFMA(a1,bhw[1][1],aZ);  aZ  = MFMA(a2,bhw[1][2],aZ);  aZ  = MFMA(a3,bhw[1][3],aZ);
      aNH = MFMA(a0,bhw[2][0],aNH); aNH = MFMA(a1,bhw[2][1],aNH); aNH = MFMA(a2,bhw[2][2],aNH); aNH = MFMA(a3,bhw[2][3],aNH);
    }
    {
      const char* yfb = smem + SMEM_YF + t*4096;
      s16x8 f0 = ldsA(yfb,lane,0), f1 = ldsA(yfb,lane,1), f2 = ldsA(yfb,lane,2), f3 = ldsA(yfb,lane,3);
      aR  = MFMA(f0,byf[0][0],aR);  aR  = MFMA(f1,byf[0][1],aR);  aR  = MFMA(f2,byf[0][2],aR);  aR  = MFMA(f3,byf[0][3],aR);
      aZ  = MFMA(f0,byf[1][0],aZ);  aZ  = MFMA(f1,byf[1][1],aZ);  aZ  = MFMA(f2,byf[1][2],aZ);  aZ  = MFMA(f3,byf[1][3],aZ);
      aNI = MFMA(f0,byf[2][0],aNI); aNI = MFMA(f1,byf[2][1],aNI); aNI = MFMA(f2,byf[2][2],aNI); aNI = MFMA(f3,byf[2][3],aNI);
    }
    {
      const char* ybb = smem + SMEM_YB + (L_N-1-t)*4096;
      s16x8 g0 = ldsA(ybb,lane,0), g1 = ldsA(ybb,lane,1), g2 = ldsA(ybb,lane,2), g3 = ldsA(ybb,lane,3);
      aR  = MFMA(g0,byb[0][0],aR);  aR  = MFMA(g1,byb[0][1],aR);  aR  = MFMA(g2,byb[0][2],aR);  aR  = MFMA(g3,byb[0][3],aR);
      aZ  = MFMA(g0,byb[1][0],aZ);  aZ  = MFMA(g1,byb[1][1],aZ);  aZ  = MFMA(g2,byb[1][2],aZ);  aZ  = MFMA(g3,byb[1][3],aZ);
      aNI = MFMA(g0,byb[2][0],aNI); aNI = MFMA(g1,byb[2][1],aNI); aNI = MFMA(g2,byb[2][2],aNI); aNI = MFMA(g3,byb[2][3],aNI);
    }
    #pragma unroll
    for (int q=0;q<4;q++){
      const int row = krow*4+q;
      float r = sigm2(aR[q]), z = sigm2(aZ[q]);
      float n = ntanh2(fmaf(r, aNH[q], aNI[q]));
      float h = fmaf(z, hreg[q]-n, n);
      hreg[q] = h;
      *(unsigned short*)(hw + swzByte(row,unit)) = (unsigned short)cvtpk(h, h);
      if (t == L_N-1){
        if (validL[row])
          out[(size_t)seqV[row]*H_N + unit] = h;
      }
    }
    if (hasSel && t < L_N-1){
      #pragma unroll
      for (int q=0;q<4;q++){
        const int row = krow*4+q;
        int c = selC[row]; if (c > 8) c = 8;
        for (int m=0;m<c;m++)
          ysel[((size_t)selI[row*8+m]*(L_N-1) + t)*H_N + unit] = hreg[q];
      }
    }
    __syncthreads();
  }
}

// ================= loss (finalize folded in via done-counter) =================
__global__ __launch_bounds__(64) void k_loss(
    const float* __restrict__ ysel, const float* __restrict__ y0,
    const int* __restrict__ wrev, const int* __restrict__ ssidx,
    const float* __restrict__ fcw, const float* __restrict__ fcb,
    float* __restrict__ accum, float* __restrict__ out)
{
  const int i = blockIdx.x;
  const int f = threadIdx.x;
  __shared__ float yh[H_N];
  const int seq = ssidx[i];
  float A=0.0f, B=0.0f, Sy=0.0f;
  const float bias = fcb[f];
  for (int t=0;t<L_N-1;t++){
    for (int k=f;k<H_N;k+=64) yh[k] = ysel[((size_t)i*(L_N-1)+t)*H_N + k];
    __syncthreads();
    float lg = bias;
    #pragma unroll 4
    for (int k=0;k<H_N;k++) lg = fmaf(fcw[f*H_N+k], yh[k], lg);
    const int node = wrev[(size_t)seq*L_N + t + 1];
    const float yt = y0[(size_t)node*F_N + f];
    A += yt * softplusf(-lg);
    B += (1.0f-yt) * softplusf(lg);
    Sy += yt;
    __syncthreads();
  }
  for (int off=32; off; off>>=1){
    A += __shfl_down(A,off); B += __shfl_down(B,off); Sy += __shfl_down(Sy,off);
  }
  if (f==0){
    atomicAdd(&accum[1],A); atomicAdd(&accum[2],B); atomicAdd(&accum[3],Sy);
    __threadfence();
    unsigned int done = atomicAdd((unsigned int*)&accum[5], 1u);
    if (done == NSEL-1){
      float As = atomicAdd(&accum[1], 0.0f);
      float Bs = atomicAdd(&accum[2], 0.0f);
      float Ss = atomicAdd(&accum[3], 0.0f);
      out[(size_t)SEQ_N*H_N] = As/Ss + Bs/(float)(NSEL*(L_N-1)*F_N);
    }
  }
}

extern "C" void kernel_launch(void* const* d_in, const int* in_sizes, int n_in,
                              void* d_out, int out_size, void* d_ws, size_t ws_size,
                              hipStream_t stream)
{
  const float* x     = (const float*)d_in[0];
  const float* y0    = (const float*)d_in[1];
  const float* wih_f = (const float*)d_in[2];
  const float* whh_f = (const float*)d_in[3];
  const float* bih_f = (const float*)d_in[4];
  const float* bhh_f = (const float*)d_in[5];
  const float* wih_b = (const float*)d_in[6];
  const float* whh_b = (const float*)d_in[7];
  const float* bih_b = (const float*)d_in[8];
  const float* bhh_b = (const float*)d_in[9];
  const float* wih   = (const float*)d_in[10];
  const float* whh   = (const float*)d_in[11];
  const float* bih   = (const float*)d_in[12];
  const float* bhh   = (const float*)d_in[13];
  const float* fc_w  = (const float*)d_in[14];
  const float* fc_b  = (const float*)d_in[15];
  const int*   walks = (const int*)d_in[16];
  const int*   dstdeg= (const int*)d_in[17];
  const int*   ssidx = (const int*)d_in[18];
  (void)in_sizes; (void)n_in; (void)out_size; (void)ws_size;

  char* ws = (char*)d_ws;
  size_t off = 0;
  auto wsalloc = [&](size_t bytes)->void* {
    void* p = ws + off; off += (bytes + 255) & ~(size_t)255; return p;
  };
  int*   accum_i = (int*)wsalloc(32);   // [0]=degmax [1..3]=loss [4]=slowCnt [5]=done
  float* accum_f = (float*)accum_i;
  int*   wrev   = (int*)  wsalloc(sizeof(int)  * SEQ_N * L_N);
  float* uwbuf  = (float*)wsalloc(sizeof(float)* SEQ_N * L_N * 2);
  unsigned short* pk_whhf = (unsigned short*)wsalloc(2u*24*4*64*8);
  unsigned short* pk_whhb = (unsigned short*)wsalloc(2u*24*4*64*8);
  unsigned short* pk_whh  = (unsigned short*)wsalloc(2u*24*4*64*8);
  unsigned short* pk_wih  = (unsigned short*)wsalloc(2u*24*12*64*8);
  float* ysel   = (float*)wsalloc(sizeof(float)* NSEL * (L_N-1) * H_N);
  char*  gxrz   = (char*)wsalloc((size_t)N_NODES*512);
  char*  gxn    = (char*)wsalloc((size_t)N_NODES*256);
  int*   canonFlag = (int*)wsalloc(sizeof(int)*SEQ_N);
  int*   slowIdxA  = (int*)wsalloc(sizeof(int)*SEQ_N);
  float* gposb = (float*)wsalloc(sizeof(float)*L_N*G_N);
  float* hc0   = (float*)wsalloc(sizeof(float)*H_N);

  hipMemsetAsync(accum_i, 0, 32, stream);
  k_prep<<<993, 512, 0, stream>>>(
      wih_f, whh_f, bih_f, bhh_f,
      wih_b, whh_b, bih_b, bhh_b,
      wih, whh, bih, bhh,
      walks, dstdeg,
      pk_whhf, pk_whhb, pk_whh, pk_wih,
      gposb, hc0, wrev, uwbuf, accum_i, canonFlag, slowIdxA);
  k_gx<<<N_NODES/16, 512, 0, stream>>>(x, pk_wih, wih, dstdeg, accum_i, gxrz, gxn);
  k_fast<<<SEQ_N/BSEQ, 512, 0, stream>>>(gxrz, gxn, pk_whh, bhh,
      gposb, hc0, ssidx, wrev, canonFlag,
      (float*)d_out, ysel);
  hipFuncSetAttribute(reinterpret_cast<const void*>(k_slow),
                      hipFuncAttributeMaxDynamicSharedMemorySize, SMEM_TOTAL);
  k_slow<<<SEQ_N/BSEQ, 512, SMEM_TOTAL, stream>>>(gxrz, gxn,
      pk_whhf, pk_whhb, pk_whh, pk_wih,
      wih_f, bih_f, bhh_f,
      wih_b, bih_b, bhh_b,
      bih, bhh,
      ssidx, wrev, uwbuf,
      slowIdxA, accum_i+4,
      (float*)d_out, ysel);
  k_loss<<<NSEL, 64, 0, stream>>>(ysel, y0, wrev, ssidx, fc_w, fc_b, accum_f, (float*)d_out);
}